// Round 1
// baseline (75439.362 us; speedup 1.0000x reference)
//
#include <hip/hip_runtime.h>
#include <hip/hip_bf16.h>
#include <hip/hip_cooperative_groups.h>

namespace cg = cooperative_groups;

// B=64 S=512 T=96 E=256 H=512 ENC_DIM=1024 4H=2048

__device__ __forceinline__ float sigm(float x){ return 1.f/(1.f+__expf(-x)); }
__device__ __forceinline__ float tanhfast(float x){
  float ax = fabsf(x);
  float e = __expf(-2.f*ax);
  float r = (1.f-e)/(1.f+e);
  return copysignf(r, x);
}
__device__ __forceinline__ float dot4(float4 a, float4 b){
  return fmaf(a.x,b.x, fmaf(a.y,b.y, fmaf(a.z,b.z, a.w*b.w)));
}

// ---------------- precompute: rank-1 folds, WencT transpose, head consts ----------------
__global__ void __launch_bounds__(256) precompute(
  const float* __restrict__ Wenc,                    // [512][1024]
  const float* __restrict__ Wihf, const float* __restrict__ epW, const float* __restrict__ epb,
  const float* __restrict__ bihf, const float* __restrict__ bhhf,
  const float* __restrict__ Wihb, const float* __restrict__ bihb, const float* __restrict__ bhhb,
  const float* __restrict__ dWih, const float* __restrict__ dpW, const float* __restrict__ dpb,
  const float* __restrict__ dbih, const float* __restrict__ dbhh,
  const float* __restrict__ valW, const float* __restrict__ valb,
  const float* __restrict__ stopW, const float* __restrict__ stopb,
  float* __restrict__ PQ,     // [Pf|Qf|Pb|Qb|Pd|Qd] each 2048
  float* __restrict__ WT,     // [1024][512]  WT[j][n] = Wenc[n][j]
  float* __restrict__ hc)     // 4 head consts
{
  const int idx = blockIdx.x*256 + threadIdx.x;
  if (idx < 524288){
    const int j = idx >> 9, n = idx & 511;
    WT[idx] = Wenc[(size_t)n*1024 + j];
  } else if (idx < 524288 + 6*2048){
    const int q = idx - 524288;
    const int set = q >> 11, j = q & 2047;
    const float* row; const float* vec; float add = 0.f;
    switch(set){
      case 0: row = Wihf + (size_t)j*256; vec = epW; break;
      case 1: row = Wihf + (size_t)j*256; vec = epb; add = bihf[j]+bhhf[j]; break;
      case 2: row = Wihb + (size_t)j*256; vec = epW; break;
      case 3: row = Wihb + (size_t)j*256; vec = epb; add = bihb[j]+bhhb[j]; break;
      case 4: row = dWih + (size_t)j*1280; vec = dpW; break;
      default: row = dWih + (size_t)j*1280; vec = dpb; add = dbih[j]+dbhh[j]; break;
    }
    float a = add;
    for (int e=0;e<256;e++) a = fmaf(row[e], vec[e], a);
    PQ[set*2048 + j] = a;
  } else if (idx < 524288 + 6*2048 + 4){
    const int q = idx - (524288 + 6*2048);
    const float* wrow = (q<2) ? valW : stopW;
    const float* vec  = (q&1) ? dpb : dpW;
    float a = (q&1) ? ((q<2)? valb[0] : stopb[0]) : 0.f;
    for (int e=0;e<256;e++) a = fmaf(wrow[1536+e], vec[e], a);
    hc[q] = a;
  }
}

// ---------------- encoder: cooperative, 1 grid.sync per time step ----------------
// 256 blocks x 256 threads. dir = bid>>7. Each thread owns one (b,u) cell:
// c-state in registers, h double-buffered in ws.
__global__ void __launch_bounds__(256) enc_coop(
    const float* __restrict__ src, const int* __restrict__ smask,
    const float* __restrict__ Whhf, const float* __restrict__ Whhb,
    const float* __restrict__ PQ,
    float* __restrict__ hf0, float* __restrict__ hf1,
    float* __restrict__ hb0, float* __restrict__ hb1,
    float* __restrict__ cf, float* __restrict__ cb,
    __hip_bfloat16* __restrict__ enc)
{
    cg::grid_group grid = cg::this_grid();
    const int bid = blockIdx.x;
    const int dir = bid >> 7;
    const int wid = bid & 127;
    const int tid = threadIdx.x;
    const int b = tid >> 2, ul = tid & 3;
    const int u = wid*4 + ul;
    const float* Whh = dir ? Whhb : Whhf;
    const float* P = PQ + dir*4096;
    const float* Q = P + 2048;
    const float p0=P[u], p1=P[u+512], p2=P[u+1024], p3=P[u+1536];
    const float q0=Q[u], q1=Q[u+512], q2=Q[u+1024], q3=Q[u+1536];
    const float4* w0 = (const float4*)(Whh + (size_t)u*512);
    const float4* w1 = (const float4*)(Whh + ((size_t)u+512)*512);
    const float4* w2 = (const float4*)(Whh + ((size_t)u+1024)*512);
    const float4* w3 = (const float4*)(Whh + ((size_t)u+1536)*512);
    float* hA = dir ? hb0 : hf0;   // read at even tt, written at odd tt
    float* hB = dir ? hb1 : hf1;
    float creg = 0.f, hprev = 0.f;
    for (int tt=0; tt<512; ++tt){
        const int t = dir ? (511-tt) : tt;
        const float4* hv = (const float4*)(((tt&1) ? hB : hA) + b*512);
        float a0=0.f,a1=0.f,a2=0.f,a3=0.f;
        #pragma unroll 4
        for (int k=0;k<128;k++){
            const float4 h4 = hv[k];
            a0 += dot4(h4, w0[k]);
            a1 += dot4(h4, w1[k]);
            a2 += dot4(h4, w2[k]);
            a3 += dot4(h4, w3[k]);
        }
        const float sx = src[b*512+t]*0.001f;
        const int m = smask[b*512+t];
        const float pi = a0 + sx*p0 + q0;
        const float pf = a1 + sx*p1 + q1;
        const float pg = a2 + sx*p2 + q2;
        const float po = a3 + sx*p3 + q3;
        const float cn = fmaf(sigm(pf), creg, sigm(pi)*tanhfast(pg));
        const float hn = sigm(po)*tanhfast(cn);
        const float hkeep = m ? hn : hprev;
        creg = m ? cn : creg;
        hprev = hkeep;
        (((tt&1) ? hA : hB))[b*512+u] = hkeep;
        enc[((size_t)(b*512 + t))*1024 + dir*512 + u] = __float2bfloat16(m ? hn : 0.f);
        grid.sync();
    }
    (dir ? cb : cf)[b*512+u] = creg;   // final h already sits in hf0/hb0
}

// ---------------- decoder init: hidden/cell = tanh([hF,hB]@W.T + b) ----------------
__global__ void __launch_bounds__(256) fc_init(
  const float* __restrict__ hf0, const float* __restrict__ hb0,
  const float* __restrict__ cf, const float* __restrict__ cb,
  const float* __restrict__ fchW, const float* __restrict__ fchB,
  const float* __restrict__ fccW, const float* __restrict__ fccB,
  float* __restrict__ dech, float* __restrict__ decc)
{
  const int which = blockIdx.x >> 7;
  const int wid = blockIdx.x & 127;
  const int b = threadIdx.x >> 2, ul = threadIdx.x & 3;
  const int u = wid*4 + ul;
  const float* s0 = which ? cf : hf0;
  const float* s1 = which ? cb : hb0;
  const float* W = which ? fccW : fchW;
  float acc = (which ? fccB : fchB)[u];
  const float4* x0 = (const float4*)(s0 + b*512);
  const float4* x1 = (const float4*)(s1 + b*512);
  const float4* wr = (const float4*)(W + (size_t)u*1024);
  #pragma unroll 4
  for (int k=0;k<128;k++) acc += dot4(x0[k], wr[k]);
  #pragma unroll 4
  for (int k=0;k<128;k++) acc += dot4(x1[k], wr[128+k]);
  (which ? decc : dech)[b*512+u] = tanhfast(acc);
}

// ---------------- eh = enc_out @ Wenc.T, stored transposed ehT[b][n][s] ----------------
__global__ void __launch_bounds__(512) eh_gemm(
  const __hip_bfloat16* __restrict__ enc, const float* __restrict__ WT, float* __restrict__ ehT)
{
  const int b = blockIdx.x >> 6;
  const int s = (blockIdx.x & 63)*8 + (threadIdx.x >> 6);
  const int n0 = (threadIdx.x & 63)*8;
  const __hip_bfloat16* ap = enc + ((size_t)(b*512 + s))*1024;
  float c0=0,c1=0,c2=0,c3=0,c4=0,c5=0,c6=0,c7=0;
  for (int k=0;k<1024;k++){
    const float a = __bfloat162float(ap[k]);
    const float4* w = (const float4*)(WT + (size_t)k*512 + n0);
    const float4 wA = w[0], wB = w[1];
    c0 = fmaf(a, wA.x, c0); c1 = fmaf(a, wA.y, c1);
    c2 = fmaf(a, wA.z, c2); c3 = fmaf(a, wA.w, c3);
    c4 = fmaf(a, wB.x, c4); c5 = fmaf(a, wB.y, c5);
    c6 = fmaf(a, wB.z, c6); c7 = fmaf(a, wB.w, c7);
  }
  float* op = ehT + ((size_t)(b*512) + n0)*512 + s;
  op[0]=c0; op[512]=c1; op[1024]=c2; op[1536]=c3;
  op[2048]=c4; op[2560]=c5; op[3072]=c6; op[3584]=c7;
}

// ---------------- decoder step kernels ----------------
// blocks 0..127: attn_dh = h @ Wdec.T ; blocks 128..191: heads for step t-1
__global__ void __launch_bounds__(256) dec_attn_heads(
  const float* __restrict__ dech, const float* __restrict__ Wdec,
  float* __restrict__ adh,
  const float* __restrict__ ctx, const float* __restrict__ valW,
  const float* __restrict__ stopW, const float* __restrict__ trg,
  const float* __restrict__ hc, float* __restrict__ out, int t)
{
  __shared__ float r1[256], r2[256];
  const int bid = blockIdx.x;
  if (bid < 128){
    const int b = threadIdx.x >> 2, jl = threadIdx.x & 3;
    const int j = bid*4 + jl;
    const float4* h4 = (const float4*)(dech + b*512);
    const float4* w4 = (const float4*)(Wdec + (size_t)j*512);
    float acc = 0.f;
    #pragma unroll 4
    for (int k=0;k<128;k++) acc += dot4(h4[k], w4[k]);
    adh[b*512 + j] = acc;
  } else if (t > 0){
    const int b = bid - 128;
    float apv = 0.f, asl = 0.f;
    for (int k = threadIdx.x; k < 1536; k += 256){
      const float f = (k < 512) ? dech[b*512+k] : ctx[b*1024 + (k-512)];
      apv = fmaf(f, valW[k], apv);
      asl = fmaf(f, stopW[k], asl);
    }
    r1[threadIdx.x] = apv; r2[threadIdx.x] = asl;
    __syncthreads();
    for (int off=128; off>0; off>>=1){
      if (threadIdx.x < off){ r1[threadIdx.x]+=r1[threadIdx.x+off]; r2[threadIdx.x]+=r2[threadIdx.x+off]; }
      __syncthreads();
    }
    if (threadIdx.x==0){
      const float x = trg[b*96 + (t-1)]*0.001f;
      out[b*95 + (t-1)] = (r1[0] + x*hc[0] + hc[1]) * 1000.f;
      out[6080 + b*95 + (t-1)] = r2[0] + x*hc[2] + hc[3];
    }
  }
}

__global__ void __launch_bounds__(512) dec_scores(
  const float* __restrict__ adh, const float* __restrict__ ehT,
  const float* __restrict__ attnv, const int* __restrict__ smask,
  float* __restrict__ scores)
{
  const int b = blockIdx.x >> 2;
  const int s0 = (blockIdx.x & 3)*128;
  const int sl = threadIdx.x & 127;
  const int ks = threadIdx.x >> 7;
  __shared__ float dh[512], vv[512];
  __shared__ float part[4][128];
  dh[threadIdx.x] = adh[b*512 + threadIdx.x];
  vv[threadIdx.x] = attnv[threadIdx.x];
  __syncthreads();
  const int s = s0 + sl;
  const float* ehp = ehT + ((size_t)(b*512 + ks*128))*512 + s;
  float acc = 0.f;
  #pragma unroll 4
  for (int i=0;i<128;i++){
    acc = fmaf(vv[ks*128+i], tanhfast(dh[ks*128+i] + ehp[(size_t)i*512]), acc);
  }
  part[ks][sl] = acc;
  __syncthreads();
  if (ks==0){
    const float total = part[0][sl]+part[1][sl]+part[2][sl]+part[3][sl];
    scores[b*512+s] = smask[b*512+s] ? total : -1.0e9f;
  }
}

// softmax (recomputed per block) + context partial. block = (b, j-quarter)
__global__ void __launch_bounds__(512) dec_ctx(
  const float* __restrict__ scores, const __hip_bfloat16* __restrict__ enc,
  float* __restrict__ ctx)
{
  const int b = blockIdx.x >> 2;
  const int j0 = (blockIdx.x & 3) * 256;
  const int tid = threadIdx.x;
  __shared__ float w[512];
  __shared__ float red[512];
  const float sc = scores[b*512 + tid];
  red[tid] = sc;
  __syncthreads();
  for (int off=256; off>0; off>>=1){
    if (tid < off) red[tid] = fmaxf(red[tid], red[tid+off]);
    __syncthreads();
  }
  const float mx = red[0];
  __syncthreads();
  const float e = __expf(sc - mx);
  w[tid] = e;
  red[tid] = e;
  __syncthreads();
  for (int off=256; off>0; off>>=1){
    if (tid < off) red[tid] += red[tid+off];
    __syncthreads();
  }
  const float Z = red[0];
  __syncthreads();
  const int kh = tid >> 8, jl = tid & 255;
  const __hip_bfloat16* ep = enc + ((size_t)(b*512 + kh*256))*1024 + j0 + jl;
  float acc = 0.f;
  #pragma unroll 4
  for (int s2=0; s2<256; s2++)
    acc = fmaf(w[kh*256+s2], __bfloat162float(ep[(size_t)s2*1024]), acc);
  red[tid] = acc;
  __syncthreads();
  if (kh==0) ctx[b*1024 + j0 + jl] = (red[jl] + red[256+jl]) / Z;
}

__global__ void __launch_bounds__(512) dec_gates(
  const float* __restrict__ ctx, const float* __restrict__ dech,
  const float* __restrict__ dWih, const float* __restrict__ dWhh,
  const float* __restrict__ PQd, const float* __restrict__ trg,
  float* __restrict__ gates, int t)
{
  const int r = blockIdx.x*8 + (threadIdx.x & 7);
  const int b = threadIdx.x >> 3;
  const float x = trg[b*96 + t]*0.001f;
  float acc = fmaf(x, PQd[r], PQd[2048 + r]);
  const float4* c4 = (const float4*)(ctx + b*1024);
  const float4* wc = (const float4*)(dWih + (size_t)r*1280 + 256);
  #pragma unroll 4
  for (int k=0;k<256;k++) acc += dot4(c4[k], wc[k]);
  const float4* h4 = (const float4*)(dech + b*512);
  const float4* wh = (const float4*)(dWhh + (size_t)r*512);
  #pragma unroll 4
  for (int k=0;k<128;k++) acc += dot4(h4[k], wh[k]);
  gates[b*2048 + r] = acc;
}

__global__ void __launch_bounds__(512) dec_update(
  const float* __restrict__ gates, float* __restrict__ dech, float* __restrict__ decc)
{
  const int b = blockIdx.x, u = threadIdx.x;
  const float gi = gates[b*2048 + u];
  const float gf = gates[b*2048 + 512 + u];
  const float gg = gates[b*2048 + 1024 + u];
  const float go = gates[b*2048 + 1536 + u];
  const float c = decc[b*512 + u];
  const float cn = fmaf(sigm(gf), c, sigm(gi)*tanhfast(gg));
  const float hn = sigm(go)*tanhfast(cn);
  decc[b*512+u] = cn;
  dech[b*512+u] = hn;
}

// ---------------- launch ----------------
extern "C" void kernel_launch(void* const* d_in, const int* in_sizes, int n_in,
                              void* d_out, int out_size, void* d_ws, size_t ws_size,
                              hipStream_t stream)
{
  (void)in_sizes; (void)n_in; (void)out_size; (void)ws_size;
  const float* src   = (const float*)d_in[0];
  const int*   smask = (const int*)  d_in[1];
  const float* trg   = (const float*)d_in[2];
  const float* epW   = (const float*)d_in[4];
  const float* epb   = (const float*)d_in[5];
  const float* Wihf  = (const float*)d_in[6];
  const float* Whhf  = (const float*)d_in[7];
  const float* bihf  = (const float*)d_in[8];
  const float* bhhf  = (const float*)d_in[9];
  const float* Wihb  = (const float*)d_in[10];
  const float* Whhb  = (const float*)d_in[11];
  const float* bihb  = (const float*)d_in[12];
  const float* bhhb  = (const float*)d_in[13];
  const float* fchW  = (const float*)d_in[14];
  const float* fchB  = (const float*)d_in[15];
  const float* fccW  = (const float*)d_in[16];
  const float* fccB  = (const float*)d_in[17];
  const float* dpW   = (const float*)d_in[18];
  const float* dpb   = (const float*)d_in[19];
  const float* Wenc  = (const float*)d_in[20];
  const float* Wdec  = (const float*)d_in[21];
  const float* attnv = (const float*)d_in[22];
  const float* dWih  = (const float*)d_in[23];
  const float* dWhh  = (const float*)d_in[24];
  const float* dbih  = (const float*)d_in[25];
  const float* dbhh  = (const float*)d_in[26];
  const float* valW  = (const float*)d_in[27];
  const float* valb  = (const float*)d_in[28];
  const float* stopW = (const float*)d_in[29];
  const float* stopb = (const float*)d_in[30];
  float* out = (float*)d_out;

  char* ws = (char*)d_ws;
  __hip_bfloat16* enc = (__hip_bfloat16*)(ws + 0);          // 64*512*1024 bf16 = 64 MiB
  float* ehT = (float*)(ws + 67108864);                     // [64][512][512] f32 = 64 MiB
  float* hf0 = (float*)(ws + 134217728);
  float* hf1 = hf0 + 32768;
  float* hb0 = hf1 + 32768;
  float* hb1 = hb0 + 32768;
  float* cf  = hb1 + 32768;
  float* cb  = cf + 32768;
  float* PQ  = cb + 32768;        // 6*2048
  float* dech = PQ + 12288;
  float* decc = dech + 32768;
  float* adh = decc + 32768;
  float* scores = adh + 32768;
  float* ctx = scores + 32768;
  float* gates = ctx + 65536;
  float* WT = gates + 131072;     // 1024*512
  float* hc = WT + 524288;        // 4
  float* PQd = PQ + 8192;

  hipMemsetAsync(hf0, 0, 131072, stream);
  hipMemsetAsync(hb0, 0, 131072, stream);

  precompute<<<2097, 256, 0, stream>>>(Wenc, Wihf, epW, epb, bihf, bhhf, Wihb, bihb, bhhb,
                                       dWih, dpW, dpb, dbih, dbhh, valW, valb, stopW, stopb,
                                       PQ, WT, hc);

  {
    void* args[] = { (void*)&src, (void*)&smask, (void*)&Whhf, (void*)&Whhb, (void*)&PQ,
                     (void*)&hf0, (void*)&hf1, (void*)&hb0, (void*)&hb1,
                     (void*)&cf, (void*)&cb, (void*)&enc };
    hipLaunchCooperativeKernel((void*)enc_coop, dim3(256), dim3(256), args, 0, stream);
  }

  fc_init<<<256, 256, 0, stream>>>(hf0, hb0, cf, cb, fchW, fchB, fccW, fccB, dech, decc);
  eh_gemm<<<4096, 512, 0, stream>>>(enc, WT, ehT);

  for (int t=0; t<95; ++t){
    dec_attn_heads<<<192, 256, 0, stream>>>(dech, Wdec, adh, ctx, valW, stopW, trg, hc, out, t);
    dec_scores<<<256, 512, 0, stream>>>(adh, ehT, attnv, smask, scores);
    dec_ctx<<<256, 512, 0, stream>>>(scores, enc, ctx);
    dec_gates<<<256, 512, 0, stream>>>(ctx, dech, dWih, dWhh, PQd, trg, gates, t);
    dec_update<<<64, 512, 0, stream>>>(gates, dech, decc);
  }
  // final heads for t=94 (attn_dh part harmless)
  dec_attn_heads<<<192, 256, 0, stream>>>(dech, Wdec, adh, ctx, valW, stopW, trg, hc, out, 95);
}

// Round 2
// 29995.010 us; speedup vs baseline: 2.5151x; 2.5151x over previous
//
#include <hip/hip_runtime.h>
#include <hip/hip_bf16.h>

#define AGENT __HIP_MEMORY_SCOPE_AGENT

// B=64 S=512 T=96 E=256 H=512 ENC_DIM=1024 4H=2048

__device__ __forceinline__ float sigm(float x){ return 1.f/(1.f+__expf(-x)); }
__device__ __forceinline__ float tanhfast(float x){
  float ax = fabsf(x);
  float e = __expf(-2.f*ax);
  float r = (1.f-e)/(1.f+e);
  return copysignf(r, x);
}
__device__ __forceinline__ float dot4(float4 a, float4 b){
  return fmaf(a.x,b.x, fmaf(a.y,b.y, fmaf(a.z,b.z, a.w*b.w)));
}

// ---------------- precompute: rank-1 folds, WencT transpose, head consts ----------------
__global__ void __launch_bounds__(256) precompute(
  const float* __restrict__ Wenc,                    // [512][1024]
  const float* __restrict__ Wihf, const float* __restrict__ epW, const float* __restrict__ epb,
  const float* __restrict__ bihf, const float* __restrict__ bhhf,
  const float* __restrict__ Wihb, const float* __restrict__ bihb, const float* __restrict__ bhhb,
  const float* __restrict__ dWih, const float* __restrict__ dpW, const float* __restrict__ dpb,
  const float* __restrict__ dbih, const float* __restrict__ dbhh,
  const float* __restrict__ valW, const float* __restrict__ valb,
  const float* __restrict__ stopW, const float* __restrict__ stopb,
  float* __restrict__ PQ,     // [Pf|Qf|Pb|Qb|Pd|Qd] each 2048
  float* __restrict__ WT,     // [1024][512]  WT[j][n] = Wenc[n][j]
  float* __restrict__ hc)     // 4 head consts
{
  const int idx = blockIdx.x*256 + threadIdx.x;
  if (idx < 524288){
    const int j = idx >> 9, n = idx & 511;
    WT[idx] = Wenc[(size_t)n*1024 + j];
  } else if (idx < 524288 + 6*2048){
    const int q = idx - 524288;
    const int set = q >> 11, j = q & 2047;
    const float* row; const float* vec; float add = 0.f;
    switch(set){
      case 0: row = Wihf + (size_t)j*256; vec = epW; break;
      case 1: row = Wihf + (size_t)j*256; vec = epb; add = bihf[j]+bhhf[j]; break;
      case 2: row = Wihb + (size_t)j*256; vec = epW; break;
      case 3: row = Wihb + (size_t)j*256; vec = epb; add = bihb[j]+bhhb[j]; break;
      case 4: row = dWih + (size_t)j*1280; vec = dpW; break;
      default: row = dWih + (size_t)j*1280; vec = dpb; add = dbih[j]+dbhh[j]; break;
    }
    float a = add;
    for (int e=0;e<256;e++) a = fmaf(row[e], vec[e], a);
    PQ[set*2048 + j] = a;
  } else if (idx < 524288 + 6*2048 + 4){
    const int q = idx - (524288 + 6*2048);
    const float* wrow = (q<2) ? valW : stopW;
    const float* vec  = (q&1) ? dpb : dpW;
    float a = (q&1) ? ((q<2)? valb[0] : stopb[0]) : 0.f;
    for (int e=0;e<256;e++) a = fmaf(wrow[1536+e], vec[e], a);
    hc[q] = a;
  }
}

// ---------------- encoder: cooperative, custom fence-free barrier ----------------
// 256 blocks x 512 threads. bid: dir=bid>>7, half=(bid>>5)&3 (16-batch slice),
// us=bid&31 (16-unit slice). tid: b_l=tid&15, u_l=(tid>>4)&15, kh=tid>>8 (k half).
// Cross-block h goes L3-direct (sc0 sc1); barrier = relaxed agent atomic counter.
__global__ void __launch_bounds__(512) enc_coop2(
    const float* __restrict__ src, const int* __restrict__ smask,
    const float* __restrict__ Whhf, const float* __restrict__ Whhb,
    const float* __restrict__ PQ,
    float* __restrict__ hb,            // [2 dir][2 buf][64][512] f32
    float* __restrict__ cf, float* __restrict__ cb,
    __hip_bfloat16* __restrict__ enc,  // [64][512][1024]
    unsigned* __restrict__ cnt)
{
  __shared__ float hlds[16*516];   // 16 batches x 512 units, pad 4 -> 2-way max
  __shared__ float4 pr[256];       // k-split partial sums
  const int tid = threadIdx.x;
  const int bid = blockIdx.x;
  const int dir = bid>>7, half = (bid>>5)&3, us = bid&31;
  const int b_l = tid&15, u_l = (tid>>4)&15, kh = tid>>8;
  const int b = half*16 + b_l, u = us*16 + u_l;
  const float* Whh = dir? Whhb : Whhf;
  const float4* w0 = (const float4*)(Whh + ((size_t)u       )*512 + (size_t)kh*256);
  const float4* w1 = (const float4*)(Whh + ((size_t)u +  512)*512 + (size_t)kh*256);
  const float4* w2 = (const float4*)(Whh + ((size_t)u + 1024)*512 + (size_t)kh*256);
  const float4* w3 = (const float4*)(Whh + ((size_t)u + 1536)*512 + (size_t)kh*256);
  const float* P = PQ + dir*4096; const float* Q = P + 2048;
  const float p0=P[u], p1=P[u+512], p2=P[u+1024], p3=P[u+1536];
  const float q0=Q[u], q1=Q[u+512], q2=Q[u+1024], q3=Q[u+1536];
  float creg = 0.f, hprev = 0.f;
  unsigned* encu = (unsigned*)enc;

  for (int tt=0; tt<512; ++tt){
    const int t = dir ? (511-tt) : tt;
    if (tt>0){
      if (tid==0){
        while (__hip_atomic_load(cnt, __ATOMIC_RELAXED, AGENT) < 256u*(unsigned)tt)
          __builtin_amdgcn_s_sleep(1);
      }
      __syncthreads();
      // stage h_{tt-1} from L3 (bypass L2), fuse enc bf16 emission for tprev
      const float2* sp = (const float2*)(hb + (((size_t)dir*2 + ((tt-1)&1))*64 + half*16)*512) + tid;
      float2 tmp[8];
      #pragma unroll
      for (int i=0;i<8;i++){
        const float2* p = sp + i*512;
        asm volatile("global_load_dwordx2 %0, %1, off sc0 sc1" : "=v"(tmp[i]) : "v"(p) : "memory");
      }
      asm volatile("s_waitcnt vmcnt(0)" ::: "memory");
      __builtin_amdgcn_sched_barrier(0);
      const int tprev = dir ? (512-tt) : (tt-1);
      #pragma unroll
      for (int i=0;i<8;i++){
        const int w = i*512 + tid;          // 8B word index within 16x512 slice
        const int row = w>>8, colw = w&255;
        ((float2*)hlds)[row*258 + colw] = tmp[i];
        if (us==0){
          const int bi = half*16 + row;
          const int m = smask[bi*512 + tprev];
          const unsigned short hx = __bfloat16_as_ushort(__float2bfloat16(m ? tmp[i].x : 0.f));
          const unsigned short hy = __bfloat16_as_ushort(__float2bfloat16(m ? tmp[i].y : 0.f));
          const unsigned pk = (unsigned)hx | ((unsigned)hy<<16);
          __builtin_nontemporal_store(pk, encu + (((size_t)(bi*512 + tprev)*1024 + dir*512)>>1) + colw);
        }
      }
      __syncthreads();
    }
    float a0=0.f,a1=0.f,a2=0.f,a3=0.f;
    if (tt>0){
      const float4* hv = (const float4*)hlds + (size_t)b_l*129 + kh*64;
      #pragma unroll 8
      for (int k=0;k<64;k++){
        const float4 h4 = hv[k];
        a0 += dot4(h4, w0[k]);
        a1 += dot4(h4, w1[k]);
        a2 += dot4(h4, w2[k]);
        a3 += dot4(h4, w3[k]);
      }
    }
    if (kh==1) pr[tid-256] = make_float4(a0,a1,a2,a3);
    __syncthreads();
    if (kh==0){
      const float4 pp = pr[tid];
      const float sx = src[b*512+t]*0.001f;
      const int m = smask[b*512+t];
      const float pi = a0+pp.x + sx*p0 + q0;
      const float pf = a1+pp.y + sx*p1 + q1;
      const float pg = a2+pp.z + sx*p2 + q2;
      const float po = a3+pp.w + sx*p3 + q3;
      const float cn = fmaf(sigm(pf), creg, sigm(pi)*tanhfast(pg));
      const float hn = sigm(po)*tanhfast(cn);
      const float hk = m ? hn : hprev;
      creg = m ? cn : creg;
      hprev = hk;
      float* hp = hb + (((size_t)dir*2 + (tt&1))*64 + b)*512 + u;
      asm volatile("global_store_dword %0, %1, off sc0 sc1" :: "v"(hp), "v"(hk) : "memory");
    }
    asm volatile("s_waitcnt vmcnt(0)" ::: "memory");
    __syncthreads();
    if (tid==0) __hip_atomic_fetch_add(cnt, 1u, __ATOMIC_RELAXED, AGENT);
  }

  // final: wait for step 511 stores, emit enc for the last t, write c state
  if (tid==0){
    while (__hip_atomic_load(cnt, __ATOMIC_RELAXED, AGENT) < 256u*512u)
      __builtin_amdgcn_s_sleep(1);
  }
  __syncthreads();
  if (us==0){
    const float2* sp = (const float2*)(hb + (((size_t)dir*2 + 1)*64 + half*16)*512) + tid;
    float2 tmp[8];
    #pragma unroll
    for (int i=0;i<8;i++){
      const float2* p = sp + i*512;
      asm volatile("global_load_dwordx2 %0, %1, off sc0 sc1" : "=v"(tmp[i]) : "v"(p) : "memory");
    }
    asm volatile("s_waitcnt vmcnt(0)" ::: "memory");
    __builtin_amdgcn_sched_barrier(0);
    const int tl = dir ? 0 : 511;
    #pragma unroll
    for (int i=0;i<8;i++){
      const int w = i*512 + tid;
      const int row = w>>8, colw = w&255;
      const int bi = half*16 + row;
      const int m = smask[bi*512 + tl];
      const unsigned short hx = __bfloat16_as_ushort(__float2bfloat16(m ? tmp[i].x : 0.f));
      const unsigned short hy = __bfloat16_as_ushort(__float2bfloat16(m ? tmp[i].y : 0.f));
      const unsigned pk = (unsigned)hx | ((unsigned)hy<<16);
      __builtin_nontemporal_store(pk, encu + (((size_t)(bi*512 + tl)*1024 + dir*512)>>1) + colw);
    }
  }
  if (kh==0){
    (dir ? cb : cf)[b*512+u] = creg;
  }
}

// ---------------- decoder init: hidden/cell = tanh([hF,hB]@W.T + b) ----------------
__global__ void __launch_bounds__(256) fc_init(
  const float* __restrict__ hf0, const float* __restrict__ hb0,
  const float* __restrict__ cf, const float* __restrict__ cb,
  const float* __restrict__ fchW, const float* __restrict__ fchB,
  const float* __restrict__ fccW, const float* __restrict__ fccB,
  float* __restrict__ dech, float* __restrict__ decc)
{
  const int which = blockIdx.x >> 7;
  const int wid = blockIdx.x & 127;
  const int b = threadIdx.x >> 2, ul = threadIdx.x & 3;
  const int u = wid*4 + ul;
  const float* s0 = which ? cf : hf0;
  const float* s1 = which ? cb : hb0;
  const float* W = which ? fccW : fchW;
  float acc = (which ? fccB : fchB)[u];
  const float4* x0 = (const float4*)(s0 + b*512);
  const float4* x1 = (const float4*)(s1 + b*512);
  const float4* wr = (const float4*)(W + (size_t)u*1024);
  #pragma unroll 4
  for (int k=0;k<128;k++) acc += dot4(x0[k], wr[k]);
  #pragma unroll 4
  for (int k=0;k<128;k++) acc += dot4(x1[k], wr[128+k]);
  (which ? decc : dech)[b*512+u] = tanhfast(acc);
}

// ---------------- eh = enc_out @ Wenc.T, stored transposed ehT[b][n][s] ----------------
__global__ void __launch_bounds__(512) eh_gemm(
  const __hip_bfloat16* __restrict__ enc, const float* __restrict__ WT, float* __restrict__ ehT)
{
  const int b = blockIdx.x >> 6;
  const int s = (blockIdx.x & 63)*8 + (threadIdx.x >> 6);
  const int n0 = (threadIdx.x & 63)*8;
  const __hip_bfloat16* ap = enc + ((size_t)(b*512 + s))*1024;
  float c0=0,c1=0,c2=0,c3=0,c4=0,c5=0,c6=0,c7=0;
  for (int k=0;k<1024;k++){
    const float a = __bfloat162float(ap[k]);
    const float4* w = (const float4*)(WT + (size_t)k*512 + n0);
    const float4 wA = w[0], wB = w[1];
    c0 = fmaf(a, wA.x, c0); c1 = fmaf(a, wA.y, c1);
    c2 = fmaf(a, wA.z, c2); c3 = fmaf(a, wA.w, c3);
    c4 = fmaf(a, wB.x, c4); c5 = fmaf(a, wB.y, c5);
    c6 = fmaf(a, wB.z, c6); c7 = fmaf(a, wB.w, c7);
  }
  float* op = ehT + ((size_t)(b*512) + n0)*512 + s;
  op[0]=c0; op[512]=c1; op[1024]=c2; op[1536]=c3;
  op[2048]=c4; op[2560]=c5; op[3072]=c6; op[3584]=c7;
}

// ---------------- decoder step kernels ----------------
__global__ void __launch_bounds__(256) dec_attn_heads(
  const float* __restrict__ dech, const float* __restrict__ Wdec,
  float* __restrict__ adh,
  const float* __restrict__ ctx, const float* __restrict__ valW,
  const float* __restrict__ stopW, const float* __restrict__ trg,
  const float* __restrict__ hc, float* __restrict__ out, int t)
{
  __shared__ float r1[256], r2[256];
  const int bid = blockIdx.x;
  if (bid < 128){
    const int b = threadIdx.x >> 2, jl = threadIdx.x & 3;
    const int j = bid*4 + jl;
    const float4* h4 = (const float4*)(dech + b*512);
    const float4* w4 = (const float4*)(Wdec + (size_t)j*512);
    float acc = 0.f;
    #pragma unroll 4
    for (int k=0;k<128;k++) acc += dot4(h4[k], w4[k]);
    adh[b*512 + j] = acc;
  } else if (t > 0){
    const int b = bid - 128;
    float apv = 0.f, asl = 0.f;
    for (int k = threadIdx.x; k < 1536; k += 256){
      const float f = (k < 512) ? dech[b*512+k] : ctx[b*1024 + (k-512)];
      apv = fmaf(f, valW[k], apv);
      asl = fmaf(f, stopW[k], asl);
    }
    r1[threadIdx.x] = apv; r2[threadIdx.x] = asl;
    __syncthreads();
    for (int off=128; off>0; off>>=1){
      if (threadIdx.x < off){ r1[threadIdx.x]+=r1[threadIdx.x+off]; r2[threadIdx.x]+=r2[threadIdx.x+off]; }
      __syncthreads();
    }
    if (threadIdx.x==0){
      const float x = trg[b*96 + (t-1)]*0.001f;
      out[b*95 + (t-1)] = (r1[0] + x*hc[0] + hc[1]) * 1000.f;
      out[6080 + b*95 + (t-1)] = r2[0] + x*hc[2] + hc[3];
    }
  }
}

__global__ void __launch_bounds__(512) dec_scores(
  const float* __restrict__ adh, const float* __restrict__ ehT,
  const float* __restrict__ attnv, const int* __restrict__ smask,
  float* __restrict__ scores)
{
  const int b = blockIdx.x >> 2;
  const int s0 = (blockIdx.x & 3)*128;
  const int sl = threadIdx.x & 127;
  const int ks = threadIdx.x >> 7;
  __shared__ float dh[512], vv[512];
  __shared__ float part[4][128];
  dh[threadIdx.x] = adh[b*512 + threadIdx.x];
  vv[threadIdx.x] = attnv[threadIdx.x];
  __syncthreads();
  const int s = s0 + sl;
  const float* ehp = ehT + ((size_t)(b*512 + ks*128))*512 + s;
  float acc = 0.f;
  #pragma unroll 4
  for (int i=0;i<128;i++){
    acc = fmaf(vv[ks*128+i], tanhfast(dh[ks*128+i] + ehp[(size_t)i*512]), acc);
  }
  part[ks][sl] = acc;
  __syncthreads();
  if (ks==0){
    const float total = part[0][sl]+part[1][sl]+part[2][sl]+part[3][sl];
    scores[b*512+s] = smask[b*512+s] ? total : -1.0e9f;
  }
}

__global__ void __launch_bounds__(512) dec_ctx(
  const float* __restrict__ scores, const __hip_bfloat16* __restrict__ enc,
  float* __restrict__ ctx)
{
  const int b = blockIdx.x >> 2;
  const int j0 = (blockIdx.x & 3) * 256;
  const int tid = threadIdx.x;
  __shared__ float w[512];
  __shared__ float red[512];
  const float sc = scores[b*512 + tid];
  red[tid] = sc;
  __syncthreads();
  for (int off=256; off>0; off>>=1){
    if (tid < off) red[tid] = fmaxf(red[tid], red[tid+off]);
    __syncthreads();
  }
  const float mx = red[0];
  __syncthreads();
  const float e = __expf(sc - mx);
  w[tid] = e;
  red[tid] = e;
  __syncthreads();
  for (int off=256; off>0; off>>=1){
    if (tid < off) red[tid] += red[tid+off];
    __syncthreads();
  }
  const float Z = red[0];
  __syncthreads();
  const int kh = tid >> 8, jl = tid & 255;
  const __hip_bfloat16* ep = enc + ((size_t)(b*512 + kh*256))*1024 + j0 + jl;
  float acc = 0.f;
  #pragma unroll 4
  for (int s2=0; s2<256; s2++)
    acc = fmaf(w[kh*256+s2], __bfloat162float(ep[(size_t)s2*1024]), acc);
  red[tid] = acc;
  __syncthreads();
  if (kh==0) ctx[b*1024 + j0 + jl] = (red[jl] + red[256+jl]) / Z;
}

__global__ void __launch_bounds__(512) dec_gates(
  const float* __restrict__ ctx, const float* __restrict__ dech,
  const float* __restrict__ dWih, const float* __restrict__ dWhh,
  const float* __restrict__ PQd, const float* __restrict__ trg,
  float* __restrict__ gates, int t)
{
  const int r = blockIdx.x*8 + (threadIdx.x & 7);
  const int b = threadIdx.x >> 3;
  const float x = trg[b*96 + t]*0.001f;
  float acc = fmaf(x, PQd[r], PQd[2048 + r]);
  const float4* c4 = (const float4*)(ctx + b*1024);
  const float4* wc = (const float4*)(dWih + (size_t)r*1280 + 256);
  #pragma unroll 4
  for (int k=0;k<256;k++) acc += dot4(c4[k], wc[k]);
  const float4* h4 = (const float4*)(dech + b*512);
  const float4* wh = (const float4*)(dWhh + (size_t)r*512);
  #pragma unroll 4
  for (int k=0;k<128;k++) acc += dot4(h4[k], wh[k]);
  gates[b*2048 + r] = acc;
}

__global__ void __launch_bounds__(512) dec_update(
  const float* __restrict__ gates, float* __restrict__ dech, float* __restrict__ decc)
{
  const int b = blockIdx.x, u = threadIdx.x;
  const float gi = gates[b*2048 + u];
  const float gf = gates[b*2048 + 512 + u];
  const float gg = gates[b*2048 + 1024 + u];
  const float go = gates[b*2048 + 1536 + u];
  const float c = decc[b*512 + u];
  const float cn = fmaf(sigm(gf), c, sigm(gi)*tanhfast(gg));
  const float hn = sigm(go)*tanhfast(cn);
  decc[b*512+u] = cn;
  dech[b*512+u] = hn;
}

// ---------------- launch ----------------
extern "C" void kernel_launch(void* const* d_in, const int* in_sizes, int n_in,
                              void* d_out, int out_size, void* d_ws, size_t ws_size,
                              hipStream_t stream)
{
  (void)in_sizes; (void)n_in; (void)out_size; (void)ws_size;
  const float* src   = (const float*)d_in[0];
  const int*   smask = (const int*)  d_in[1];
  const float* trg   = (const float*)d_in[2];
  const float* epW   = (const float*)d_in[4];
  const float* epb   = (const float*)d_in[5];
  const float* Wihf  = (const float*)d_in[6];
  const float* Whhf  = (const float*)d_in[7];
  const float* bihf  = (const float*)d_in[8];
  const float* bhhf  = (const float*)d_in[9];
  const float* Wihb  = (const float*)d_in[10];
  const float* Whhb  = (const float*)d_in[11];
  const float* bihb  = (const float*)d_in[12];
  const float* bhhb  = (const float*)d_in[13];
  const float* fchW  = (const float*)d_in[14];
  const float* fchB  = (const float*)d_in[15];
  const float* fccW  = (const float*)d_in[16];
  const float* fccB  = (const float*)d_in[17];
  const float* dpW   = (const float*)d_in[18];
  const float* dpb   = (const float*)d_in[19];
  const float* Wenc  = (const float*)d_in[20];
  const float* Wdec  = (const float*)d_in[21];
  const float* attnv = (const float*)d_in[22];
  const float* dWih  = (const float*)d_in[23];
  const float* dWhh  = (const float*)d_in[24];
  const float* dbih  = (const float*)d_in[25];
  const float* dbhh  = (const float*)d_in[26];
  const float* valW  = (const float*)d_in[27];
  const float* valb  = (const float*)d_in[28];
  const float* stopW = (const float*)d_in[29];
  const float* stopb = (const float*)d_in[30];
  float* out = (float*)d_out;

  char* ws = (char*)d_ws;
  __hip_bfloat16* enc = (__hip_bfloat16*)(ws + 0);          // 64 MiB
  float* ehT = (float*)(ws + 67108864);                     // 64 MiB
  float* hb  = (float*)(ws + 134217728);                    // 2*2*64*512 f32 = 512 KiB
  float* cf  = hb + 131072;
  float* cb  = cf + 32768;
  float* PQ  = cb + 32768;        // 6*2048
  float* dech = PQ + 12288;
  float* decc = dech + 32768;
  float* adh = decc + 32768;
  float* scores = adh + 32768;
  float* ctx = scores + 32768;
  float* gates = ctx + 65536;
  float* WT = gates + 131072;     // 1024*512
  float* hc = WT + 524288;        // 4
  unsigned* cnt = (unsigned*)(hc + 4);
  float* PQd = PQ + 8192;
  float* hfF = hb + 32768;        // dir0 buf1 (final forward h)
  float* hbF = hb + 98304;        // dir1 buf1 (final backward h)

  hipMemsetAsync(cnt, 0, 4, stream);

  precompute<<<2097, 256, 0, stream>>>(Wenc, Wihf, epW, epb, bihf, bhhf, Wihb, bihb, bhhb,
                                       dWih, dpW, dpb, dbih, dbhh, valW, valb, stopW, stopb,
                                       PQ, WT, hc);

  {
    void* args[] = { (void*)&src, (void*)&smask, (void*)&Whhf, (void*)&Whhb, (void*)&PQ,
                     (void*)&hb, (void*)&cf, (void*)&cb, (void*)&enc, (void*)&cnt };
    hipLaunchCooperativeKernel((void*)enc_coop2, dim3(256), dim3(512), args, 0, stream);
  }

  fc_init<<<256, 256, 0, stream>>>(hfF, hbF, cf, cb, fchW, fchB, fccW, fccB, dech, decc);
  eh_gemm<<<4096, 512, 0, stream>>>(enc, WT, ehT);

  for (int t=0; t<95; ++t){
    dec_attn_heads<<<192, 256, 0, stream>>>(dech, Wdec, adh, ctx, valW, stopW, trg, hc, out, t);
    dec_scores<<<256, 512, 0, stream>>>(adh, ehT, attnv, smask, scores);
    dec_ctx<<<256, 512, 0, stream>>>(scores, enc, ctx);
    dec_gates<<<256, 512, 0, stream>>>(ctx, dech, dWih, dWhh, PQd, trg, gates, t);
    dec_update<<<64, 512, 0, stream>>>(gates, dech, decc);
  }
  dec_attn_heads<<<192, 256, 0, stream>>>(dech, Wdec, adh, ctx, valW, stopW, trg, hc, out, 95);
}

// Round 4
// 28749.792 us; speedup vs baseline: 2.6240x; 1.0433x over previous
//
#include <hip/hip_runtime.h>
#include <hip/hip_bf16.h>

#define AGENT __HIP_MEMORY_SCOPE_AGENT

typedef float f32x4 __attribute__((ext_vector_type(4)));

// B=64 S=512 T=96 E=256 H=512 ENC_DIM=1024 4H=2048

__device__ __forceinline__ float sigm(float x){ return 1.f/(1.f+__expf(-x)); }
__device__ __forceinline__ float tanhfast(float x){
  float ax = fabsf(x);
  float e = __expf(-2.f*ax);
  float r = (1.f-e)/(1.f+e);
  return copysignf(r, x);
}
__device__ __forceinline__ float dot4(float4 a, float4 b){
  return fmaf(a.x,b.x, fmaf(a.y,b.y, fmaf(a.z,b.z, a.w*b.w)));
}

// ---------------- precompute: rank-1 folds, WencT transpose, head consts ----------------
__global__ void __launch_bounds__(256) precompute(
  const float* __restrict__ Wenc,
  const float* __restrict__ Wihf, const float* __restrict__ epW, const float* __restrict__ epb,
  const float* __restrict__ bihf, const float* __restrict__ bhhf,
  const float* __restrict__ Wihb, const float* __restrict__ bihb, const float* __restrict__ bhhb,
  const float* __restrict__ dWih, const float* __restrict__ dpW, const float* __restrict__ dpb,
  const float* __restrict__ dbih, const float* __restrict__ dbhh,
  const float* __restrict__ valW, const float* __restrict__ valb,
  const float* __restrict__ stopW, const float* __restrict__ stopb,
  float* __restrict__ PQ, float* __restrict__ WT, float* __restrict__ hc)
{
  const int idx = blockIdx.x*256 + threadIdx.x;
  if (idx < 524288){
    const int j = idx >> 9, n = idx & 511;
    WT[idx] = Wenc[(size_t)n*1024 + j];
  } else if (idx < 524288 + 6*2048){
    const int q = idx - 524288;
    const int set = q >> 11, j = q & 2047;
    const float* row; const float* vec; float add = 0.f;
    switch(set){
      case 0: row = Wihf + (size_t)j*256; vec = epW; break;
      case 1: row = Wihf + (size_t)j*256; vec = epb; add = bihf[j]+bhhf[j]; break;
      case 2: row = Wihb + (size_t)j*256; vec = epW; break;
      case 3: row = Wihb + (size_t)j*256; vec = epb; add = bihb[j]+bhhb[j]; break;
      case 4: row = dWih + (size_t)j*1280; vec = dpW; break;
      default: row = dWih + (size_t)j*1280; vec = dpb; add = dbih[j]+dbhh[j]; break;
    }
    float a = add;
    for (int e=0;e<256;e++) a = fmaf(row[e], vec[e], a);
    PQ[set*2048 + j] = a;
  } else if (idx < 524288 + 6*2048 + 4){
    const int q = idx - (524288 + 6*2048);
    const float* wrow = (q<2) ? valW : stopW;
    const float* vec  = (q&1) ? dpb : dpW;
    float a = (q&1) ? ((q<2)? valb[0] : stopb[0]) : 0.f;
    for (int e=0;e<256;e++) a = fmaf(wrow[1536+e], vec[e], a);
    hc[q] = a;
  }
}

// ---------------- encoder v3: 8 independent group barriers, coalesced h exchange ----------------
// 256 blocks x 512 threads. bid: dir=bid>>7, half=(bid>>5)&3, us=bid&31.
// Group = (dir,half): 32 blocks, own counter line. h layout: [dir*2+buf][us][half*16+b_l][u_l]
// -> each block stores ONE contiguous 1KB chunk; loads are 1KB-contiguous per us'.
__global__ void __launch_bounds__(512) enc_coop3(
    const float* __restrict__ src, const int* __restrict__ smask,
    const float* __restrict__ Whhf, const float* __restrict__ Whhb,
    const float* __restrict__ PQ,
    float* __restrict__ hb,            // [4][32][1024] f32
    float* __restrict__ hfin,          // [2][64][512] f32
    float* __restrict__ cf, float* __restrict__ cb,
    __hip_bfloat16* __restrict__ enc,  // [64][512][1024]
    unsigned* __restrict__ cnt)        // 8 groups x 32 dwords (128B apart)
{
  __shared__ float hlds[16*516];    // h[b_l][u], pad 4
  __shared__ float4 pr[256];        // k-split partials
  __shared__ float hstage[16*20];   // staged h (recurrence value)
  __shared__ float estage[16*20];   // staged enc value (masked hn)
  const int tid = threadIdx.x;
  const int bid = blockIdx.x;
  const int dir = bid>>7, half = (bid>>5)&3, us = bid&31;
  unsigned* gcnt = cnt + (dir*4 + half)*32;
  const int b_l = tid&15, u_l = (tid>>4)&15, kh = tid>>8;
  const int b = half*16 + b_l, u = us*16 + u_l;
  const float* Whh = dir? Whhb : Whhf;
  const float4* w0 = (const float4*)(Whh + ((size_t)u       )*512 + (size_t)kh*256);
  const float4* w1 = (const float4*)(Whh + ((size_t)u +  512)*512 + (size_t)kh*256);
  const float4* w2 = (const float4*)(Whh + ((size_t)u + 1024)*512 + (size_t)kh*256);
  const float4* w3 = (const float4*)(Whh + ((size_t)u + 1536)*512 + (size_t)kh*256);
  const float* P = PQ + dir*4096; const float* Q = P + 2048;
  const float p0=P[u], p1=P[u+512], p2=P[u+1024], p3=P[u+1536];
  const float q0=Q[u], q1=Q[u+512], q2=Q[u+1024], q3=Q[u+1536];
  float creg = 0.f, hprev = 0.f;
  const f32x4* hb4 = (const f32x4*)hb;

  for (int tt=0; tt<512; ++tt){
    const int t = dir ? (511-tt) : tt;
    if (tt>0){
      if (tid==0){
        while (__hip_atomic_load(gcnt, __ATOMIC_RELAXED, AGENT) < 32u*(unsigned)tt)
          __builtin_amdgcn_s_sleep(1);
      }
      __syncthreads();
      // load h_{tt-1}: 4 fully-coalesced float4 per thread (32KB/block)
      const int base4 = (dir*2 + ((tt-1)&1))*8192 + half*64;
      f32x4 tmp[4];
      #pragma unroll
      for (int i=0;i<4;i++){
        const int f = i*512 + tid;
        const f32x4* p = hb4 + base4 + (f>>6)*256 + (f&63);
        asm volatile("global_load_dwordx4 %0, %1, off sc0 sc1" : "=v"(tmp[i]) : "v"(p) : "memory");
      }
      asm volatile("s_waitcnt vmcnt(0)" ::: "memory");
      __builtin_amdgcn_sched_barrier(0);
      #pragma unroll
      for (int i=0;i<4;i++){
        const int f = i*512 + tid;
        const int usp = f>>6, bl2 = (f>>2)&15, uq = f&3;
        *(f32x4*)(hlds + bl2*516 + usp*16 + uq*4) = tmp[i];
      }
      __syncthreads();
    }
    float a0=0.f,a1=0.f,a2=0.f,a3=0.f;
    if (tt>0){
      const float4* hv = (const float4*)hlds + (size_t)b_l*129 + kh*64;
      #pragma unroll 8
      for (int k=0;k<64;k++){
        const float4 h4 = hv[k];
        a0 += dot4(h4, w0[k]);
        a1 += dot4(h4, w1[k]);
        a2 += dot4(h4, w2[k]);
        a3 += dot4(h4, w3[k]);
      }
    }
    if (kh==1) pr[tid-256] = make_float4(a0,a1,a2,a3);
    __syncthreads();
    if (kh==0){
      const float4 pp = pr[tid];
      const float sx = src[b*512+t]*0.001f;
      const int m = smask[b*512+t];
      const float pi = a0+pp.x + sx*p0 + q0;
      const float pf = a1+pp.y + sx*p1 + q1;
      const float pg = a2+pp.z + sx*p2 + q2;
      const float po = a3+pp.w + sx*p3 + q3;
      const float cn = fmaf(sigm(pf), creg, sigm(pi)*tanhfast(pg));
      const float hn = sigm(po)*tanhfast(cn);
      const float hk = m ? hn : hprev;
      creg = m ? cn : creg;
      hprev = hk;
      hstage[b_l*20 + u_l] = hk;
      estage[b_l*20 + u_l] = m ? hn : 0.f;
    }
    __syncthreads();
    if (tid < 64){
      const int bb = tid>>2, uq = tid&3;
      const f32x4 hv4 = *(const f32x4*)(hstage + bb*20 + uq*4);
      const float4 ev4 = *(const float4*)(estage + bb*20 + uq*4);
      float* dst = hb + ((size_t)(dir*2 + (tt&1))*32 + us)*1024 + half*256 + tid*4;
      asm volatile("global_store_dwordx4 %0, %1, off sc0 sc1" :: "v"(dst), "v"(hv4) : "memory");
      const unsigned lo = (unsigned)__bfloat16_as_ushort(__float2bfloat16(ev4.x))
                        | ((unsigned)__bfloat16_as_ushort(__float2bfloat16(ev4.y))<<16);
      const unsigned hi = (unsigned)__bfloat16_as_ushort(__float2bfloat16(ev4.z))
                        | ((unsigned)__bfloat16_as_ushort(__float2bfloat16(ev4.w))<<16);
      const int bi = half*16 + bb;
      uint2* ep = (uint2*)(enc + ((size_t)(bi*512 + t))*1024 + dir*512 + us*16 + uq*4);
      *ep = make_uint2(lo, hi);
    }
    asm volatile("s_waitcnt vmcnt(0)" ::: "memory");
    __syncthreads();
    if (tid==0) __hip_atomic_fetch_add(gcnt, 1u, __ATOMIC_RELAXED, AGENT);
  }

  if (kh==0){
    hfin[dir*32768 + b*512 + u] = hprev;
    (dir ? cb : cf)[b*512+u] = creg;
  }
}

// ---------------- decoder init ----------------
__global__ void __launch_bounds__(256) fc_init(
  const float* __restrict__ hf0, const float* __restrict__ hb0,
  const float* __restrict__ cf, const float* __restrict__ cb,
  const float* __restrict__ fchW, const float* __restrict__ fchB,
  const float* __restrict__ fccW, const float* __restrict__ fccB,
  float* __restrict__ dech, float* __restrict__ decc)
{
  const int which = blockIdx.x >> 7;
  const int wid = blockIdx.x & 127;
  const int b = threadIdx.x >> 2, ul = threadIdx.x & 3;
  const int u = wid*4 + ul;
  const float* s0 = which ? cf : hf0;
  const float* s1 = which ? cb : hb0;
  const float* W = which ? fccW : fchW;
  float acc = (which ? fccB : fchB)[u];
  const float4* x0 = (const float4*)(s0 + b*512);
  const float4* x1 = (const float4*)(s1 + b*512);
  const float4* wr = (const float4*)(W + (size_t)u*1024);
  #pragma unroll 4
  for (int k=0;k<128;k++) acc += dot4(x0[k], wr[k]);
  #pragma unroll 4
  for (int k=0;k<128;k++) acc += dot4(x1[k], wr[128+k]);
  (which ? decc : dech)[b*512+u] = tanhfast(acc);
}

// ---------------- eh = enc_out @ Wenc.T, stored transposed ehT[b][n][s] ----------------
__global__ void __launch_bounds__(512) eh_gemm(
  const __hip_bfloat16* __restrict__ enc, const float* __restrict__ WT, float* __restrict__ ehT)
{
  const int b = blockIdx.x >> 6;
  const int s = (blockIdx.x & 63)*8 + (threadIdx.x >> 6);
  const int n0 = (threadIdx.x & 63)*8;
  const __hip_bfloat16* ap = enc + ((size_t)(b*512 + s))*1024;
  float c0=0,c1=0,c2=0,c3=0,c4=0,c5=0,c6=0,c7=0;
  for (int k=0;k<1024;k++){
    const float a = __bfloat162float(ap[k]);
    const float4* w = (const float4*)(WT + (size_t)k*512 + n0);
    const float4 wA = w[0], wB = w[1];
    c0 = fmaf(a, wA.x, c0); c1 = fmaf(a, wA.y, c1);
    c2 = fmaf(a, wA.z, c2); c3 = fmaf(a, wA.w, c3);
    c4 = fmaf(a, wB.x, c4); c5 = fmaf(a, wB.y, c5);
    c6 = fmaf(a, wB.z, c6); c7 = fmaf(a, wB.w, c7);
  }
  float* op = ehT + ((size_t)(b*512) + n0)*512 + s;
  op[0]=c0; op[512]=c1; op[1024]=c2; op[1536]=c3;
  op[2048]=c4; op[2560]=c5; op[3072]=c6; op[3584]=c7;
}

// ---------------- decoder step kernels ----------------
__global__ void __launch_bounds__(256) dec_attn_heads(
  const float* __restrict__ dech, const float* __restrict__ Wdec,
  float* __restrict__ adh,
  const float* __restrict__ ctx, const float* __restrict__ valW,
  const float* __restrict__ stopW, const float* __restrict__ trg,
  const float* __restrict__ hc, float* __restrict__ out, int t)
{
  __shared__ float r1[256], r2[256];
  const int bid = blockIdx.x;
  if (bid < 128){
    const int b = threadIdx.x >> 2, jl = threadIdx.x & 3;
    const int j = bid*4 + jl;
    const float4* h4 = (const float4*)(dech + b*512);
    const float4* w4 = (const float4*)(Wdec + (size_t)j*512);
    float acc = 0.f;
    #pragma unroll 4
    for (int k=0;k<128;k++) acc += dot4(h4[k], w4[k]);
    adh[b*512 + j] = acc;
  } else if (t > 0){
    const int b = bid - 128;
    float apv = 0.f, asl = 0.f;
    for (int k = threadIdx.x; k < 1536; k += 256){
      const float f = (k < 512) ? dech[b*512+k] : ctx[b*1024 + (k-512)];
      apv = fmaf(f, valW[k], apv);
      asl = fmaf(f, stopW[k], asl);
    }
    r1[threadIdx.x] = apv; r2[threadIdx.x] = asl;
    __syncthreads();
    for (int off=128; off>0; off>>=1){
      if (threadIdx.x < off){ r1[threadIdx.x]+=r1[threadIdx.x+off]; r2[threadIdx.x]+=r2[threadIdx.x+off]; }
      __syncthreads();
    }
    if (threadIdx.x==0){
      const float x = trg[b*96 + (t-1)]*0.001f;
      out[b*95 + (t-1)] = (r1[0] + x*hc[0] + hc[1]) * 1000.f;
      out[6080 + b*95 + (t-1)] = r2[0] + x*hc[2] + hc[3];
    }
  }
}

__global__ void __launch_bounds__(512) dec_scores(
  const float* __restrict__ adh, const float* __restrict__ ehT,
  const float* __restrict__ attnv, const int* __restrict__ smask,
  float* __restrict__ scores)
{
  const int b = blockIdx.x >> 2;
  const int s0 = (blockIdx.x & 3)*128;
  const int sl = threadIdx.x & 127;
  const int ks = threadIdx.x >> 7;
  __shared__ float dh[512], vv[512];
  __shared__ float part[4][128];
  dh[threadIdx.x] = adh[b*512 + threadIdx.x];
  vv[threadIdx.x] = attnv[threadIdx.x];
  __syncthreads();
  const int s = s0 + sl;
  const float* ehp = ehT + ((size_t)(b*512 + ks*128))*512 + s;
  float acc = 0.f;
  #pragma unroll 4
  for (int i=0;i<128;i++){
    acc = fmaf(vv[ks*128+i], tanhfast(dh[ks*128+i] + ehp[(size_t)i*512]), acc);
  }
  part[ks][sl] = acc;
  __syncthreads();
  if (ks==0){
    const float total = part[0][sl]+part[1][sl]+part[2][sl]+part[3][sl];
    scores[b*512+s] = smask[b*512+s] ? total : -1.0e9f;
  }
}

__global__ void __launch_bounds__(512) dec_ctx(
  const float* __restrict__ scores, const __hip_bfloat16* __restrict__ enc,
  float* __restrict__ ctx)
{
  const int b = blockIdx.x >> 2;
  const int j0 = (blockIdx.x & 3) * 256;
  const int tid = threadIdx.x;
  __shared__ float w[512];
  __shared__ float red[512];
  const float sc = scores[b*512 + tid];
  red[tid] = sc;
  __syncthreads();
  for (int off=256; off>0; off>>=1){
    if (tid < off) red[tid] = fmaxf(red[tid], red[tid+off]);
    __syncthreads();
  }
  const float mx = red[0];
  __syncthreads();
  const float e = __expf(sc - mx);
  w[tid] = e;
  red[tid] = e;
  __syncthreads();
  for (int off=256; off>0; off>>=1){
    if (tid < off) red[tid] += red[tid+off];
    __syncthreads();
  }
  const float Z = red[0];
  __syncthreads();
  const int kh = tid >> 8, jl = tid & 255;
  const __hip_bfloat16* ep = enc + ((size_t)(b*512 + kh*256))*1024 + j0 + jl;
  float acc = 0.f;
  #pragma unroll 4
  for (int s2=0; s2<256; s2++)
    acc = fmaf(w[kh*256+s2], __bfloat162float(ep[(size_t)s2*1024]), acc);
  red[tid] = acc;
  __syncthreads();
  if (kh==0) ctx[b*1024 + j0 + jl] = (red[jl] + red[256+jl]) / Z;
}

__global__ void __launch_bounds__(512) dec_gates(
  const float* __restrict__ ctx, const float* __restrict__ dech,
  const float* __restrict__ dWih, const float* __restrict__ dWhh,
  const float* __restrict__ PQd, const float* __restrict__ trg,
  float* __restrict__ gates, int t)
{
  const int r = blockIdx.x*8 + (threadIdx.x & 7);
  const int b = threadIdx.x >> 3;
  const float x = trg[b*96 + t]*0.001f;
  float acc = fmaf(x, PQd[r], PQd[2048 + r]);
  const float4* c4 = (const float4*)(ctx + b*1024);
  const float4* wc = (const float4*)(dWih + (size_t)r*1280 + 256);
  #pragma unroll 4
  for (int k=0;k<256;k++) acc += dot4(c4[k], wc[k]);
  const float4* h4 = (const float4*)(dech + b*512);
  const float4* wh = (const float4*)(dWhh + (size_t)r*512);
  #pragma unroll 4
  for (int k=0;k<128;k++) acc += dot4(h4[k], wh[k]);
  gates[b*2048 + r] = acc;
}

__global__ void __launch_bounds__(512) dec_update(
  const float* __restrict__ gates, float* __restrict__ dech, float* __restrict__ decc)
{
  const int b = blockIdx.x, u = threadIdx.x;
  const float gi = gates[b*2048 + u];
  const float gf = gates[b*2048 + 512 + u];
  const float gg = gates[b*2048 + 1024 + u];
  const float go = gates[b*2048 + 1536 + u];
  const float c = decc[b*512 + u];
  const float cn = fmaf(sigm(gf), c, sigm(gi)*tanhfast(gg));
  const float hn = sigm(go)*tanhfast(cn);
  decc[b*512+u] = cn;
  dech[b*512+u] = hn;
}

// ---------------- launch ----------------
extern "C" void kernel_launch(void* const* d_in, const int* in_sizes, int n_in,
                              void* d_out, int out_size, void* d_ws, size_t ws_size,
                              hipStream_t stream)
{
  (void)in_sizes; (void)n_in; (void)out_size; (void)ws_size;
  const float* src   = (const float*)d_in[0];
  const int*   smask = (const int*)  d_in[1];
  const float* trg   = (const float*)d_in[2];
  const float* epW   = (const float*)d_in[4];
  const float* epb   = (const float*)d_in[5];
  const float* Wihf  = (const float*)d_in[6];
  const float* Whhf  = (const float*)d_in[7];
  const float* bihf  = (const float*)d_in[8];
  const float* bhhf  = (const float*)d_in[9];
  const float* Wihb  = (const float*)d_in[10];
  const float* Whhb  = (const float*)d_in[11];
  const float* bihb  = (const float*)d_in[12];
  const float* bihb2 = (const float*)d_in[13];
  const float* fchW  = (const float*)d_in[14];
  const float* fchB  = (const float*)d_in[15];
  const float* fccW  = (const float*)d_in[16];
  const float* fccB  = (const float*)d_in[17];
  const float* dpW   = (const float*)d_in[18];
  const float* dpb   = (const float*)d_in[19];
  const float* Wenc  = (const float*)d_in[20];
  const float* Wdec  = (const float*)d_in[21];
  const float* attnv = (const float*)d_in[22];
  const float* dWih  = (const float*)d_in[23];
  const float* dWhh  = (const float*)d_in[24];
  const float* dbih  = (const float*)d_in[25];
  const float* dbhh  = (const float*)d_in[26];
  const float* valW  = (const float*)d_in[27];
  const float* valb  = (const float*)d_in[28];
  const float* stopW = (const float*)d_in[29];
  const float* stopb = (const float*)d_in[30];
  const float* bhhb  = bihb2;
  float* out = (float*)d_out;

  char* ws = (char*)d_ws;
  __hip_bfloat16* enc = (__hip_bfloat16*)(ws + 0);          // 64 MiB
  float* ehT = (float*)(ws + 67108864);                     // 64 MiB
  float* hb   = (float*)(ws + 134217728);   // [4][32][1024] = 512 KiB
  float* hfin = hb + 131072;                // [2][64][512]
  float* cf   = hfin + 65536;
  float* cb   = cf + 32768;
  float* PQ   = cb + 32768;                 // 6*2048
  float* dech = PQ + 12288;
  float* decc = dech + 32768;
  float* adh = decc + 32768;
  float* scores = adh + 32768;
  float* ctx = scores + 32768;
  float* gates = ctx + 65536;
  float* WT = gates + 131072;               // 1024*512
  float* hc = WT + 524288;                  // 4 (+pad)
  unsigned* cnt = (unsigned*)(hc + 32);     // 8 groups x 32 dwords
  float* PQd = PQ + 8192;

  (void)hipMemsetAsync(cnt, 0, 8*32*4, stream);

  precompute<<<2097, 256, 0, stream>>>(Wenc, Wihf, epW, epb, bihf, bhhf, Wihb, bihb, bhhb,
                                       dWih, dpW, dpb, dbih, dbhh, valW, valb, stopW, stopb,
                                       PQ, WT, hc);

  {
    void* args[] = { (void*)&src, (void*)&smask, (void*)&Whhf, (void*)&Whhb, (void*)&PQ,
                     (void*)&hb, (void*)&hfin, (void*)&cf, (void*)&cb, (void*)&enc, (void*)&cnt };
    (void)hipLaunchCooperativeKernel((void*)enc_coop3, dim3(256), dim3(512), args, 0, stream);
  }

  {
    const float* hfF = hfin;
    const float* hbF = hfin + 32768;
    fc_init<<<256, 256, 0, stream>>>(hfF, hbF, cf, cb, fchW, fchB, fccW, fccB, dech, decc);
  }
  eh_gemm<<<4096, 512, 0, stream>>>(enc, WT, ehT);

  for (int t=0; t<95; ++t){
    dec_attn_heads<<<192, 256, 0, stream>>>(dech, Wdec, adh, ctx, valW, stopW, trg, hc, out, t);
    dec_scores<<<256, 512, 0, stream>>>(adh, ehT, attnv, smask, scores);
    dec_ctx<<<256, 512, 0, stream>>>(scores, enc, ctx);
    dec_gates<<<256, 512, 0, stream>>>(ctx, dech, dWih, dWhh, PQd, trg, gates, t);
    dec_update<<<64, 512, 0, stream>>>(gates, dech, decc);
  }
  dec_attn_heads<<<192, 256, 0, stream>>>(dech, Wdec, adh, ctx, valW, stopW, trg, hc, out, 95);
}

// Round 5
// 20294.008 us; speedup vs baseline: 3.7173x; 1.4167x over previous
//
#include <hip/hip_runtime.h>
#include <hip/hip_bf16.h>

#define AGENT __HIP_MEMORY_SCOPE_AGENT

typedef float f32x4 __attribute__((ext_vector_type(4)));
typedef short short8 __attribute__((ext_vector_type(8)));
union V16 { f32x4 f; short8 s; };

// B=64 S=512 T=96 E=256 H=512 ENC_DIM=1024 4H=2048

__device__ __forceinline__ float sigm(float x){ return 1.f/(1.f+__expf(-x)); }
__device__ __forceinline__ float tanhfast(float x){
  float ax = fabsf(x);
  float e = __expf(-2.f*ax);
  float r = (1.f-e)/(1.f+e);
  return copysignf(r, x);
}
__device__ __forceinline__ float dot4(float4 a, float4 b){
  return fmaf(a.x,b.x, fmaf(a.y,b.y, fmaf(a.z,b.z, a.w*b.w)));
}
__device__ __forceinline__ unsigned short bfbits(float x){
  return __bfloat16_as_ushort(__float2bfloat16(x));
}

// ---------------- precompute: rank-1 folds, WencT transpose, head consts ----------------
__global__ void __launch_bounds__(256) precompute(
  const float* __restrict__ Wenc,
  const float* __restrict__ Wihf, const float* __restrict__ epW, const float* __restrict__ epb,
  const float* __restrict__ bihf, const float* __restrict__ bhhf,
  const float* __restrict__ Wihb, const float* __restrict__ bihb, const float* __restrict__ bhhb,
  const float* __restrict__ dWih, const float* __restrict__ dpW, const float* __restrict__ dpb,
  const float* __restrict__ dbih, const float* __restrict__ dbhh,
  const float* __restrict__ valW, const float* __restrict__ valb,
  const float* __restrict__ stopW, const float* __restrict__ stopb,
  float* __restrict__ PQ, float* __restrict__ WT, float* __restrict__ hc)
{
  const int idx = blockIdx.x*256 + threadIdx.x;
  if (idx < 524288){
    const int j = idx >> 9, n = idx & 511;
    WT[idx] = Wenc[(size_t)n*1024 + j];
  } else if (idx < 524288 + 6*2048){
    const int q = idx - 524288;
    const int set = q >> 11, j = q & 2047;
    const float* row; const float* vec; float add = 0.f;
    switch(set){
      case 0: row = Wihf + (size_t)j*256; vec = epW; break;
      case 1: row = Wihf + (size_t)j*256; vec = epb; add = bihf[j]+bhhf[j]; break;
      case 2: row = Wihb + (size_t)j*256; vec = epW; break;
      case 3: row = Wihb + (size_t)j*256; vec = epb; add = bihb[j]+bhhb[j]; break;
      case 4: row = dWih + (size_t)j*1280; vec = dpW; break;
      default: row = dWih + (size_t)j*1280; vec = dpb; add = dbih[j]+dbhh[j]; break;
    }
    float a = add;
    for (int e=0;e<256;e++) a = fmaf(row[e], vec[e], a);
    PQ[set*2048 + j] = a;
  } else if (idx < 524288 + 6*2048 + 4){
    const int q = idx - (524288 + 6*2048);
    const float* wrow = (q<2) ? valW : stopW;
    const float* vec  = (q&1) ? dpb : dpW;
    float a = (q&1) ? ((q<2)? valb[0] : stopb[0]) : 0.f;
    for (int e=0;e<256;e++) a = fmaf(wrow[1536+e], vec[e], a);
    hc[q] = a;
  }
}

// ---------------- Whh -> bf16 [2][2048][512] ----------------
__global__ void __launch_bounds__(512) wconv(
  const float* __restrict__ Whhf, const float* __restrict__ Whhb, unsigned short* __restrict__ Wbf)
{
  const int i = blockIdx.x*512 + threadIdx.x;
  const float v = (i < 1048576) ? Whhf[i] : Whhb[i-1048576];
  Wbf[i] = bfbits(v);
}

// ---------------- encoder v4: MFMA recurrence, weights resident in VGPRs ----------------
// 256 blocks x 512 threads. bid: dir=bid>>7, bhalf=(bid>>5)&3 (16 batches), us=bid&31 (16 units).
// Wave w = (nt=w&3 gate, kh=w>>2 K-half): B-panel 16 cols x 256 k bf16 in 32 VGPRs (loaded once).
// Per step: load H[16b x 512u] bf16 (16KB) from L3 -> XOR-swizzled LDS -> 8 ds_read+MFMA per wave.
// Group barrier (dir,bhalf): 8 groups x 32 blocks, own counter line, relaxed agent atomics.
__global__ void __launch_bounds__(512) enc_mfma(
    const float* __restrict__ src, const int* __restrict__ smask,
    const unsigned short* __restrict__ Wbf,   // [2][2048][512] bf16
    const float* __restrict__ PQ,
    unsigned short* __restrict__ hbuf,        // [2dir][2par][64][512] bf16
    float* __restrict__ hfin,                 // [2][64][512] f32
    float* __restrict__ cf, float* __restrict__ cb,
    __hip_bfloat16* __restrict__ enc,         // [64][512][1024] bf16
    unsigned* __restrict__ cnt)               // 8 groups x 32 dwords
{
  __shared__ float hlds[16*256];              // 16 KB: row b_l, 64 chunks of 16B, chunk XOR (row&7)
  __shared__ float red[4*64*4];               // 4 KB kh-reduction
  __shared__ float gbuf[4*256];               // 4 KB gates [nt][b_l][u_l]
  __shared__ alignas(16) unsigned short hstage[256];
  __shared__ alignas(16) unsigned short estage[256];

  const int tid = threadIdx.x;
  const int bid = blockIdx.x;
  const int dir = bid>>7, bhalf = (bid>>5)&3, us = bid&31;
  const int b0 = bhalf*16;
  unsigned* gcnt = cnt + (dir*4 + bhalf)*32;
  const int wv = tid>>6, lane = tid&63;
  const int nt = wv&3, kh = wv>>2;
  const int rowb = lane&15;

  // resident B-panel: gate nt, unit cols us*16+(lane&15), k = kh*256 + kt*32 + (lane>>4)*8
  short8 bfr[8];
  {
    const int g = nt*512 + us*16 + (lane&15);
    const unsigned short* wp = Wbf + ((size_t)dir*2048 + g)*512 + kh*256 + (lane>>4)*8;
    #pragma unroll
    for (int kt=0;kt<8;kt++) bfr[kt] = *(const short8*)(wp + kt*32);
  }

  // cell-thread constants (tid<256): b_l=tid>>4, u_l=tid&15
  float p0=0,p1=0,p2=0,p3=0,q0=0,q1=0,q2=0,q3=0;
  float creg = 0.f, hprev = 0.f;
  int bg = 0, ug = 0;
  if (tid < 256){
    bg = b0 + (tid>>4);
    ug = us*16 + (tid&15);
    const float* P = PQ + dir*4096; const float* Q = P + 2048;
    p0=P[ug]; p1=P[ug+512]; p2=P[ug+1024]; p3=P[ug+1536];
    q0=Q[ug]; q1=Q[ug+512]; q2=Q[ug+1024]; q3=Q[ug+1536];
  }

  for (int tt=0; tt<512; ++tt){
    const int t = dir ? (511-tt) : tt;
    if (tt>0){
      if (tid==0){
        while (__hip_atomic_load(gcnt, __ATOMIC_RELAXED, AGENT) < 32u*(unsigned)tt)
          __builtin_amdgcn_s_sleep(1);
      }
      __syncthreads();
      // stage H_{tt-1}: 1024 x 16B chunks, coalesced, L2-bypassed
      const int par = (tt-1)&1;
      f32x4 tmp0, tmp1;
      {
        const int f0 = tid, f1 = 512 + tid;
        const unsigned short* g0 = hbuf + (((size_t)(dir*2+par)*64 + b0 + (f0>>6))<<9) + (f0&63)*8;
        const unsigned short* g1 = hbuf + (((size_t)(dir*2+par)*64 + b0 + (f1>>6))<<9) + (f1&63)*8;
        asm volatile("global_load_dwordx4 %0, %1, off sc0 sc1" : "=v"(tmp0) : "v"(g0) : "memory");
        asm volatile("global_load_dwordx4 %0, %1, off sc0 sc1" : "=v"(tmp1) : "v"(g1) : "memory");
      }
      asm volatile("s_waitcnt vmcnt(0)" ::: "memory");
      __builtin_amdgcn_sched_barrier(0);
      {
        const int r0 = tid>>6, c0 = tid&63;
        *(f32x4*)&hlds[r0*256 + ((c0 ^ (r0&7))<<2)] = tmp0;
        const int r1 = (512+tid)>>6, c1 = tid&63;
        *(f32x4*)&hlds[r1*256 + ((c1 ^ (r1&7))<<2)] = tmp1;
      }
      __syncthreads();
    }

    // MFMA: gates[16b x 16cols] for gate nt, K-half kh
    f32x4 acc = {0.f,0.f,0.f,0.f};
    if (tt>0){
      #pragma unroll
      for (int kt=0; kt<8; ++kt){
        const int ch = (kh*8 + kt)*4 + (lane>>4);
        V16 a; a.f = *(const f32x4*)&hlds[rowb*256 + ((ch ^ (rowb&7))<<2)];
        acc = __builtin_amdgcn_mfma_f32_16x16x32_bf16(a.s, bfr[kt], acc, 0, 0, 0);
      }
    }
    if (kh==1) *(f32x4*)&red[(nt*64+lane)*4] = acc;
    __syncthreads();
    if (kh==0){
      const f32x4 o = *(const f32x4*)&red[(nt*64+lane)*4];
      #pragma unroll
      for (int i=0;i<4;i++){
        const int r = (lane>>4)*4 + i, c = lane&15;
        gbuf[nt*256 + r*16 + c] = acc[i] + o[i];
      }
    }
    __syncthreads();

    // LSTM cell update on 256 threads; h/enc staged to LDS
    if (tid < 256){
      const float sx = src[bg*512+t]*0.001f;
      const int m = smask[bg*512+t];
      const float gi = gbuf[0*256+tid] + sx*p0 + q0;
      const float gf = gbuf[1*256+tid] + sx*p1 + q1;
      const float gg = gbuf[2*256+tid] + sx*p2 + q2;
      const float go = gbuf[3*256+tid] + sx*p3 + q3;
      const float cn = fmaf(sigm(gf), creg, sigm(gi)*tanhfast(gg));
      const float hn = sigm(go)*tanhfast(cn);
      const float hk = m ? hn : hprev;
      creg = m ? cn : creg;
      hprev = hk;
      hstage[tid] = bfbits(hk);
      estage[tid] = bfbits(m ? hn : 0.f);
    }
    __syncthreads();
    if (tid < 32){
      const int row = tid>>1, hw = tid&1;
      const f32x4 v = *(const f32x4*)(hstage + row*16 + hw*8);
      unsigned short* dst = hbuf + (((size_t)(dir*2+(tt&1))*64 + b0 + row)<<9) + us*16 + hw*8;
      asm volatile("global_store_dwordx4 %0, %1, off sc0 sc1" :: "v"(dst), "v"(v) : "memory");
    } else if (tid < 64){
      const int j = tid-32, row = j>>1, hw = j&1;
      const f32x4 v = *(const f32x4*)(estage + row*16 + hw*8);
      *(f32x4*)((unsigned short*)enc + ((size_t)((b0+row)*512 + t))*1024 + dir*512 + us*16 + hw*8) = v;
    }
    asm volatile("s_waitcnt vmcnt(0)" ::: "memory");
    __syncthreads();
    if (tid==0) __hip_atomic_fetch_add(gcnt, 1u, __ATOMIC_RELAXED, AGENT);
  }

  if (tid < 256){
    hfin[dir*32768 + bg*512 + ug] = hprev;
    (dir ? cb : cf)[bg*512 + ug] = creg;
  }
}

// ---------------- decoder init ----------------
__global__ void __launch_bounds__(256) fc_init(
  const float* __restrict__ hf0, const float* __restrict__ hb0,
  const float* __restrict__ cf, const float* __restrict__ cb,
  const float* __restrict__ fchW, const float* __restrict__ fchB,
  const float* __restrict__ fccW, const float* __restrict__ fccB,
  float* __restrict__ dech, float* __restrict__ decc)
{
  const int which = blockIdx.x >> 7;
  const int wid = blockIdx.x & 127;
  const int b = threadIdx.x >> 2, ul = threadIdx.x & 3;
  const int u = wid*4 + ul;
  const float* s0 = which ? cf : hf0;
  const float* s1 = which ? cb : hb0;
  const float* W = which ? fccW : fchW;
  float acc = (which ? fccB : fchB)[u];
  const float4* x0 = (const float4*)(s0 + b*512);
  const float4* x1 = (const float4*)(s1 + b*512);
  const float4* wr = (const float4*)(W + (size_t)u*1024);
  #pragma unroll 4
  for (int k=0;k<128;k++) acc += dot4(x0[k], wr[k]);
  #pragma unroll 4
  for (int k=0;k<128;k++) acc += dot4(x1[k], wr[128+k]);
  (which ? decc : dech)[b*512+u] = tanhfast(acc);
}

// ---------------- eh = enc_out @ Wenc.T, stored transposed ehT[b][n][s] ----------------
__global__ void __launch_bounds__(512) eh_gemm(
  const __hip_bfloat16* __restrict__ enc, const float* __restrict__ WT, float* __restrict__ ehT)
{
  const int b = blockIdx.x >> 6;
  const int s = (blockIdx.x & 63)*8 + (threadIdx.x >> 6);
  const int n0 = (threadIdx.x & 63)*8;
  const __hip_bfloat16* ap = enc + ((size_t)(b*512 + s))*1024;
  float c0=0,c1=0,c2=0,c3=0,c4=0,c5=0,c6=0,c7=0;
  for (int k=0;k<1024;k++){
    const float a = __bfloat162float(ap[k]);
    const float4* w = (const float4*)(WT + (size_t)k*512 + n0);
    const float4 wA = w[0], wB = w[1];
    c0 = fmaf(a, wA.x, c0); c1 = fmaf(a, wA.y, c1);
    c2 = fmaf(a, wA.z, c2); c3 = fmaf(a, wA.w, c3);
    c4 = fmaf(a, wB.x, c4); c5 = fmaf(a, wB.y, c5);
    c6 = fmaf(a, wB.z, c6); c7 = fmaf(a, wB.w, c7);
  }
  float* op = ehT + ((size_t)(b*512) + n0)*512 + s;
  op[0]=c0; op[512]=c1; op[1024]=c2; op[1536]=c3;
  op[2048]=c4; op[2560]=c5; op[3072]=c6; op[3584]=c7;
}

// ---------------- decoder step kernels (unchanged this round) ----------------
__global__ void __launch_bounds__(256) dec_attn_heads(
  const float* __restrict__ dech, const float* __restrict__ Wdec,
  float* __restrict__ adh,
  const float* __restrict__ ctx, const float* __restrict__ valW,
  const float* __restrict__ stopW, const float* __restrict__ trg,
  const float* __restrict__ hc, float* __restrict__ out, int t)
{
  __shared__ float r1[256], r2[256];
  const int bid = blockIdx.x;
  if (bid < 128){
    const int b = threadIdx.x >> 2, jl = threadIdx.x & 3;
    const int j = bid*4 + jl;
    const float4* h4 = (const float4*)(dech + b*512);
    const float4* w4 = (const float4*)(Wdec + (size_t)j*512);
    float acc = 0.f;
    #pragma unroll 4
    for (int k=0;k<128;k++) acc += dot4(h4[k], w4[k]);
    adh[b*512 + j] = acc;
  } else if (t > 0){
    const int b = bid - 128;
    float apv = 0.f, asl = 0.f;
    for (int k = threadIdx.x; k < 1536; k += 256){
      const float f = (k < 512) ? dech[b*512+k] : ctx[b*1024 + (k-512)];
      apv = fmaf(f, valW[k], apv);
      asl = fmaf(f, stopW[k], asl);
    }
    r1[threadIdx.x] = apv; r2[threadIdx.x] = asl;
    __syncthreads();
    for (int off=128; off>0; off>>=1){
      if (threadIdx.x < off){ r1[threadIdx.x]+=r1[threadIdx.x+off]; r2[threadIdx.x]+=r2[threadIdx.x+off]; }
      __syncthreads();
    }
    if (threadIdx.x==0){
      const float x = trg[b*96 + (t-1)]*0.001f;
      out[b*95 + (t-1)] = (r1[0] + x*hc[0] + hc[1]) * 1000.f;
      out[6080 + b*95 + (t-1)] = r2[0] + x*hc[2] + hc[3];
    }
  }
}

__global__ void __launch_bounds__(512) dec_scores(
  const float* __restrict__ adh, const float* __restrict__ ehT,
  const float* __restrict__ attnv, const int* __restrict__ smask,
  float* __restrict__ scores)
{
  const int b = blockIdx.x >> 2;
  const int s0 = (blockIdx.x & 3)*128;
  const int sl = threadIdx.x & 127;
  const int ks = threadIdx.x >> 7;
  __shared__ float dh[512], vv[512];
  __shared__ float part[4][128];
  dh[threadIdx.x] = adh[b*512 + threadIdx.x];
  vv[threadIdx.x] = attnv[threadIdx.x];
  __syncthreads();
  const int s = s0 + sl;
  const float* ehp = ehT + ((size_t)(b*512 + ks*128))*512 + s;
  float acc = 0.f;
  #pragma unroll 4
  for (int i=0;i<128;i++){
    acc = fmaf(vv[ks*128+i], tanhfast(dh[ks*128+i] + ehp[(size_t)i*512]), acc);
  }
  part[ks][sl] = acc;
  __syncthreads();
  if (ks==0){
    const float total = part[0][sl]+part[1][sl]+part[2][sl]+part[3][sl];
    scores[b*512+s] = smask[b*512+s] ? total : -1.0e9f;
  }
}

__global__ void __launch_bounds__(512) dec_ctx(
  const float* __restrict__ scores, const __hip_bfloat16* __restrict__ enc,
  float* __restrict__ ctx)
{
  const int b = blockIdx.x >> 2;
  const int j0 = (blockIdx.x & 3) * 256;
  const int tid = threadIdx.x;
  __shared__ float w[512];
  __shared__ float red[512];
  const float sc = scores[b*512 + tid];
  red[tid] = sc;
  __syncthreads();
  for (int off=256; off>0; off>>=1){
    if (tid < off) red[tid] = fmaxf(red[tid], red[tid+off]);
    __syncthreads();
  }
  const float mx = red[0];
  __syncthreads();
  const float e = __expf(sc - mx);
  w[tid] = e;
  red[tid] = e;
  __syncthreads();
  for (int off=256; off>0; off>>=1){
    if (tid < off) red[tid] += red[tid+off];
    __syncthreads();
  }
  const float Z = red[0];
  __syncthreads();
  const int kh = tid >> 8, jl = tid & 255;
  const __hip_bfloat16* ep = enc + ((size_t)(b*512 + kh*256))*1024 + j0 + jl;
  float acc = 0.f;
  #pragma unroll 4
  for (int s2=0; s2<256; s2++)
    acc = fmaf(w[kh*256+s2], __bfloat162float(ep[(size_t)s2*1024]), acc);
  red[tid] = acc;
  __syncthreads();
  if (kh==0) ctx[b*1024 + j0 + jl] = (red[jl] + red[256+jl]) / Z;
}

__global__ void __launch_bounds__(512) dec_gates(
  const float* __restrict__ ctx, const float* __restrict__ dech,
  const float* __restrict__ dWih, const float* __restrict__ dWhh,
  const float* __restrict__ PQd, const float* __restrict__ trg,
  float* __restrict__ gates, int t)
{
  const int r = blockIdx.x*8 + (threadIdx.x & 7);
  const int b = threadIdx.x >> 3;
  const float x = trg[b*96 + t]*0.001f;
  float acc = fmaf(x, PQd[r], PQd[2048 + r]);
  const float4* c4 = (const float4*)(ctx + b*1024);
  const float4* wc = (const float4*)(dWih + (size_t)r*1280 + 256);
  #pragma unroll 4
  for (int k=0;k<256;k++) acc += dot4(c4[k], wc[k]);
  const float4* h4 = (const float4*)(dech + b*512);
  const float4* wh = (const float4*)(dWhh + (size_t)r*512);
  #pragma unroll 4
  for (int k=0;k<128;k++) acc += dot4(h4[k], wh[k]);
  gates[b*2048 + r] = acc;
}

__global__ void __launch_bounds__(512) dec_update(
  const float* __restrict__ gates, float* __restrict__ dech, float* __restrict__ decc)
{
  const int b = blockIdx.x, u = threadIdx.x;
  const float gi = gates[b*2048 + u];
  const float gf = gates[b*2048 + 512 + u];
  const float gg = gates[b*2048 + 1024 + u];
  const float go = gates[b*2048 + 1536 + u];
  const float c = decc[b*512 + u];
  const float cn = fmaf(sigm(gf), c, sigm(gi)*tanhfast(gg));
  const float hn = sigm(go)*tanhfast(cn);
  decc[b*512+u] = cn;
  dech[b*512+u] = hn;
}

// ---------------- launch ----------------
extern "C" void kernel_launch(void* const* d_in, const int* in_sizes, int n_in,
                              void* d_out, int out_size, void* d_ws, size_t ws_size,
                              hipStream_t stream)
{
  (void)in_sizes; (void)n_in; (void)out_size; (void)ws_size;
  const float* src   = (const float*)d_in[0];
  const int*   smask = (const int*)  d_in[1];
  const float* trg   = (const float*)d_in[2];
  const float* epW   = (const float*)d_in[4];
  const float* epb   = (const float*)d_in[5];
  const float* Wihf  = (const float*)d_in[6];
  const float* Whhf  = (const float*)d_in[7];
  const float* bihf  = (const float*)d_in[8];
  const float* bhhf  = (const float*)d_in[9];
  const float* Wihb  = (const float*)d_in[10];
  const float* Whhb  = (const float*)d_in[11];
  const float* bihb  = (const float*)d_in[12];
  const float* bhhb  = (const float*)d_in[13];
  const float* fchW  = (const float*)d_in[14];
  const float* fchB  = (const float*)d_in[15];
  const float* fccW  = (const float*)d_in[16];
  const float* fccB  = (const float*)d_in[17];
  const float* dpW   = (const float*)d_in[18];
  const float* dpb   = (const float*)d_in[19];
  const float* Wenc  = (const float*)d_in[20];
  const float* Wdec  = (const float*)d_in[21];
  const float* attnv = (const float*)d_in[22];
  const float* dWih  = (const float*)d_in[23];
  const float* dWhh  = (const float*)d_in[24];
  const float* dbih  = (const float*)d_in[25];
  const float* dbhh  = (const float*)d_in[26];
  const float* valW  = (const float*)d_in[27];
  const float* valb  = (const float*)d_in[28];
  const float* stopW = (const float*)d_in[29];
  const float* stopb = (const float*)d_in[30];
  float* out = (float*)d_out;

  char* ws = (char*)d_ws;
  __hip_bfloat16* enc = (__hip_bfloat16*)(ws + 0);          // 64 MiB
  float* ehT = (float*)(ws + 67108864);                     // 64 MiB
  unsigned short* hbuf = (unsigned short*)(ws + 134217728); // [2][2][64][512] bf16 = 256 KiB
  unsigned short* Wbf  = hbuf + 131072;                     // [2][2048][512] bf16 = 4 MiB
  float* hfin = (float*)(Wbf + 2097152);                    // [2][64][512] f32
  float* cf   = hfin + 65536;
  float* cb   = cf + 32768;
  float* PQ   = cb + 32768;                 // 6*2048
  float* dech = PQ + 12288;
  float* decc = dech + 32768;
  float* adh = decc + 32768;
  float* scores = adh + 32768;
  float* ctx = scores + 32768;
  float* gates = ctx + 65536;
  float* WT = gates + 131072;               // 1024*512
  float* hc = WT + 524288;                  // 4 (+pad)
  unsigned* cnt = (unsigned*)(hc + 32);     // 8 groups x 32 dwords
  float* PQd = PQ + 8192;

  (void)hipMemsetAsync(cnt, 0, 8*32*4, stream);

  precompute<<<2097, 256, 0, stream>>>(Wenc, Wihf, epW, epb, bihf, bhhf, Wihb, bihb, bhhb,
                                       dWih, dpW, dpb, dbih, dbhh, valW, valb, stopW, stopb,
                                       PQ, WT, hc);
  wconv<<<4096, 512, 0, stream>>>(Whhf, Whhb, Wbf);

  {
    void* args[] = { (void*)&src, (void*)&smask, (void*)&Wbf, (void*)&PQ,
                     (void*)&hbuf, (void*)&hfin, (void*)&cf, (void*)&cb, (void*)&enc, (void*)&cnt };
    (void)hipLaunchCooperativeKernel((void*)enc_mfma, dim3(256), dim3(512), args, 0, stream);
  }

  {
    const float* hfF = hfin;
    const float* hbF = hfin + 32768;
    fc_init<<<256, 256, 0, stream>>>(hfF, hbF, cf, cb, fchW, fchB, fccW, fccB, dech, decc);
  }
  eh_gemm<<<4096, 512, 0, stream>>>(enc, WT, ehT);

  for (int t=0; t<95; ++t){
    dec_attn_heads<<<192, 256, 0, stream>>>(dech, Wdec, adh, ctx, valW, stopW, trg, hc, out, t);
    dec_scores<<<256, 512, 0, stream>>>(adh, ehT, attnv, smask, scores);
    dec_ctx<<<256, 512, 0, stream>>>(scores, enc, ctx);
    dec_gates<<<256, 512, 0, stream>>>(ctx, dech, dWih, dWhh, PQd, trg, gates, t);
    dec_update<<<64, 512, 0, stream>>>(gates, dech, decc);
  }
  dec_attn_heads<<<192, 256, 0, stream>>>(dech, Wdec, adh, ctx, valW, stopW, trg, hc, out, 95);
}

// Round 6
// 14582.869 us; speedup vs baseline: 5.1731x; 1.3916x over previous
//
#include <hip/hip_runtime.h>
#include <hip/hip_bf16.h>

#define AGENT __HIP_MEMORY_SCOPE_AGENT

typedef float f32x4 __attribute__((ext_vector_type(4)));
typedef short short8 __attribute__((ext_vector_type(8)));
union V16 { f32x4 f; short8 s; };

// B=64 S=512 T=96 E=256 H=512 ENC_DIM=1024 4H=2048

__device__ __forceinline__ float sigm(float x){ return 1.f/(1.f+__expf(-x)); }
__device__ __forceinline__ float tanhfast(float x){
  float ax = fabsf(x);
  float e = __expf(-2.f*ax);
  float r = (1.f-e)/(1.f+e);
  return copysignf(r, x);
}
__device__ __forceinline__ float dot4(float4 a, float4 b){
  return fmaf(a.x,b.x, fmaf(a.y,b.y, fmaf(a.z,b.z, a.w*b.w)));
}
__device__ __forceinline__ unsigned short bfbits(float x){
  return __bfloat16_as_ushort(__float2bfloat16(x));
}
__device__ __forceinline__ float bfu2f(unsigned short u){
  union{unsigned v; float f;} x; x.v = ((unsigned)u)<<16; return x.f;
}

// ---------------- precompute: rank-1 folds, WencT transpose, head consts ----------------
__global__ void __launch_bounds__(256) precompute(
  const float* __restrict__ Wenc,
  const float* __restrict__ Wihf, const float* __restrict__ epW, const float* __restrict__ epb,
  const float* __restrict__ bihf, const float* __restrict__ bhhf,
  const float* __restrict__ Wihb, const float* __restrict__ bihb, const float* __restrict__ bhhb,
  const float* __restrict__ dWih, const float* __restrict__ dpW, const float* __restrict__ dpb,
  const float* __restrict__ dbih, const float* __restrict__ dbhh,
  const float* __restrict__ valW, const float* __restrict__ valb,
  const float* __restrict__ stopW, const float* __restrict__ stopb,
  float* __restrict__ PQ, float* __restrict__ WT, float* __restrict__ hc)
{
  const int idx = blockIdx.x*256 + threadIdx.x;
  if (idx < 524288){
    const int j = idx >> 9, n = idx & 511;
    WT[idx] = Wenc[(size_t)n*1024 + j];
  } else if (idx < 524288 + 6*2048){
    const int q = idx - 524288;
    const int set = q >> 11, j = q & 2047;
    const float* row; const float* vec; float add = 0.f;
    switch(set){
      case 0: row = Wihf + (size_t)j*256; vec = epW; break;
      case 1: row = Wihf + (size_t)j*256; vec = epb; add = bihf[j]+bhhf[j]; break;
      case 2: row = Wihb + (size_t)j*256; vec = epW; break;
      case 3: row = Wihb + (size_t)j*256; vec = epb; add = bihb[j]+bhhb[j]; break;
      case 4: row = dWih + (size_t)j*1280; vec = dpW; break;
      default: row = dWih + (size_t)j*1280; vec = dpb; add = dbih[j]+dbhh[j]; break;
    }
    float a = add;
    for (int e=0;e<256;e++) a = fmaf(row[e], vec[e], a);
    PQ[set*2048 + j] = a;
  } else if (idx < 524288 + 6*2048 + 4){
    const int q = idx - (524288 + 6*2048);
    const float* wrow = (q<2) ? valW : stopW;
    const float* vec  = (q&1) ? dpb : dpW;
    float a = (q&1) ? ((q<2)? valb[0] : stopb[0]) : 0.f;
    for (int e=0;e<256;e++) a = fmaf(wrow[1536+e], vec[e], a);
    hc[q] = a;
  }
}

// ---------------- weight converts: enc Whh, decoder Wcat=[dWih-ctx|dWhh], WdecT ----------------
__global__ void __launch_bounds__(512) wconv(
  const float* __restrict__ Whhf, const float* __restrict__ Whhb,
  const float* __restrict__ dWih, const float* __restrict__ dWhh,
  const float* __restrict__ Wdec,
  unsigned short* __restrict__ Wbf, unsigned short* __restrict__ Wcat,
  unsigned short* __restrict__ WdecT)
{
  const int i = blockIdx.x*512 + threadIdx.x;
  if (i < 2097152){
    const float v = (i < 1048576) ? Whhf[i] : Whhb[i-1048576];
    Wbf[i] = bfbits(v);
  } else if (i < 2097152+3145728){
    const int q = i - 2097152;
    const int r = q/1536, k = q - r*1536;
    const float v = (k<1024) ? dWih[(size_t)r*1280 + 256 + k] : dWhh[(size_t)r*512 + (k-1024)];
    Wcat[q] = bfbits(v);
  } else {
    const int q = i - (2097152+3145728);
    const int u = q>>9, n = q&511;
    WdecT[q] = bfbits(Wdec[n*512+u]);
  }
}

// ---------------- encoder v4 (unchanged from round 5) ----------------
__global__ void __launch_bounds__(512) enc_mfma(
    const float* __restrict__ src, const int* __restrict__ smask,
    const unsigned short* __restrict__ Wbf,
    const float* __restrict__ PQ,
    unsigned short* __restrict__ hbuf,
    float* __restrict__ hfin,
    float* __restrict__ cf, float* __restrict__ cb,
    __hip_bfloat16* __restrict__ enc,
    unsigned* __restrict__ cnt)
{
  __shared__ float hlds[16*256];
  __shared__ float red[4*64*4];
  __shared__ float gbuf[4*256];
  __shared__ alignas(16) unsigned short hstage[256];
  __shared__ alignas(16) unsigned short estage[256];

  const int tid = threadIdx.x;
  const int bid = blockIdx.x;
  const int dir = bid>>7, bhalf = (bid>>5)&3, us = bid&31;
  const int b0 = bhalf*16;
  unsigned* gcnt = cnt + (dir*4 + bhalf)*32;
  const int wv = tid>>6, lane = tid&63;
  const int nt = wv&3, kh = wv>>2;
  const int rowb = lane&15;

  short8 bfr[8];
  {
    const int g = nt*512 + us*16 + (lane&15);
    const unsigned short* wp = Wbf + ((size_t)dir*2048 + g)*512 + kh*256 + (lane>>4)*8;
    #pragma unroll
    for (int kt=0;kt<8;kt++) bfr[kt] = *(const short8*)(wp + kt*32);
  }

  float p0=0,p1=0,p2=0,p3=0,q0=0,q1=0,q2=0,q3=0;
  float creg = 0.f, hprev = 0.f;
  int bg = 0, ug = 0;
  if (tid < 256){
    bg = b0 + (tid>>4);
    ug = us*16 + (tid&15);
    const float* P = PQ + dir*4096; const float* Q = P + 2048;
    p0=P[ug]; p1=P[ug+512]; p2=P[ug+1024]; p3=P[ug+1536];
    q0=Q[ug]; q1=Q[ug+512]; q2=Q[ug+1024]; q3=Q[ug+1536];
  }

  for (int tt=0; tt<512; ++tt){
    const int t = dir ? (511-tt) : tt;
    if (tt>0){
      if (tid==0){
        while (__hip_atomic_load(gcnt, __ATOMIC_RELAXED, AGENT) < 32u*(unsigned)tt)
          __builtin_amdgcn_s_sleep(1);
      }
      __syncthreads();
      const int par = (tt-1)&1;
      f32x4 tmp0, tmp1;
      {
        const int f0 = tid, f1 = 512 + tid;
        const unsigned short* g0 = hbuf + (((size_t)(dir*2+par)*64 + b0 + (f0>>6))<<9) + (f0&63)*8;
        const unsigned short* g1 = hbuf + (((size_t)(dir*2+par)*64 + b0 + (f1>>6))<<9) + (f1&63)*8;
        asm volatile("global_load_dwordx4 %0, %1, off sc0 sc1" : "=v"(tmp0) : "v"(g0) : "memory");
        asm volatile("global_load_dwordx4 %0, %1, off sc0 sc1" : "=v"(tmp1) : "v"(g1) : "memory");
      }
      asm volatile("s_waitcnt vmcnt(0)" ::: "memory");
      __builtin_amdgcn_sched_barrier(0);
      {
        const int r0 = tid>>6, c0 = tid&63;
        *(f32x4*)&hlds[r0*256 + ((c0 ^ (r0&7))<<2)] = tmp0;
        const int r1 = (512+tid)>>6, c1 = tid&63;
        *(f32x4*)&hlds[r1*256 + ((c1 ^ (r1&7))<<2)] = tmp1;
      }
      __syncthreads();
    }

    f32x4 acc = {0.f,0.f,0.f,0.f};
    if (tt>0){
      #pragma unroll
      for (int kt=0; kt<8; ++kt){
        const int ch = (kh*8 + kt)*4 + (lane>>4);
        V16 a; a.f = *(const f32x4*)&hlds[rowb*256 + ((ch ^ (rowb&7))<<2)];
        acc = __builtin_amdgcn_mfma_f32_16x16x32_bf16(a.s, bfr[kt], acc, 0, 0, 0);
      }
    }
    if (kh==1) *(f32x4*)&red[(nt*64+lane)*4] = acc;
    __syncthreads();
    if (kh==0){
      const f32x4 o = *(const f32x4*)&red[(nt*64+lane)*4];
      #pragma unroll
      for (int i=0;i<4;i++){
        const int r = (lane>>4)*4 + i, c = lane&15;
        gbuf[nt*256 + r*16 + c] = acc[i] + o[i];
      }
    }
    __syncthreads();

    if (tid < 256){
      const float sx = src[bg*512+t]*0.001f;
      const int m = smask[bg*512+t];
      const float gi = gbuf[0*256+tid] + sx*p0 + q0;
      const float gf = gbuf[1*256+tid] + sx*p1 + q1;
      const float gg = gbuf[2*256+tid] + sx*p2 + q2;
      const float go = gbuf[3*256+tid] + sx*p3 + q3;
      const float cn = fmaf(sigm(gf), creg, sigm(gi)*tanhfast(gg));
      const float hn = sigm(go)*tanhfast(cn);
      const float hk = m ? hn : hprev;
      creg = m ? cn : creg;
      hprev = hk;
      hstage[tid] = bfbits(hk);
      estage[tid] = bfbits(m ? hn : 0.f);
    }
    __syncthreads();
    if (tid < 32){
      const int row = tid>>1, hw = tid&1;
      const f32x4 v = *(const f32x4*)(hstage + row*16 + hw*8);
      unsigned short* dst = hbuf + (((size_t)(dir*2+(tt&1))*64 + b0 + row)<<9) + us*16 + hw*8;
      asm volatile("global_store_dwordx4 %0, %1, off sc0 sc1" :: "v"(dst), "v"(v) : "memory");
    } else if (tid < 64){
      const int j = tid-32, row = j>>1, hw = j&1;
      const f32x4 v = *(const f32x4*)(estage + row*16 + hw*8);
      *(f32x4*)((unsigned short*)enc + ((size_t)((b0+row)*512 + t))*1024 + dir*512 + us*16 + hw*8) = v;
    }
    asm volatile("s_waitcnt vmcnt(0)" ::: "memory");
    __syncthreads();
    if (tid==0) __hip_atomic_fetch_add(gcnt, 1u, __ATOMIC_RELAXED, AGENT);
  }

  if (tid < 256){
    hfin[dir*32768 + bg*512 + ug] = hprev;
    (dir ? cb : cf)[bg*512 + ug] = creg;
  }
}

// ---------------- decoder init ----------------
__global__ void __launch_bounds__(256) fc_init(
  const float* __restrict__ hf0, const float* __restrict__ hb0,
  const float* __restrict__ cf, const float* __restrict__ cb,
  const float* __restrict__ fchW, const float* __restrict__ fchB,
  const float* __restrict__ fccW, const float* __restrict__ fccB,
  float* __restrict__ dech, float* __restrict__ decc)
{
  const int which = blockIdx.x >> 7;
  const int wid = blockIdx.x & 127;
  const int b = threadIdx.x >> 2, ul = threadIdx.x & 3;
  const int u = wid*4 + ul;
  const float* s0 = which ? cf : hf0;
  const float* s1 = which ? cb : hb0;
  const float* W = which ? fccW : fchW;
  float acc = (which ? fccB : fchB)[u];
  const float4* x0 = (const float4*)(s0 + b*512);
  const float4* x1 = (const float4*)(s1 + b*512);
  const float4* wr = (const float4*)(W + (size_t)u*1024);
  #pragma unroll 4
  for (int k=0;k<128;k++) acc += dot4(x0[k], wr[k]);
  #pragma unroll 4
  for (int k=0;k<128;k++) acc += dot4(x1[k], wr[128+k]);
  (which ? decc : dech)[b*512+u] = tanhfast(acc);
}

// ---------------- eh = enc_out @ Wenc.T -> bf16, transposed ehT[b][n][s] ----------------
__global__ void __launch_bounds__(512) eh_gemm(
  const __hip_bfloat16* __restrict__ enc, const float* __restrict__ WT,
  __hip_bfloat16* __restrict__ ehT)
{
  const int b = blockIdx.x >> 6;
  const int s = (blockIdx.x & 63)*8 + (threadIdx.x >> 6);
  const int n0 = (threadIdx.x & 63)*8;
  const __hip_bfloat16* ap = enc + ((size_t)(b*512 + s))*1024;
  float c0=0,c1=0,c2=0,c3=0,c4=0,c5=0,c6=0,c7=0;
  for (int k=0;k<1024;k++){
    const float a = __bfloat162float(ap[k]);
    const float4* w = (const float4*)(WT + (size_t)k*512 + n0);
    const float4 wA = w[0], wB = w[1];
    c0 = fmaf(a, wA.x, c0); c1 = fmaf(a, wA.y, c1);
    c2 = fmaf(a, wA.z, c2); c3 = fmaf(a, wA.w, c3);
    c4 = fmaf(a, wB.x, c4); c5 = fmaf(a, wB.y, c5);
    c6 = fmaf(a, wB.z, c6); c7 = fmaf(a, wB.w, c7);
  }
  __hip_bfloat16* op = ehT + ((size_t)(b*512) + n0)*512 + s;
  op[0]=__float2bfloat16(c0); op[512]=__float2bfloat16(c1);
  op[1024]=__float2bfloat16(c2); op[1536]=__float2bfloat16(c3);
  op[2048]=__float2bfloat16(c4); op[2560]=__float2bfloat16(c5);
  op[3072]=__float2bfloat16(c6); op[3584]=__float2bfloat16(c7);
}

// ---------------- fused persistent decoder ----------------
__device__ __forceinline__ void gridbar(unsigned* dcnt, unsigned target){
  asm volatile("s_waitcnt vmcnt(0)" ::: "memory");
  __syncthreads();
  if (threadIdx.x==0){
    __hip_atomic_fetch_add(dcnt, 1u, __ATOMIC_RELAXED, AGENT);
    while (__hip_atomic_load(dcnt, __ATOMIC_RELAXED, AGENT) < target)
      __builtin_amdgcn_s_sleep(2);
  }
  __syncthreads();
}

__global__ void __launch_bounds__(512) dec_fused(
  const float* __restrict__ trg, const int* __restrict__ smask,
  const float* __restrict__ attnv,
  const unsigned short* __restrict__ ehTb,
  const unsigned short* __restrict__ encw,
  const unsigned short* __restrict__ Wcat,
  const unsigned short* __restrict__ WdecT,
  const float* __restrict__ PQd, const float* __restrict__ hc,
  const float* __restrict__ valW, const float* __restrict__ stopW,
  const float* __restrict__ dech0, const float* __restrict__ decc0,
  float* __restrict__ adh, float* __restrict__ scoresb, float* __restrict__ ctxf,
  unsigned short* __restrict__ xbuf, float* __restrict__ gates,
  float* __restrict__ out, unsigned* __restrict__ dcnt)
{
  __shared__ alignas(16) float redl[8192];
  __shared__ float vlds[512];
  __shared__ float alds[512];
  const int tid = threadIdx.x;
  const int bid = blockIdx.x;
  const int b = bid>>2, quad = bid&3;
  const int lane = tid&63, wv = tid>>6;
  unsigned gen = 0;

  vlds[tid] = attnv[tid];

  // P4 resident weights (bid<128): rows n0=bid*16..+16, wave k-range wv*192..+192
  short8 gw[6];
  if (bid < 128){
    const int n = bid*16 + (lane&15);
    const unsigned short* wp = Wcat + (size_t)n*1536 + wv*192 + (lane>>4)*8;
    #pragma unroll
    for (int ks=0;ks<6;ks++) gw[ks] = *(const short8*)(wp + ks*32);
  }

  // P5 state + constants (bid%4==0)
  const bool isb = (quad==0);
  float hr=0.f, cr=0.f;
  float pqi=0,pqf=0,pqg=0,pqo=0, qqi=0,qqf=0,qqg=0,qqo=0;
  float vwh=0,vwc0=0,vwc1=0, swh=0,swc0=0,swc1=0;
  if (isb){
    hr = dech0[b*512+tid]; cr = decc0[b*512+tid];
    pqi = PQd[tid];      pqf = PQd[512+tid];      pqg = PQd[1024+tid];      pqo = PQd[1536+tid];
    qqi = PQd[2048+tid]; qqf = PQd[2048+512+tid]; qqg = PQd[2048+1024+tid]; qqo = PQd[2048+1536+tid];
    vwh = valW[tid]; vwc0 = valW[512+tid]; vwc1 = valW[1024+tid];
    swh = stopW[tid]; swc0 = stopW[512+tid]; swc1 = stopW[1024+tid];
  }

  // ---- D0: seed xbuf-dech + adh(0) ----
  if (isb){
    const unsigned hb16 = (unsigned)bfbits(hr);
    unsigned short* xp = xbuf + b*1536 + 1024 + tid;
    asm volatile("global_store_short %0, %1, off sc0 sc1" :: "v"(xp), "v"(hb16) : "memory");
    redl[tid] = hr;
  }
  __syncthreads();
  if (isb){
    float acc = 0.f;
    for (int u=0; u<512; ++u)
      acc = fmaf(redl[u], bfu2f(WdecT[u*512+tid]), acc);
    float* ap = adh + b*512 + tid;
    asm volatile("global_store_dword %0, %1, off sc0 sc1" :: "v"(ap), "v"(acc) : "memory");
  }
  ++gen; gridbar(dcnt, 256u*gen);

  for (int t=0; t<95; ++t){
    // ---- P2: scores[b][quad*128..+128] ----
    {
      float a;
      const float* ap = adh + b*512 + tid;
      asm volatile("global_load_dword %0, %1, off sc0 sc1\ns_waitcnt vmcnt(0)" : "=v"(a) : "v"(ap) : "memory");
      alds[tid] = a;
    }
    __syncthreads();
    {
      const int ns = tid>>7, sl = tid&127;
      const int s = quad*128 + sl;
      const unsigned short* ep = ehTb + ((size_t)(b*512 + ns*128))*512 + s;
      float f = 0.f;
      #pragma unroll 4
      for (int i=0;i<128;i++){
        const float e = bfu2f(ep[(size_t)i*512]);
        f = fmaf(vlds[ns*128+i], tanhfast(alds[ns*128+i] + e), f);
      }
      redl[tid] = f;
      __syncthreads();
      if (ns==0){
        const float tot = redl[sl] + redl[128+sl] + redl[256+sl] + redl[384+sl];
        const float sc = smask[b*512+s] ? tot : -1.0e9f;
        float* sp = scoresb + b*512 + s;
        asm volatile("global_store_dword %0, %1, off sc0 sc1" :: "v"(sp), "v"(sc) : "memory");
      }
    }
    ++gen; gridbar(dcnt, 256u*gen);

    // ---- P3: softmax + ctx[b][quad*256..+256] ----
    {
      float s0;
      const float* sp = scoresb + b*512 + tid;
      asm volatile("global_load_dword %0, %1, off sc0 sc1\ns_waitcnt vmcnt(0)" : "=v"(s0) : "v"(sp) : "memory");
      redl[512+tid] = s0;
      __syncthreads();
      for (int off=256; off>0; off>>=1){
        if (tid<off) redl[512+tid] = fmaxf(redl[512+tid], redl[512+tid+off]);
        __syncthreads();
      }
      const float m = redl[512];
      __syncthreads();
      const float e = __expf(s0 - m);
      redl[512+tid] = e;
      __syncthreads();
      for (int off=256; off>0; off>>=1){
        if (tid<off) redl[512+tid] += redl[512+tid+off];
        __syncthreads();
      }
      const float Z = redl[512];
      __syncthreads();
      redl[tid] = e / Z;            // w
      __syncthreads();
      const int sh = tid>>8, jl = tid&255;
      const int j = quad*256 + jl;
      const unsigned short* ep2 = encw + ((size_t)(b*512 + sh*256))*1024 + j;
      float c = 0.f;
      #pragma unroll 4
      for (int i=0;i<256;i++) c = fmaf(redl[sh*256+i], bfu2f(ep2[(size_t)i*1024]), c);
      redl[512+tid] = c;
      __syncthreads();
      if (sh==0){
        const float cv = redl[512+jl] + redl[768+jl];
        float* cp = ctxf + b*1024 + j;
        asm volatile("global_store_dword %0, %1, off sc0 sc1" :: "v"(cp), "v"(cv) : "memory");
        const unsigned cb16 = (unsigned)bfbits(cv);
        unsigned short* xp = xbuf + b*1536 + j;
        asm volatile("global_store_short %0, %1, off sc0 sc1" :: "v"(xp), "v"(cb16) : "memory");
      }
    }
    ++gen; gridbar(dcnt, 256u*gen);

    // ---- P4: gates MFMA (bid<128), double-buffered A-frags ----
    if (bid < 128){
      f32x4 av[2][6];
      f32x4 acc[4] = {{0,0,0,0},{0,0,0,0},{0,0,0,0},{0,0,0,0}};
      {
        const unsigned short* xp0 = xbuf + (size_t)(lane&15)*1536 + wv*192 + (lane>>4)*8;
        #pragma unroll
        for (int ks=0;ks<6;ks++){
          const unsigned short* p = xp0 + ks*32;
          asm volatile("global_load_dwordx4 %0, %1, off sc0 sc1" : "=v"(av[0][ks]) : "v"(p) : "memory");
        }
      }
      #pragma unroll
      for (int mt=0; mt<4; ++mt){
        if (mt<3){
          const unsigned short* xpn = xbuf + (size_t)((mt+1)*16 + (lane&15))*1536 + wv*192 + (lane>>4)*8;
          #pragma unroll
          for (int ks=0;ks<6;ks++){
            const unsigned short* p = xpn + ks*32;
            asm volatile("global_load_dwordx4 %0, %1, off sc0 sc1" : "=v"(av[(mt+1)&1][ks]) : "v"(p) : "memory");
          }
          asm volatile("s_waitcnt vmcnt(6)" ::: "memory");
        } else {
          asm volatile("s_waitcnt vmcnt(0)" ::: "memory");
        }
        __builtin_amdgcn_sched_barrier(0);
        #pragma unroll
        for (int ks=0;ks<6;ks++){
          V16 a; a.f = av[mt&1][ks];
          acc[mt] = __builtin_amdgcn_mfma_f32_16x16x32_bf16(a.s, gw[ks], acc[mt], 0, 0, 0);
        }
      }
      #pragma unroll
      for (int mt=0; mt<4; ++mt)
        *(f32x4*)&redl[wv*1024 + lane*16 + mt*4] = acc[mt];
    }
    __syncthreads();
    if (bid < 128){
      #pragma unroll
      for (int h2=0; h2<2; ++h2){
        const int o = h2*512 + tid;
        const int ob = o>>4, col = o&15;
        const int mt = ob>>4, row = ob&15;
        const int base = (((row>>2)<<4) | col)*16 + mt*4 + (row&3);
        float g = 0.f;
        #pragma unroll
        for (int w2=0; w2<8; ++w2) g += redl[w2*1024 + base];
        float* gp = gates + ob*2048 + bid*16 + col;
        asm volatile("global_store_dword %0, %1, off sc0 sc1" :: "v"(gp), "v"(g) : "memory");
      }
    }
    ++gen; gridbar(dcnt, 256u*gen);

    // ---- P5: cell update + heads + adh(t+1) (bid%4==0) ----
    if (isb){
      float g4[4], c0v, c1v;
      {
        const float* gp = gates + b*2048 + tid;
        const float* cp = ctxf + b*1024 + tid;
        asm volatile("global_load_dword %0, %1, off sc0 sc1" : "=v"(g4[0]) : "v"(gp) : "memory");
        asm volatile("global_load_dword %0, %1, off sc0 sc1" : "=v"(g4[1]) : "v"(gp+512) : "memory");
        asm volatile("global_load_dword %0, %1, off sc0 sc1" : "=v"(g4[2]) : "v"(gp+1024) : "memory");
        asm volatile("global_load_dword %0, %1, off sc0 sc1" : "=v"(g4[3]) : "v"(gp+1536) : "memory");
        asm volatile("global_load_dword %0, %1, off sc0 sc1" : "=v"(c0v) : "v"(cp) : "memory");
        asm volatile("global_load_dword %0, %1, off sc0 sc1" : "=v"(c1v) : "v"(cp+512) : "memory");
        asm volatile("s_waitcnt vmcnt(0)" ::: "memory");
        __builtin_amdgcn_sched_barrier(0);
      }
      const float x = trg[b*96 + t]*0.001f;
      const float gi = g4[0] + x*pqi + qqi;
      const float gf = g4[1] + x*pqf + qqf;
      const float gg = g4[2] + x*pqg + qqg;
      const float go = g4[3] + x*pqo + qqo;
      const float cn = fmaf(sigm(gf), cr, sigm(gi)*tanhfast(gg));
      const float hn = sigm(go)*tanhfast(cn);
      cr = cn; hr = hn;
      const unsigned hb16 = (unsigned)bfbits(hn);
      unsigned short* xp = xbuf + b*1536 + 1024 + tid;
      asm volatile("global_store_short %0, %1, off sc0 sc1" :: "v"(xp), "v"(hb16) : "memory");
      redl[tid] = hn;
      redl[512+tid]  = fmaf(hn, vwh, fmaf(c0v, vwc0, c1v*vwc1));
      redl[1024+tid] = fmaf(hn, swh, fmaf(c0v, swc0, c1v*swc1));
      __syncthreads();
      for (int off=256; off>0; off>>=1){
        if (tid<off){ redl[512+tid]+=redl[512+tid+off]; redl[1024+tid]+=redl[1024+tid+off]; }
        __syncthreads();
      }
      if (tid==0){
        out[b*95 + t] = (redl[512] + x*hc[0] + hc[1])*1000.f;
        out[6080 + b*95 + t] = redl[1024] + x*hc[2] + hc[3];
      }
      float acc = 0.f;
      for (int u=0; u<512; ++u)
        acc = fmaf(redl[u], bfu2f(WdecT[u*512+tid]), acc);
      float* ap = adh + b*512 + tid;
      asm volatile("global_store_dword %0, %1, off sc0 sc1" :: "v"(ap), "v"(acc) : "memory");
    }
    ++gen; gridbar(dcnt, 256u*gen);
  }
}

// ---------------- launch ----------------
extern "C" void kernel_launch(void* const* d_in, const int* in_sizes, int n_in,
                              void* d_out, int out_size, void* d_ws, size_t ws_size,
                              hipStream_t stream)
{
  (void)in_sizes; (void)n_in; (void)out_size; (void)ws_size;
  const float* src   = (const float*)d_in[0];
  const int*   smask = (const int*)  d_in[1];
  const float* trg   = (const float*)d_in[2];
  const float* epW   = (const float*)d_in[4];
  const float* epb   = (const float*)d_in[5];
  const float* Wihf  = (const float*)d_in[6];
  const float* Whhf  = (const float*)d_in[7];
  const float* bihf  = (const float*)d_in[8];
  const float* bhhf  = (const float*)d_in[9];
  const float* Wihb  = (const float*)d_in[10];
  const float* Whhb  = (const float*)d_in[11];
  const float* bihb  = (const float*)d_in[12];
  const float* bhhb  = (const float*)d_in[13];
  const float* fchW  = (const float*)d_in[14];
  const float* fchB  = (const float*)d_in[15];
  const float* fccW  = (const float*)d_in[16];
  const float* fccB  = (const float*)d_in[17];
  const float* dpW   = (const float*)d_in[18];
  const float* dpb   = (const float*)d_in[19];
  const float* Wenc  = (const float*)d_in[20];
  const float* Wdec  = (const float*)d_in[21];
  const float* attnv = (const float*)d_in[22];
  const float* dWih  = (const float*)d_in[23];
  const float* dWhh  = (const float*)d_in[24];
  const float* dbih  = (const float*)d_in[25];
  const float* dbhh  = (const float*)d_in[26];
  const float* valW  = (const float*)d_in[27];
  const float* valb  = (const float*)d_in[28];
  const float* stopW = (const float*)d_in[29];
  const float* stopb = (const float*)d_in[30];
  float* out = (float*)d_out;

  char* ws = (char*)d_ws;
  unsigned short* enc   = (unsigned short*)(ws);              // 64 MiB
  unsigned short* ehT   = (unsigned short*)(ws + 67108864);   // 32 MiB bf16
  unsigned short* hbuf  = (unsigned short*)(ws + 100663296);  // 512 KiB
  unsigned short* Wbf   = (unsigned short*)(ws + 101187584);  // 4 MiB
  unsigned short* Wcat  = (unsigned short*)(ws + 105381888);  // 6 MiB
  unsigned short* WdecT = (unsigned short*)(ws + 111673344);  // 512 KiB
  float* WT    = (float*)(ws + 112197632);                    // 2 MiB
  float* hfin  = (float*)(ws + 114294784);
  float* cf    = (float*)(ws + 114556928);
  float* cb    = (float*)(ws + 114688000);
  float* PQ    = (float*)(ws + 114819072);
  float* dech0 = (float*)(ws + 114868224);
  float* decc0 = (float*)(ws + 114999296);
  float* adh   = (float*)(ws + 115130368);
  float* scoresb = (float*)(ws + 115261440);
  float* ctxf  = (float*)(ws + 115392512);
  unsigned short* xbuf = (unsigned short*)(ws + 115654656);
  float* gates = (float*)(ws + 115851264);
  float* hc    = (float*)(ws + 116375552);
  unsigned* cnt  = (unsigned*)(ws + 116375680);
  unsigned* dcnt = (unsigned*)(ws + 116376704);
  float* PQd = PQ + 8192;

  (void)hipMemsetAsync(cnt, 0, 1152, stream);

  precompute<<<2097, 256, 0, stream>>>(Wenc, Wihf, epW, epb, bihf, bhhf, Wihb, bihb, bhhb,
                                       dWih, dpW, dpb, dbih, dbhh, valW, valb, stopW, stopb,
                                       PQ, WT, hc);
  wconv<<<10752, 512, 0, stream>>>(Whhf, Whhb, dWih, dWhh, Wdec, Wbf, Wcat, WdecT);

  {
    void* args[] = { (void*)&src, (void*)&smask, (void*)&Wbf, (void*)&PQ,
                     (void*)&hbuf, (void*)&hfin, (void*)&cf, (void*)&cb, (void*)&enc, (void*)&cnt };
    (void)hipLaunchCooperativeKernel((void*)enc_mfma, dim3(256), dim3(512), args, 0, stream);
  }

  {
    const float* hfF = hfin;
    const float* hbF = hfin + 32768;
    fc_init<<<256, 256, 0, stream>>>(hfF, hbF, cf, cb, fchW, fchB, fccW, fccB, dech0, decc0);
  }
  eh_gemm<<<4096, 512, 0, stream>>>((const __hip_bfloat16*)enc, WT, (__hip_bfloat16*)ehT);

  {
    void* args[] = { (void*)&trg, (void*)&smask, (void*)&attnv,
                     (void*)&ehT, (void*)&enc, (void*)&Wcat, (void*)&WdecT,
                     (void*)&PQd, (void*)&hc, (void*)&valW, (void*)&stopW,
                     (void*)&dech0, (void*)&decc0,
                     (void*)&adh, (void*)&scoresb, (void*)&ctxf,
                     (void*)&xbuf, (void*)&gates, (void*)&out, (void*)&dcnt };
    (void)hipLaunchCooperativeKernel((void*)dec_fused, dim3(256), dim3(512), args, 0, stream);
  }
}

// Round 8
// 11960.550 us; speedup vs baseline: 6.3073x; 1.2192x over previous
//
#include <hip/hip_runtime.h>
#include <hip/hip_bf16.h>

#define AGENT __HIP_MEMORY_SCOPE_AGENT

typedef float f32x4 __attribute__((ext_vector_type(4)));
typedef short short8 __attribute__((ext_vector_type(8)));
union V16 { f32x4 f; short8 s; };

// B=64 S=512 T=96 E=256 H=512 ENC_DIM=1024 4H=2048

__device__ __forceinline__ float sigm(float x){ return 1.f/(1.f+__expf(-x)); }
__device__ __forceinline__ float tanhfast(float x){
  float ax = fabsf(x);
  float e = __expf(-2.f*ax);
  float r = (1.f-e)/(1.f+e);
  return copysignf(r, x);
}
__device__ __forceinline__ float dot4(float4 a, float4 b){
  return fmaf(a.x,b.x, fmaf(a.y,b.y, fmaf(a.z,b.z, a.w*b.w)));
}
__device__ __forceinline__ unsigned short bfbits(float x){
  return __bfloat16_as_ushort(__float2bfloat16(x));
}
__device__ __forceinline__ float bfu2f(unsigned short u){
  union{unsigned v; float f;} x; x.v = ((unsigned)u)<<16; return x.f;
}

// ---------------- precompute ----------------
__global__ void __launch_bounds__(256) precompute(
  const float* __restrict__ Wenc,
  const float* __restrict__ Wihf, const float* __restrict__ epW, const float* __restrict__ epb,
  const float* __restrict__ bihf, const float* __restrict__ bhhf,
  const float* __restrict__ Wihb, const float* __restrict__ bihb, const float* __restrict__ bhhb,
  const float* __restrict__ dWih, const float* __restrict__ dpW, const float* __restrict__ dpb,
  const float* __restrict__ dbih, const float* __restrict__ dbhh,
  const float* __restrict__ valW, const float* __restrict__ valb,
  const float* __restrict__ stopW, const float* __restrict__ stopb,
  float* __restrict__ PQ, float* __restrict__ WT, float* __restrict__ hc)
{
  const int idx = blockIdx.x*256 + threadIdx.x;
  if (idx < 524288){
    const int j = idx >> 9, n = idx & 511;
    WT[idx] = Wenc[(size_t)n*1024 + j];
  } else if (idx < 524288 + 6*2048){
    const int q = idx - 524288;
    const int set = q >> 11, j = q & 2047;
    const float* row; const float* vec; float add = 0.f;
    switch(set){
      case 0: row = Wihf + (size_t)j*256; vec = epW; break;
      case 1: row = Wihf + (size_t)j*256; vec = epb; add = bihf[j]+bhhf[j]; break;
      case 2: row = Wihb + (size_t)j*256; vec = epW; break;
      case 3: row = Wihb + (size_t)j*256; vec = epb; add = bihb[j]+bhhb[j]; break;
      case 4: row = dWih + (size_t)j*1280; vec = dpW; break;
      default: row = dWih + (size_t)j*1280; vec = dpb; add = dbih[j]+dbhh[j]; break;
    }
    float a = add;
    for (int e=0;e<256;e++) a = fmaf(row[e], vec[e], a);
    PQ[set*2048 + j] = a;
  } else if (idx < 524288 + 6*2048 + 4){
    const int q = idx - (524288 + 6*2048);
    const float* wrow = (q<2) ? valW : stopW;
    const float* vec  = (q&1) ? dpb : dpW;
    float a = (q&1) ? ((q<2)? valb[0] : stopb[0]) : 0.f;
    for (int e=0;e<256;e++) a = fmaf(wrow[1536+e], vec[e], a);
    hc[q] = a;
  }
}

// ---------------- weight converts ----------------
__global__ void __launch_bounds__(512) wconv(
  const float* __restrict__ Whhf, const float* __restrict__ Whhb,
  const float* __restrict__ dWih, const float* __restrict__ dWhh,
  const float* __restrict__ Wdec,
  unsigned short* __restrict__ Wbf, unsigned short* __restrict__ Wcat,
  unsigned short* __restrict__ WdecT)
{
  const int i = blockIdx.x*512 + threadIdx.x;
  if (i < 2097152){
    const float v = (i < 1048576) ? Whhf[i] : Whhb[i-1048576];
    Wbf[i] = bfbits(v);
  } else if (i < 2097152+3145728){
    const int q = i - 2097152;
    const int r = q/1536, k = q - r*1536;
    const float v = (k<1024) ? dWih[(size_t)r*1280 + 256 + k] : dWhh[(size_t)r*512 + (k-1024)];
    Wcat[q] = bfbits(v);
  } else {
    const int q = i - (2097152+3145728);
    const int u = q>>9, n = q&511;
    WdecT[q] = bfbits(Wdec[n*512+u]);
  }
}

// ---------------- encoder (unchanged, proven) ----------------
__global__ void __launch_bounds__(512) enc_mfma(
    const float* __restrict__ src, const int* __restrict__ smask,
    const unsigned short* __restrict__ Wbf,
    const float* __restrict__ PQ,
    unsigned short* __restrict__ hbuf,
    float* __restrict__ hfin,
    float* __restrict__ cf, float* __restrict__ cb,
    __hip_bfloat16* __restrict__ enc,
    unsigned* __restrict__ cnt)
{
  __shared__ float hlds[16*256];
  __shared__ float red[4*64*4];
  __shared__ float gbuf[4*256];
  __shared__ alignas(16) unsigned short hstage[256];
  __shared__ alignas(16) unsigned short estage[256];

  const int tid = threadIdx.x;
  const int bid = blockIdx.x;
  const int dir = bid>>7, bhalf = (bid>>5)&3, us = bid&31;
  const int b0 = bhalf*16;
  unsigned* gcnt = cnt + (dir*4 + bhalf)*32;
  const int wv = tid>>6, lane = tid&63;
  const int nt = wv&3, kh = wv>>2;
  const int rowb = lane&15;

  short8 bfr[8];
  {
    const int g = nt*512 + us*16 + (lane&15);
    const unsigned short* wp = Wbf + ((size_t)dir*2048 + g)*512 + kh*256 + (lane>>4)*8;
    #pragma unroll
    for (int kt=0;kt<8;kt++) bfr[kt] = *(const short8*)(wp + kt*32);
  }

  float p0=0,p1=0,p2=0,p3=0,q0=0,q1=0,q2=0,q3=0;
  float creg = 0.f, hprev = 0.f;
  int bg = 0, ug = 0;
  if (tid < 256){
    bg = b0 + (tid>>4);
    ug = us*16 + (tid&15);
    const float* P = PQ + dir*4096; const float* Q = P + 2048;
    p0=P[ug]; p1=P[ug+512]; p2=P[ug+1024]; p3=P[ug+1536];
    q0=Q[ug]; q1=Q[ug+512]; q2=Q[ug+1024]; q3=Q[ug+1536];
  }

  for (int tt=0; tt<512; ++tt){
    const int t = dir ? (511-tt) : tt;
    if (tt>0){
      if (tid==0){
        while (__hip_atomic_load(gcnt, __ATOMIC_RELAXED, AGENT) < 32u*(unsigned)tt)
          __builtin_amdgcn_s_sleep(1);
      }
      __syncthreads();
      const int par = (tt-1)&1;
      f32x4 tmp0, tmp1;
      {
        const int f0 = tid, f1 = 512 + tid;
        const unsigned short* g0 = hbuf + (((size_t)(dir*2+par)*64 + b0 + (f0>>6))<<9) + (f0&63)*8;
        const unsigned short* g1 = hbuf + (((size_t)(dir*2+par)*64 + b0 + (f1>>6))<<9) + (f1&63)*8;
        asm volatile("global_load_dwordx4 %0, %1, off sc0 sc1" : "=v"(tmp0) : "v"(g0) : "memory");
        asm volatile("global_load_dwordx4 %0, %1, off sc0 sc1" : "=v"(tmp1) : "v"(g1) : "memory");
      }
      asm volatile("s_waitcnt vmcnt(0)" ::: "memory");
      __builtin_amdgcn_sched_barrier(0);
      {
        const int r0 = tid>>6, c0 = tid&63;
        *(f32x4*)&hlds[r0*256 + ((c0 ^ (r0&7))<<2)] = tmp0;
        const int r1 = (512+tid)>>6, c1 = tid&63;
        *(f32x4*)&hlds[r1*256 + ((c1 ^ (r1&7))<<2)] = tmp1;
      }
      __syncthreads();
    }

    f32x4 acc = {0.f,0.f,0.f,0.f};
    if (tt>0){
      #pragma unroll
      for (int kt=0; kt<8; ++kt){
        const int ch = (kh*8 + kt)*4 + (lane>>4);
        V16 a; a.f = *(const f32x4*)&hlds[rowb*256 + ((ch ^ (rowb&7))<<2)];
        acc = __builtin_amdgcn_mfma_f32_16x16x32_bf16(a.s, bfr[kt], acc, 0, 0, 0);
      }
    }
    if (kh==1) *(f32x4*)&red[(nt*64+lane)*4] = acc;
    __syncthreads();
    if (kh==0){
      const f32x4 o = *(const f32x4*)&red[(nt*64+lane)*4];
      #pragma unroll
      for (int i=0;i<4;i++){
        const int r = (lane>>4)*4 + i, c = lane&15;
        gbuf[nt*256 + r*16 + c] = acc[i] + o[i];
      }
    }
    __syncthreads();

    if (tid < 256){
      const float sx = src[bg*512+t]*0.001f;
      const int m = smask[bg*512+t];
      const float gi = gbuf[0*256+tid] + sx*p0 + q0;
      const float gf = gbuf[1*256+tid] + sx*p1 + q1;
      const float gg = gbuf[2*256+tid] + sx*p2 + q2;
      const float go = gbuf[3*256+tid] + sx*p3 + q3;
      const float cn = fmaf(sigm(gf), creg, sigm(gi)*tanhfast(gg));
      const float hn = sigm(go)*tanhfast(cn);
      const float hk = m ? hn : hprev;
      creg = m ? cn : creg;
      hprev = hk;
      hstage[tid] = bfbits(hk);
      estage[tid] = bfbits(m ? hn : 0.f);
    }
    __syncthreads();
    if (tid < 32){
      const int row = tid>>1, hw = tid&1;
      const f32x4 v = *(const f32x4*)(hstage + row*16 + hw*8);
      unsigned short* dst = hbuf + (((size_t)(dir*2+(tt&1))*64 + b0 + row)<<9) + us*16 + hw*8;
      asm volatile("global_store_dwordx4 %0, %1, off sc0 sc1" :: "v"(dst), "v"(v) : "memory");
    } else if (tid < 64){
      const int j = tid-32, row = j>>1, hw = j&1;
      const f32x4 v = *(const f32x4*)(estage + row*16 + hw*8);
      *(f32x4*)((unsigned short*)enc + ((size_t)((b0+row)*512 + t))*1024 + dir*512 + us*16 + hw*8) = v;
    }
    asm volatile("s_waitcnt vmcnt(0)" ::: "memory");
    __syncthreads();
    if (tid==0) __hip_atomic_fetch_add(gcnt, 1u, __ATOMIC_RELAXED, AGENT);
  }

  if (tid < 256){
    hfin[dir*32768 + bg*512 + ug] = hprev;
    (dir ? cb : cf)[bg*512 + ug] = creg;
  }
}

// ---------------- decoder init ----------------
__global__ void __launch_bounds__(256) fc_init(
  const float* __restrict__ hf0, const float* __restrict__ hb0,
  const float* __restrict__ cf, const float* __restrict__ cb,
  const float* __restrict__ fchW, const float* __restrict__ fchB,
  const float* __restrict__ fccW, const float* __restrict__ fccB,
  float* __restrict__ dech, float* __restrict__ decc)
{
  const int which = blockIdx.x >> 7;
  const int wid = blockIdx.x & 127;
  const int b = threadIdx.x >> 2, ul = threadIdx.x & 3;
  const int u = wid*4 + ul;
  const float* s0 = which ? cf : hf0;
  const float* s1 = which ? cb : hb0;
  const float* W = which ? fccW : fchW;
  float acc = (which ? fccB : fchB)[u];
  const float4* x0 = (const float4*)(s0 + b*512);
  const float4* x1 = (const float4*)(s1 + b*512);
  const float4* wr = (const float4*)(W + (size_t)u*1024);
  #pragma unroll 4
  for (int k=0;k<128;k++) acc += dot4(x0[k], wr[k]);
  #pragma unroll 4
  for (int k=0;k<128;k++) acc += dot4(x1[k], wr[128+k]);
  (which ? decc : dech)[b*512+u] = tanhfast(acc);
}

// ---------------- eh = enc_out @ Wenc.T -> bf16, transposed ehT[b][n][s] ----------------
__global__ void __launch_bounds__(512) eh_gemm(
  const __hip_bfloat16* __restrict__ enc, const float* __restrict__ WT,
  __hip_bfloat16* __restrict__ ehT)
{
  const int b = blockIdx.x >> 6;
  const int s = (blockIdx.x & 63)*8 + (threadIdx.x >> 6);
  const int n0 = (threadIdx.x & 63)*8;
  const __hip_bfloat16* ap = enc + ((size_t)(b*512 + s))*1024;
  float c0=0,c1=0,c2=0,c3=0,c4=0,c5=0,c6=0,c7=0;
  for (int k=0;k<1024;k++){
    const float a = __bfloat162float(ap[k]);
    const float4* w = (const float4*)(WT + (size_t)k*512 + n0);
    const float4 wA = w[0], wB = w[1];
    c0 = fmaf(a, wA.x, c0); c1 = fmaf(a, wA.y, c1);
    c2 = fmaf(a, wA.z, c2); c3 = fmaf(a, wA.w, c3);
    c4 = fmaf(a, wB.x, c4); c5 = fmaf(a, wB.y, c5);
    c6 = fmaf(a, wB.z, c6); c7 = fmaf(a, wB.w, c7);
  }
  __hip_bfloat16* op = ehT + ((size_t)(b*512) + n0)*512 + s;
  op[0]=__float2bfloat16(c0); op[512]=__float2bfloat16(c1);
  op[1024]=__float2bfloat16(c2); op[1536]=__float2bfloat16(c3);
  op[2048]=__float2bfloat16(c4); op[2560]=__float2bfloat16(c5);
  op[3072]=__float2bfloat16(c6); op[3584]=__float2bfloat16(c7);
}

// ---------------- barriers ----------------
__device__ __forceinline__ void gbar(unsigned* gctr, unsigned* root, int grp, unsigned gen){
  asm volatile("s_waitcnt vmcnt(0)" ::: "memory");
  __syncthreads();
  if (threadIdx.x==0){
    const unsigned old = __hip_atomic_fetch_add(gctr + grp*32, 1u, __ATOMIC_RELAXED, AGENT);
    if (old == gen*16u - 1u)
      __hip_atomic_fetch_add(root, 1u, __ATOMIC_RELAXED, AGENT);
    while (__hip_atomic_load(root, __ATOMIC_RELAXED, AGENT) < gen*16u)
      __builtin_amdgcn_s_sleep(1);
  }
  __syncthreads();
}
__device__ __forceinline__ void mbar(unsigned* mc, unsigned mgen){
  asm volatile("s_waitcnt vmcnt(0)" ::: "memory");
  __syncthreads();
  if (threadIdx.x==0){
    __hip_atomic_fetch_add(mc, 1u, __ATOMIC_RELAXED, AGENT);
    while (__hip_atomic_load(mc, __ATOMIC_RELAXED, AGENT) < mgen*4u)
      __builtin_amdgcn_s_sleep(1);
  }
  __syncthreads();
}

// ---------------- fused persistent decoder v2 ----------------
__global__ void __launch_bounds__(512) dec_fused(
  const float* __restrict__ trg, const int* __restrict__ smask,
  const float* __restrict__ attnv,
  const unsigned short* __restrict__ ehTb,
  const unsigned short* __restrict__ encw,
  const unsigned short* __restrict__ Wcat,
  const unsigned short* __restrict__ WdecT,
  const float* __restrict__ PQd, const float* __restrict__ hc,
  const float* __restrict__ valW, const float* __restrict__ stopW,
  const float* __restrict__ dech0, const float* __restrict__ decc0,
  float* __restrict__ adh, float* __restrict__ scorep, float* __restrict__ ctxf,
  unsigned short* __restrict__ xbuf, float* __restrict__ gates,
  float* __restrict__ hcur, float* __restrict__ out,
  unsigned* __restrict__ gctr, unsigned* __restrict__ root, unsigned* __restrict__ mctr)
{
  __shared__ alignas(16) float redl[8192];
  __shared__ float vlds[512];
  __shared__ float alds[512];
  const int tid = threadIdx.x;
  const int bid = blockIdx.x;
  const int b = bid>>2, quad = bid&3;
  const int grp = bid>>4;
  const int lane = tid&63, wv = tid>>6;
  unsigned* mc = mctr + b*32;
  unsigned g = 0, m = 0;

  vlds[tid] = attnv[tid];

  short8 gw[6];
  if (bid < 128){
    const int n = bid*16 + (lane&15);
    const unsigned short* wp = Wcat + (size_t)n*1536 + wv*192 + (lane>>4)*8;
    #pragma unroll
    for (int ks=0;ks<6;ks++) gw[ks] = *(const short8*)(wp + ks*32);
  }

  const bool isb = (quad==0);
  float hr=0.f, cr=0.f;
  float pqi=0,pqf=0,pqg=0,pqo=0, qqi=0,qqf=0,qqg=0,qqo=0;
  float vwh=0,vwc0=0,vwc1=0, swh=0,swc0=0,swc1=0;
  if (isb){
    hr = dech0[b*512+tid]; cr = decc0[b*512+tid];
    pqi = PQd[tid];      pqf = PQd[512+tid];      pqg = PQd[1024+tid];      pqo = PQd[1536+tid];
    qqi = PQd[2048+tid]; qqf = PQd[2048+512+tid]; qqg = PQd[2048+1024+tid]; qqo = PQd[2048+1536+tid];
    vwh = valW[tid]; vwc0 = valW[512+tid]; vwc1 = valW[1024+tid];
    swh = stopW[tid]; swc0 = stopW[512+tid]; swc1 = stopW[1024+tid];
  }

  // ---- seed ----
  if (isb){
    const unsigned hb16 = (unsigned)bfbits(hr);
    unsigned short* xp = xbuf + b*1536 + 1024 + tid;
    asm volatile("global_store_short %0, %1, off sc0 sc1" :: "v"(xp), "v"(hb16) : "memory");
    float* hp = hcur + b*512 + tid;
    asm volatile("global_store_dword %0, %1, off sc0 sc1" :: "v"(hp), "v"(hr) : "memory");
  }
  ++m; mbar(mc, m);

  #define ADH_PHASE() do { \
    float hv; const float* hp_ = hcur + b*512 + tid; \
    asm volatile("global_load_dword %0, %1, off sc0 sc1\ns_waitcnt vmcnt(0)" : "=v"(hv) : "v"(hp_) : "memory"); \
    alds[tid] = hv; \
    __syncthreads(); \
    const int jq_ = tid&127, us_ = tid>>7; \
    const int j_ = quad*128 + jq_; \
    const unsigned short* wp_ = WdecT + (size_t)(us_*128)*512 + j_; \
    float p_ = 0.f; \
    _Pragma("unroll 4") \
    for (int u8=0; u8<128; ++u8) \
      p_ = fmaf(alds[us_*128+u8], bfu2f(wp_[(size_t)u8*512]), p_); \
    redl[tid] = p_; \
    __syncthreads(); \
    if (us_==0){ \
      const float a_ = redl[jq_]+redl[128+jq_]+redl[256+jq_]+redl[384+jq_]; \
      float* ap_ = adh + b*512 + j_; \
      asm volatile("global_store_dword %0, %1, off sc0 sc1" :: "v"(ap_), "v"(a_) : "memory"); \
    } \
  } while(0)

  ADH_PHASE();
  ++m; mbar(mc, m);

  for (int t=0; t<95; ++t){
    // ---- P2a: score partials ----
    {
      float av; const float* ap = adh + b*512 + tid;
      asm volatile("global_load_dword %0, %1, off sc0 sc1\ns_waitcnt vmcnt(0)" : "=v"(av) : "v"(ap) : "memory");
      alds[tid] = av;
      __syncthreads();
      const unsigned short* ep = ehTb + ((size_t)(b*512 + quad*128))*512 + tid;
      float part = 0.f;
      #pragma unroll 4
      for (int i=0;i<128;++i)
        part = fmaf(vlds[quad*128+i], tanhfast(alds[quad*128+i] + bfu2f(ep[(size_t)i*512])), part);
      float* sp = scorep + (size_t)bid*512 + tid;
      asm volatile("global_store_dword %0, %1, off sc0 sc1" :: "v"(sp), "v"(part) : "memory");
    }
    ++m; mbar(mc, m);

    // ---- P2b: softmax + ctx quarter ----
    {
      float pa, pb, pc, pd;
      const float* pp = scorep + (size_t)(b*4)*512 + tid;
      asm volatile("global_load_dword %0, %1, off sc0 sc1" : "=v"(pa) : "v"(pp) : "memory");
      asm volatile("global_load_dword %0, %1, off sc0 sc1" : "=v"(pb) : "v"(pp+512) : "memory");
      asm volatile("global_load_dword %0, %1, off sc0 sc1" : "=v"(pc) : "v"(pp+1024) : "memory");
      asm volatile("global_load_dword %0, %1, off sc0 sc1" : "=v"(pd) : "v"(pp+1536) : "memory");
      asm volatile("s_waitcnt vmcnt(0)" ::: "memory");
      __builtin_amdgcn_sched_barrier(0);
      float s0 = (pa+pb)+(pc+pd);
      s0 = smask[b*512+tid] ? s0 : -1.0e9f;
      redl[512+tid] = s0;
      __syncthreads();
      for (int off=256; off>0; off>>=1){
        if (tid<off) redl[512+tid] = fmaxf(redl[512+tid], redl[512+tid+off]);
        __syncthreads();
      }
      const float mx = redl[512];
      __syncthreads();
      const float e = __expf(s0 - mx);
      redl[512+tid] = e;
      __syncthreads();
      for (int off=256; off>0; off>>=1){
        if (tid<off) redl[512+tid] += redl[512+tid+off];
        __syncthreads();
      }
      const float Z = redl[512];
      __syncthreads();
      redl[tid] = e / Z;
      __syncthreads();
      const int sh = tid>>8, jl = tid&255;
      const int j = quad*256 + jl;
      const unsigned short* ep2 = encw + ((size_t)(b*512 + sh*256))*1024 + j;
      float c = 0.f;
      #pragma unroll 4
      for (int i=0;i<256;i++) c = fmaf(redl[sh*256+i], bfu2f(ep2[(size_t)i*1024]), c);
      redl[512+tid] = c;
      __syncthreads();
      if (sh==0){
        const float cv = redl[512+jl] + redl[768+jl];
        float* cp = ctxf + b*1024 + j;
        asm volatile("global_store_dword %0, %1, off sc0 sc1" :: "v"(cp), "v"(cv) : "memory");
        const unsigned cb16 = (unsigned)bfbits(cv);
        unsigned short* xp = xbuf + b*1536 + j;
        asm volatile("global_store_short %0, %1, off sc0 sc1" :: "v"(xp), "v"(cb16) : "memory");
      }
    }
    ++g; gbar(gctr, root, grp, g);

    // ---- P4: gates MFMA (bid<128) ----
    if (bid < 128){
      f32x4 av[2][6];
      f32x4 acc[4] = {{0,0,0,0},{0,0,0,0},{0,0,0,0},{0,0,0,0}};
      {
        const unsigned short* xp0 = xbuf + (size_t)(lane&15)*1536 + wv*192 + (lane>>4)*8;
        #pragma unroll
        for (int ks=0;ks<6;ks++){
          const unsigned short* p = xp0 + ks*32;
          asm volatile("global_load_dwordx4 %0, %1, off sc0 sc1" : "=v"(av[0][ks]) : "v"(p) : "memory");
        }
      }
      #pragma unroll
      for (int mt=0; mt<4; ++mt){
        if (mt<3){
          const unsigned short* xpn = xbuf + (size_t)((mt+1)*16 + (lane&15))*1536 + wv*192 + (lane>>4)*8;
          #pragma unroll
          for (int ks=0;ks<6;ks++){
            const unsigned short* p = xpn + ks*32;
            asm volatile("global_load_dwordx4 %0, %1, off sc0 sc1" : "=v"(av[(mt+1)&1][ks]) : "v"(p) : "memory");
          }
          asm volatile("s_waitcnt vmcnt(6)" ::: "memory");
        } else {
          asm volatile("s_waitcnt vmcnt(0)" ::: "memory");
        }
        __builtin_amdgcn_sched_barrier(0);
        #pragma unroll
        for (int ks=0;ks<6;ks++){
          V16 a; a.f = av[mt&1][ks];
          acc[mt] = __builtin_amdgcn_mfma_f32_16x16x32_bf16(a.s, gw[ks], acc[mt], 0, 0, 0);
        }
      }
      #pragma unroll
      for (int mt=0; mt<4; ++mt)
        *(f32x4*)&redl[wv*1024 + lane*16 + mt*4] = acc[mt];
    }
    __syncthreads();
    if (bid < 128){
      #pragma unroll
      for (int h2=0; h2<2; ++h2){
        const int o = h2*512 + tid;
        const int ob = o>>4, col = o&15;
        const int mt = ob>>4, row = ob&15;
        const int base = (((row>>2)<<4) | col)*16 + mt*4 + (row&3);
        float gsum = 0.f;
        #pragma unroll
        for (int w2=0; w2<8; ++w2) gsum += redl[w2*1024 + base];
        float* gp = gates + ob*2048 + bid*16 + col;
        asm volatile("global_store_dword %0, %1, off sc0 sc1" :: "v"(gp), "v"(gsum) : "memory");
      }
    }
    ++g; gbar(gctr, root, grp, g);

    // ---- P5: cell update + heads (quad==0) ----
    if (isb){
      float g4[4], c0v, c1v;
      {
        const float* gp = gates + b*2048 + tid;
        const float* cp = ctxf + b*1024 + tid;
        asm volatile("global_load_dword %0, %1, off sc0 sc1" : "=v"(g4[0]) : "v"(gp) : "memory");
        asm volatile("global_load_dword %0, %1, off sc0 sc1" : "=v"(g4[1]) : "v"(gp+512) : "memory");
        asm volatile("global_load_dword %0, %1, off sc0 sc1" : "=v"(g4[2]) : "v"(gp+1024) : "memory");
        asm volatile("global_load_dword %0, %1, off sc0 sc1" : "=v"(g4[3]) : "v"(gp+1536) : "memory");
        asm volatile("global_load_dword %0, %1, off sc0 sc1" : "=v"(c0v) : "v"(cp) : "memory");
        asm volatile("global_load_dword %0, %1, off sc0 sc1" : "=v"(c1v) : "v"(cp+512) : "memory");
        asm volatile("s_waitcnt vmcnt(0)" ::: "memory");
        __builtin_amdgcn_sched_barrier(0);
      }
      const float x = trg[b*96 + t]*0.001f;
      const float gi = g4[0] + x*pqi + qqi;
      const float gf = g4[1] + x*pqf + qqf;
      const float gg = g4[2] + x*pqg + qqg;
      const float go = g4[3] + x*pqo + qqo;
      const float cn = fmaf(sigm(gf), cr, sigm(gi)*tanhfast(gg));
      const float hn = sigm(go)*tanhfast(cn);
      cr = cn; hr = hn;
      const unsigned hb16 = (unsigned)bfbits(hn);
      unsigned short* xp = xbuf + b*1536 + 1024 + tid;
      asm volatile("global_store_short %0, %1, off sc0 sc1" :: "v"(xp), "v"(hb16) : "memory");
      float* hp = hcur + b*512 + tid;
      asm volatile("global_store_dword %0, %1, off sc0 sc1" :: "v"(hp), "v"(hn) : "memory");
      redl[512+tid]  = fmaf(hn, vwh, fmaf(c0v, vwc0, c1v*vwc1));
      redl[1024+tid] = fmaf(hn, swh, fmaf(c0v, swc0, c1v*swc1));
      __syncthreads();
      for (int off=256; off>0; off>>=1){
        if (tid<off){ redl[512+tid]+=redl[512+tid+off]; redl[1024+tid]+=redl[1024+tid+off]; }
        __syncthreads();
      }
      if (tid==0){
        out[b*95 + t] = (redl[512] + x*hc[0] + hc[1])*1000.f;
        out[6080 + b*95 + t] = redl[1024] + x*hc[2] + hc[3];
      }
    }
    ++m; mbar(mc, m);

    // ---- adh(t+1) quarters ----
    ADH_PHASE();
    ++m; mbar(mc, m);
  }
  #undef ADH_PHASE
}

// ---------------- launch ----------------
extern "C" void kernel_launch(void* const* d_in, const int* in_sizes, int n_in,
                              void* d_out, int out_size, void* d_ws, size_t ws_size,
                              hipStream_t stream)
{
  (void)in_sizes; (void)n_in; (void)out_size; (void)ws_size;
  const float* src   = (const float*)d_in[0];
  const int*   smask = (const int*)  d_in[1];
  const float* trg   = (const float*)d_in[2];
  const float* epW   = (const float*)d_in[4];
  const float* epb   = (const float*)d_in[5];
  const float* Wihf  = (const float*)d_in[6];
  const float* Whhf  = (const float*)d_in[7];
  const float* bihf  = (const float*)d_in[8];
  const float* bhhf  = (const float*)d_in[9];
  const float* Wihb  = (const float*)d_in[10];
  const float* Whhb  = (const float*)d_in[11];
  const float* bihb  = (const float*)d_in[12];
  const float* bhhb  = (const float*)d_in[13];
  const float* fchW  = (const float*)d_in[14];
  const float* fchB  = (const float*)d_in[15];
  const float* fccW  = (const float*)d_in[16];
  const float* fccB  = (const float*)d_in[17];
  const float* dpW   = (const float*)d_in[18];
  const float* dpb   = (const float*)d_in[19];
  const float* Wenc  = (const float*)d_in[20];
  const float* Wdec  = (const float*)d_in[21];
  const float* attnv = (const float*)d_in[22];
  const float* dWih  = (const float*)d_in[23];
  const float* dWhh  = (const float*)d_in[24];
  const float* dbih  = (const float*)d_in[25];
  const float* dbhh  = (const float*)d_in[26];
  const float* valW  = (const float*)d_in[27];
  const float* valb  = (const float*)d_in[28];
  const float* stopW = (const float*)d_in[29];
  const float* stopb = (const float*)d_in[30];
  float* out = (float*)d_out;

  // ---- bump allocator: no hand-computed offsets (round-7 hang was an overlap) ----
  char* ws = (char*)d_ws;
  size_t off = 0;
  auto take = [&](size_t nbytes) -> char* {
    char* p = ws + off;
    off += (nbytes + 255) & ~(size_t)255;
    return p;
  };
  unsigned short* enc   = (unsigned short*)take((size_t)64*512*1024*2);  // 64 MiB
  unsigned short* ehT   = (unsigned short*)take((size_t)64*512*512*2);   // 32 MiB
  unsigned short* hbuf  = (unsigned short*)take(2*2*64*512*2);           // 256 KiB
  unsigned short* Wbf   = (unsigned short*)take((size_t)2*2048*512*2);   // 4 MiB
  unsigned short* Wcat  = (unsigned short*)take((size_t)2048*1536*2);    // 6 MiB
  unsigned short* WdecT = (unsigned short*)take(512*512*2);              // 512 KiB
  float* WT    = (float*)take((size_t)1024*512*4);                       // 2 MiB
  float* hfin  = (float*)take(2*64*512*4);
  float* cf    = (float*)take(64*512*4);
  float* cb    = (float*)take(64*512*4);
  float* PQ    = (float*)take(6*2048*4);
  float* dech0 = (float*)take(64*512*4);
  float* decc0 = (float*)take(64*512*4);
  float* adh   = (float*)take(64*512*4);
  float* scorep= (float*)take(256*512*4);
  float* ctxf  = (float*)take(64*1024*4);
  unsigned short* xbuf = (unsigned short*)take(64*1536*2);
  float* gates = (float*)take(64*2048*4);
  float* hcur  = (float*)take(64*512*4);
  float* hc    = (float*)take(128);
  unsigned* cnt  = (unsigned*)take(1024);
  unsigned* gctr = (unsigned*)take(2048);
  unsigned* root = (unsigned*)take(256);
  unsigned* mctr = (unsigned*)take(8192);
  float* PQd = PQ + 8192;
  // counters are contiguous: cnt(1024) + gctr(2048) + root(256) + mctr(8192)
  (void)hipMemsetAsync(cnt, 0, 1024+2048+256+8192, stream);

  precompute<<<2097, 256, 0, stream>>>(Wenc, Wihf, epW, epb, bihf, bhhf, Wihb, bihb, bhhb,
                                       dWih, dpW, dpb, dbih, dbhh, valW, valb, stopW, stopb,
                                       PQ, WT, hc);
  wconv<<<10752, 512, 0, stream>>>(Whhf, Whhb, dWih, dWhh, Wdec, Wbf, Wcat, WdecT);

  {
    void* args[] = { (void*)&src, (void*)&smask, (void*)&Wbf, (void*)&PQ,
                     (void*)&hbuf, (void*)&hfin, (void*)&cf, (void*)&cb, (void*)&enc, (void*)&cnt };
    (void)hipLaunchCooperativeKernel((void*)enc_mfma, dim3(256), dim3(512), args, 0, stream);
  }

  {
    const float* hfF = hfin;
    const float* hbF = hfin + 32768;
    fc_init<<<256, 256, 0, stream>>>(hfF, hbF, cf, cb, fchW, fchB, fccW, fccB, dech0, decc0);
  }
  eh_gemm<<<4096, 512, 0, stream>>>((const __hip_bfloat16*)enc, WT, (__hip_bfloat16*)ehT);

  {
    void* args[] = { (void*)&trg, (void*)&smask, (void*)&attnv,
                     (void*)&ehT, (void*)&enc, (void*)&Wcat, (void*)&WdecT,
                     (void*)&PQd, (void*)&hc, (void*)&valW, (void*)&stopW,
                     (void*)&dech0, (void*)&decc0,
                     (void*)&adh, (void*)&scorep, (void*)&ctxf,
                     (void*)&xbuf, (void*)&gates, (void*)&hcur, (void*)&out,
                     (void*)&gctr, (void*)&root, (void*)&mctr };
    (void)hipLaunchCooperativeKernel((void*)dec_fused, dim3(256), dim3(512), args, 0, stream);
  }
}

// Round 9
// 8868.427 us; speedup vs baseline: 8.5065x; 1.3487x over previous
//
#include <hip/hip_runtime.h>
#include <hip/hip_bf16.h>

#define AGENT __HIP_MEMORY_SCOPE_AGENT

typedef float f32x4 __attribute__((ext_vector_type(4)));
typedef short short8 __attribute__((ext_vector_type(8)));
union V16 { f32x4 f; short8 s; };

// B=64 S=512 T=96 E=256 H=512 ENC_DIM=1024 4H=2048

__device__ __forceinline__ float sigm(float x){ return 1.f/(1.f+__expf(-x)); }
__device__ __forceinline__ float tanhfast(float x){
  float ax = fabsf(x);
  float e = __expf(-2.f*ax);
  float r = (1.f-e)/(1.f+e);
  return copysignf(r, x);
}
__device__ __forceinline__ float dot4(float4 a, float4 b){
  return fmaf(a.x,b.x, fmaf(a.y,b.y, fmaf(a.z,b.z, a.w*b.w)));
}
__device__ __forceinline__ unsigned short bfbits(float x){
  return __bfloat16_as_ushort(__float2bfloat16(x));
}
__device__ __forceinline__ float bfu2f(unsigned short u){
  union{unsigned v; float f;} x; x.v = ((unsigned)u)<<16; return x.f;
}

// ---------------- precompute ----------------
__global__ void __launch_bounds__(256) precompute(
  const float* __restrict__ Wenc,
  const float* __restrict__ Wihf, const float* __restrict__ epW, const float* __restrict__ epb,
  const float* __restrict__ bihf, const float* __restrict__ bhhf,
  const float* __restrict__ Wihb, const float* __restrict__ bihb, const float* __restrict__ bhhb,
  const float* __restrict__ dWih, const float* __restrict__ dpW, const float* __restrict__ dpb,
  const float* __restrict__ dbih, const float* __restrict__ dbhh,
  const float* __restrict__ valW, const float* __restrict__ valb,
  const float* __restrict__ stopW, const float* __restrict__ stopb,
  float* __restrict__ PQ, float* __restrict__ WT, float* __restrict__ hc)
{
  const int idx = blockIdx.x*256 + threadIdx.x;
  if (idx < 524288){
    const int j = idx >> 9, n = idx & 511;
    WT[idx] = Wenc[(size_t)n*1024 + j];
  } else if (idx < 524288 + 6*2048){
    const int q = idx - 524288;
    const int set = q >> 11, j = q & 2047;
    const float* row; const float* vec; float add = 0.f;
    switch(set){
      case 0: row = Wihf + (size_t)j*256; vec = epW; break;
      case 1: row = Wihf + (size_t)j*256; vec = epb; add = bihf[j]+bhhf[j]; break;
      case 2: row = Wihb + (size_t)j*256; vec = epW; break;
      case 3: row = Wihb + (size_t)j*256; vec = epb; add = bihb[j]+bhhb[j]; break;
      case 4: row = dWih + (size_t)j*1280; vec = dpW; break;
      default: row = dWih + (size_t)j*1280; vec = dpb; add = dbih[j]+dbhh[j]; break;
    }
    float a = add;
    for (int e=0;e<256;e++) a = fmaf(row[e], vec[e], a);
    PQ[set*2048 + j] = a;
  } else if (idx < 524288 + 6*2048 + 4){
    const int q = idx - (524288 + 6*2048);
    const float* wrow = (q<2) ? valW : stopW;
    const float* vec  = (q&1) ? dpb : dpW;
    float a = (q&1) ? ((q<2)? valb[0] : stopb[0]) : 0.f;
    for (int e=0;e<256;e++) a = fmaf(wrow[1536+e], vec[e], a);
    hc[q] = a;
  }
}

// ---------------- weight converts ----------------
__global__ void __launch_bounds__(512) wconv(
  const float* __restrict__ Whhf, const float* __restrict__ Whhb,
  const float* __restrict__ dWih, const float* __restrict__ dWhh,
  const float* __restrict__ Wdec,
  unsigned short* __restrict__ Wbf, unsigned short* __restrict__ Wcat,
  unsigned short* __restrict__ Wdecb)
{
  const int i = blockIdx.x*512 + threadIdx.x;
  if (i < 2097152){
    const float v = (i < 1048576) ? Whhf[i] : Whhb[i-1048576];
    Wbf[i] = bfbits(v);
  } else if (i < 2097152+3145728){
    const int q = i - 2097152;
    const int r = q/1536, k = q - r*1536;
    const float v = (k<1024) ? dWih[(size_t)r*1280 + 256 + k] : dWhh[(size_t)r*512 + (k-1024)];
    Wcat[q] = bfbits(v);
  } else {
    const int q = i - (2097152+3145728);
    Wdecb[q] = bfbits(Wdec[q]);   // row-major [j][u], u contiguous
  }
}

// ---------------- encoder (unchanged, proven) ----------------
__global__ void __launch_bounds__(512) enc_mfma(
    const float* __restrict__ src, const int* __restrict__ smask,
    const unsigned short* __restrict__ Wbf,
    const float* __restrict__ PQ,
    unsigned short* __restrict__ hbuf,
    float* __restrict__ hfin,
    float* __restrict__ cf, float* __restrict__ cb,
    __hip_bfloat16* __restrict__ enc,
    unsigned* __restrict__ cnt)
{
  __shared__ float hlds[16*256];
  __shared__ float red[4*64*4];
  __shared__ float gbuf[4*256];
  __shared__ alignas(16) unsigned short hstage[256];
  __shared__ alignas(16) unsigned short estage[256];

  const int tid = threadIdx.x;
  const int bid = blockIdx.x;
  const int dir = bid>>7, bhalf = (bid>>5)&3, us = bid&31;
  const int b0 = bhalf*16;
  unsigned* gcnt = cnt + (dir*4 + bhalf)*32;
  const int wv = tid>>6, lane = tid&63;
  const int nt = wv&3, kh = wv>>2;
  const int rowb = lane&15;

  short8 bfr[8];
  {
    const int g = nt*512 + us*16 + (lane&15);
    const unsigned short* wp = Wbf + ((size_t)dir*2048 + g)*512 + kh*256 + (lane>>4)*8;
    #pragma unroll
    for (int kt=0;kt<8;kt++) bfr[kt] = *(const short8*)(wp + kt*32);
  }

  float p0=0,p1=0,p2=0,p3=0,q0=0,q1=0,q2=0,q3=0;
  float creg = 0.f, hprev = 0.f;
  int bg = 0, ug = 0;
  if (tid < 256){
    bg = b0 + (tid>>4);
    ug = us*16 + (tid&15);
    const float* P = PQ + dir*4096; const float* Q = P + 2048;
    p0=P[ug]; p1=P[ug+512]; p2=P[ug+1024]; p3=P[ug+1536];
    q0=Q[ug]; q1=Q[ug+512]; q2=Q[ug+1024]; q3=Q[ug+1536];
  }

  for (int tt=0; tt<512; ++tt){
    const int t = dir ? (511-tt) : tt;
    if (tt>0){
      if (tid==0){
        while (__hip_atomic_load(gcnt, __ATOMIC_RELAXED, AGENT) < 32u*(unsigned)tt)
          __builtin_amdgcn_s_sleep(1);
      }
      __syncthreads();
      const int par = (tt-1)&1;
      f32x4 tmp0, tmp1;
      {
        const int f0 = tid, f1 = 512 + tid;
        const unsigned short* g0 = hbuf + (((size_t)(dir*2+par)*64 + b0 + (f0>>6))<<9) + (f0&63)*8;
        const unsigned short* g1 = hbuf + (((size_t)(dir*2+par)*64 + b0 + (f1>>6))<<9) + (f1&63)*8;
        asm volatile("global_load_dwordx4 %0, %1, off sc0 sc1" : "=v"(tmp0) : "v"(g0) : "memory");
        asm volatile("global_load_dwordx4 %0, %1, off sc0 sc1" : "=v"(tmp1) : "v"(g1) : "memory");
      }
      asm volatile("s_waitcnt vmcnt(0)" ::: "memory");
      __builtin_amdgcn_sched_barrier(0);
      {
        const int r0 = tid>>6, c0 = tid&63;
        *(f32x4*)&hlds[r0*256 + ((c0 ^ (r0&7))<<2)] = tmp0;
        const int r1 = (512+tid)>>6, c1 = tid&63;
        *(f32x4*)&hlds[r1*256 + ((c1 ^ (r1&7))<<2)] = tmp1;
      }
      __syncthreads();
    }

    f32x4 acc = {0.f,0.f,0.f,0.f};
    if (tt>0){
      #pragma unroll
      for (int kt=0; kt<8; ++kt){
        const int ch = (kh*8 + kt)*4 + (lane>>4);
        V16 a; a.f = *(const f32x4*)&hlds[rowb*256 + ((ch ^ (rowb&7))<<2)];
        acc = __builtin_amdgcn_mfma_f32_16x16x32_bf16(a.s, bfr[kt], acc, 0, 0, 0);
      }
    }
    if (kh==1) *(f32x4*)&red[(nt*64+lane)*4] = acc;
    __syncthreads();
    if (kh==0){
      const f32x4 o = *(const f32x4*)&red[(nt*64+lane)*4];
      #pragma unroll
      for (int i=0;i<4;i++){
        const int r = (lane>>4)*4 + i, c = lane&15;
        gbuf[nt*256 + r*16 + c] = acc[i] + o[i];
      }
    }
    __syncthreads();

    if (tid < 256){
      const float sx = src[bg*512+t]*0.001f;
      const int m = smask[bg*512+t];
      const float gi = gbuf[0*256+tid] + sx*p0 + q0;
      const float gf = gbuf[1*256+tid] + sx*p1 + q1;
      const float gg = gbuf[2*256+tid] + sx*p2 + q2;
      const float go = gbuf[3*256+tid] + sx*p3 + q3;
      const float cn = fmaf(sigm(gf), creg, sigm(gi)*tanhfast(gg));
      const float hn = sigm(go)*tanhfast(cn);
      const float hk = m ? hn : hprev;
      creg = m ? cn : creg;
      hprev = hk;
      hstage[tid] = bfbits(hk);
      estage[tid] = bfbits(m ? hn : 0.f);
    }
    __syncthreads();
    if (tid < 32){
      const int row = tid>>1, hw = tid&1;
      const f32x4 v = *(const f32x4*)(hstage + row*16 + hw*8);
      unsigned short* dst = hbuf + (((size_t)(dir*2+(tt&1))*64 + b0 + row)<<9) + us*16 + hw*8;
      asm volatile("global_store_dwordx4 %0, %1, off sc0 sc1" :: "v"(dst), "v"(v) : "memory");
    } else if (tid < 64){
      const int j = tid-32, row = j>>1, hw = j&1;
      const f32x4 v = *(const f32x4*)(estage + row*16 + hw*8);
      *(f32x4*)((unsigned short*)enc + ((size_t)((b0+row)*512 + t))*1024 + dir*512 + us*16 + hw*8) = v;
    }
    asm volatile("s_waitcnt vmcnt(0)" ::: "memory");
    __syncthreads();
    if (tid==0) __hip_atomic_fetch_add(gcnt, 1u, __ATOMIC_RELAXED, AGENT);
  }

  if (tid < 256){
    hfin[dir*32768 + bg*512 + ug] = hprev;
    (dir ? cb : cf)[bg*512 + ug] = creg;
  }
}

// ---------------- decoder init ----------------
__global__ void __launch_bounds__(256) fc_init(
  const float* __restrict__ hf0, const float* __restrict__ hb0,
  const float* __restrict__ cf, const float* __restrict__ cb,
  const float* __restrict__ fchW, const float* __restrict__ fchB,
  const float* __restrict__ fccW, const float* __restrict__ fccB,
  float* __restrict__ dech, float* __restrict__ decc)
{
  const int which = blockIdx.x >> 7;
  const int wid = blockIdx.x & 127;
  const int b = threadIdx.x >> 2, ul = threadIdx.x & 3;
  const int u = wid*4 + ul;
  const float* s0 = which ? cf : hf0;
  const float* s1 = which ? cb : hb0;
  const float* W = which ? fccW : fchW;
  float acc = (which ? fccB : fchB)[u];
  const float4* x0 = (const float4*)(s0 + b*512);
  const float4* x1 = (const float4*)(s1 + b*512);
  const float4* wr = (const float4*)(W + (size_t)u*1024);
  #pragma unroll 4
  for (int k=0;k<128;k++) acc += dot4(x0[k], wr[k]);
  #pragma unroll 4
  for (int k=0;k<128;k++) acc += dot4(x1[k], wr[128+k]);
  (which ? decc : dech)[b*512+u] = tanhfast(acc);
}

// ---------------- eh2[b][s][n] = enc_out @ Wenc.T (bf16, n contiguous) ----------------
__global__ void __launch_bounds__(512) eh_gemm(
  const __hip_bfloat16* __restrict__ enc, const float* __restrict__ WT,
  unsigned short* __restrict__ eh2)
{
  const int b = blockIdx.x >> 6;
  const int s = (blockIdx.x & 63)*8 + (threadIdx.x >> 6);
  const int n0 = (threadIdx.x & 63)*8;
  const __hip_bfloat16* ap = enc + ((size_t)(b*512 + s))*1024;
  float c0=0,c1=0,c2=0,c3=0,c4=0,c5=0,c6=0,c7=0;
  for (int k=0;k<1024;k++){
    const float a = __bfloat162float(ap[k]);
    const float4* w = (const float4*)(WT + (size_t)k*512 + n0);
    const float4 wA = w[0], wB = w[1];
    c0 = fmaf(a, wA.x, c0); c1 = fmaf(a, wA.y, c1);
    c2 = fmaf(a, wA.z, c2); c3 = fmaf(a, wA.w, c3);
    c4 = fmaf(a, wB.x, c4); c5 = fmaf(a, wB.y, c5);
    c6 = fmaf(a, wB.z, c6); c7 = fmaf(a, wB.w, c7);
  }
  unsigned short* op = eh2 + ((size_t)(b*512 + s))*512 + n0;
  uint4 v;
  v.x = (unsigned)bfbits(c0) | ((unsigned)bfbits(c1)<<16);
  v.y = (unsigned)bfbits(c2) | ((unsigned)bfbits(c3)<<16);
  v.z = (unsigned)bfbits(c4) | ((unsigned)bfbits(c5)<<16);
  v.w = (unsigned)bfbits(c6) | ((unsigned)bfbits(c7)<<16);
  *(uint4*)op = v;
}

// ---------------- encT2[b][j][s]: transpose of enc (s contiguous) ----------------
__global__ void __launch_bounds__(256) enc_tr(
  const unsigned short* __restrict__ enc, unsigned short* __restrict__ encT2)
{
  __shared__ unsigned short tl[64][80];  // pad: row stride 160B (16B-multiple)
  const int b = blockIdx.x>>7, st = (blockIdx.x>>4)&7, jt = blockIdx.x&15;
  const int r = threadIdx.x>>2, q = threadIdx.x&3;
  const unsigned short* src = enc + ((size_t)(b*512 + st*64 + r))*1024 + jt*64 + q*16;
  *(short8*)&tl[r][q*16]   = *(const short8*)src;
  *(short8*)&tl[r][q*16+8] = *(const short8*)(src+8);
  __syncthreads();
  unsigned short tmp[16];
  #pragma unroll
  for (int e=0;e<16;e++) tmp[e] = tl[q*16+e][r];
  unsigned short* dst = encT2 + ((size_t)(b*1024 + jt*64 + r))*512 + st*64 + q*16;
  *(short8*)dst     = *(short8*)&tmp[0];
  *(short8*)(dst+8) = *(short8*)&tmp[8];
}

// ---------------- barriers ----------------
__device__ __forceinline__ void gbar(unsigned* gctr, unsigned* root, int grp, unsigned gen){
  asm volatile("s_waitcnt vmcnt(0)" ::: "memory");
  __syncthreads();
  if (threadIdx.x==0){
    const unsigned old = __hip_atomic_fetch_add(gctr + grp*32, 1u, __ATOMIC_RELAXED, AGENT);
    if (old == gen*16u - 1u)
      __hip_atomic_fetch_add(root, 1u, __ATOMIC_RELAXED, AGENT);
    while (__hip_atomic_load(root, __ATOMIC_RELAXED, AGENT) < gen*16u)
      __builtin_amdgcn_s_sleep(1);
  }
  __syncthreads();
}
__device__ __forceinline__ void mbar(unsigned* mc, unsigned mgen){
  asm volatile("s_waitcnt vmcnt(0)" ::: "memory");
  __syncthreads();
  if (threadIdx.x==0){
    __hip_atomic_fetch_add(mc, 1u, __ATOMIC_RELAXED, AGENT);
    while (__hip_atomic_load(mc, __ATOMIC_RELAXED, AGENT) < mgen*4u)
      __builtin_amdgcn_s_sleep(1);
  }
  __syncthreads();
}

// ---------------- fused persistent decoder v3: contiguous reductions ----------------
__global__ void __launch_bounds__(512) dec_fused(
  const float* __restrict__ trg, const int* __restrict__ smask,
  const float* __restrict__ attnv,
  const unsigned short* __restrict__ eh2,    // [64][512 s][512 n]
  const unsigned short* __restrict__ encT2,  // [64][1024 j][512 s]
  const unsigned short* __restrict__ Wcat,
  const unsigned short* __restrict__ Wdecb,  // [512 j][512 u]
  const float* __restrict__ PQd, const float* __restrict__ hc,
  const float* __restrict__ valW, const float* __restrict__ stopW,
  const float* __restrict__ dech0, const float* __restrict__ decc0,
  float* __restrict__ scorep, float* __restrict__ ctxf,
  unsigned short* __restrict__ xbuf, float* __restrict__ gates,
  float* __restrict__ hcur, float* __restrict__ out,
  unsigned* __restrict__ gctr, unsigned* __restrict__ root, unsigned* __restrict__ mctr)
{
  __shared__ alignas(16) float redl[8192];
  __shared__ float vlds[512];
  __shared__ float hldsa[512];
  __shared__ float adhl[128];
  __shared__ float wlds[512];
  const int tid = threadIdx.x;
  const int bid = blockIdx.x;
  const int b = bid>>2, quad = bid&3;
  const int grp = bid>>4;
  const int lane = tid&63, wv = tid>>6;
  unsigned* mc = mctr + b*32;
  unsigned g = 0, m = 0;

  vlds[tid] = attnv[tid];

  short8 gw[6];
  if (bid < 128){
    const int n = bid*16 + (lane&15);
    const unsigned short* wp = Wcat + (size_t)n*1536 + wv*192 + (lane>>4)*8;
    #pragma unroll
    for (int ks=0;ks<6;ks++) gw[ks] = *(const short8*)(wp + ks*32);
  }

  const bool isb = (quad==0);
  float hr=0.f, cr=0.f;
  float pqi=0,pqf=0,pqg=0,pqo=0, qqi=0,qqf=0,qqg=0,qqo=0;
  float vwh=0,vwc0=0,vwc1=0, swh=0,swc0=0,swc1=0;
  if (isb){
    hr = dech0[b*512+tid]; cr = decc0[b*512+tid];
    pqi = PQd[tid];      pqf = PQd[512+tid];      pqg = PQd[1024+tid];      pqo = PQd[1536+tid];
    qqi = PQd[2048+tid]; qqf = PQd[2048+512+tid]; qqg = PQd[2048+1024+tid]; qqo = PQd[2048+1536+tid];
    vwh = valW[tid]; vwc0 = valW[512+tid]; vwc1 = valW[1024+tid];
    swh = stopW[tid]; swc0 = stopW[512+tid]; swc1 = stopW[1024+tid];
  }

  // ---- seed: h(0) -> xbuf + hcur ----
  if (isb){
    const unsigned hb16 = (unsigned)bfbits(hr);
    unsigned short* xp = xbuf + b*1536 + 1024 + tid;
    asm volatile("global_store_short %0, %1, off sc0 sc1" :: "v"(xp), "v"(hb16) : "memory");
    float* hp = hcur + b*512 + tid;
    asm volatile("global_store_dword %0, %1, off sc0 sc1" :: "v"(hp), "v"(hr) : "memory");
  }
  ++m; mbar(mc, m);

  for (int t=0; t<95; ++t){
    // ---- fused ADH (block-local j-chunk) + P2a score partials ----
    {
      float hv; const float* hp = hcur + b*512 + tid;
      asm volatile("global_load_dword %0, %1, off sc0 sc1\ns_waitcnt vmcnt(0)" : "=v"(hv) : "v"(hp) : "memory");
      hldsa[tid] = hv;
      __syncthreads();
      // adh[j] for j = quad*128 + (tid>>2); u-chunk (tid&3)*128, contiguous reads
      {
        const int jl = tid>>2, uc = tid&3;
        const unsigned short* wp = Wdecb + (size_t)(quad*128 + jl)*512 + uc*128;
        float a = 0.f;
        #pragma unroll
        for (int i=0;i<16;i++){
          const short8 w8 = *(const short8*)(wp + i*8);
          #pragma unroll
          for (int e=0;e<8;e++)
            a = fmaf(hldsa[uc*128 + i*8 + e], bfu2f((unsigned short)w8[e]), a);
        }
        redl[tid] = a;   // tid = jl*4 + uc
      }
      __syncthreads();
      if (tid < 128)
        adhl[tid] = redl[tid*4] + redl[tid*4+1] + redl[tid*4+2] + redl[tid*4+3];
      __syncthreads();
      // score partial over n-chunk quad*128..+128 for s = tid (contiguous 256B read)
      {
        const unsigned short* ep = eh2 + ((size_t)(b*512 + tid))*512 + quad*128;
        float part = 0.f;
        #pragma unroll
        for (int i=0;i<16;i++){
          const short8 e8 = *(const short8*)(ep + i*8);
          #pragma unroll
          for (int e=0;e<8;e++){
            const int n = i*8 + e;
            part = fmaf(vlds[quad*128+n], tanhfast(adhl[n] + bfu2f((unsigned short)e8[e])), part);
          }
        }
        float* sp = scorep + (size_t)bid*512 + tid;
        asm volatile("global_store_dword %0, %1, off sc0 sc1" :: "v"(sp), "v"(part) : "memory");
      }
    }
    ++m; mbar(mc, m);

    // ---- P2b: softmax + ctx quarter (s-contiguous encT2 reads) ----
    {
      float pa, pb, pc, pd;
      const float* pp = scorep + (size_t)(b*4)*512 + tid;
      asm volatile("global_load_dword %0, %1, off sc0 sc1" : "=v"(pa) : "v"(pp) : "memory");
      asm volatile("global_load_dword %0, %1, off sc0 sc1" : "=v"(pb) : "v"(pp+512) : "memory");
      asm volatile("global_load_dword %0, %1, off sc0 sc1" : "=v"(pc) : "v"(pp+1024) : "memory");
      asm volatile("global_load_dword %0, %1, off sc0 sc1" : "=v"(pd) : "v"(pp+1536) : "memory");
      asm volatile("s_waitcnt vmcnt(0)" ::: "memory");
      __builtin_amdgcn_sched_barrier(0);
      float s0 = (pa+pb)+(pc+pd);
      s0 = smask[b*512+tid] ? s0 : -1.0e9f;
      redl[512+tid] = s0;
      __syncthreads();
      for (int off=256; off>0; off>>=1){
        if (tid<off) redl[512+tid] = fmaxf(redl[512+tid], redl[512+tid+off]);
        __syncthreads();
      }
      const float mx = redl[512];
      __syncthreads();
      const float e = __expf(s0 - mx);
      redl[512+tid] = e;
      __syncthreads();
      for (int off=256; off>0; off>>=1){
        if (tid<off) redl[512+tid] += redl[512+tid+off];
        __syncthreads();
      }
      const float Z = redl[512];
      __syncthreads();
      wlds[tid] = e / Z;
      __syncthreads();
      // ctx[j] for j = quad*256 + (tid>>1); s-half (tid&1)*256, contiguous 512B reads
      {
        const int jj = tid>>1, sh = tid&1;
        const unsigned short* cp = encT2 + ((size_t)(b*1024 + quad*256 + jj))*512 + sh*256;
        float c = 0.f;
        #pragma unroll
        for (int i=0;i<32;i++){
          const short8 c8 = *(const short8*)(cp + i*8);
          #pragma unroll
          for (int e=0;e<8;e++)
            c = fmaf(wlds[sh*256 + i*8 + e], bfu2f((unsigned short)c8[e]), c);
        }
        redl[tid] = c;   // tid = jj*2 + sh
      }
      __syncthreads();
      if (tid < 256){
        const float cv = redl[tid*2] + redl[tid*2+1];
        const int j = quad*256 + tid;
        float* cp2 = ctxf + b*1024 + j;
        asm volatile("global_store_dword %0, %1, off sc0 sc1" :: "v"(cp2), "v"(cv) : "memory");
        const unsigned cb16 = (unsigned)bfbits(cv);
        unsigned short* xp = xbuf + b*1536 + j;
        asm volatile("global_store_short %0, %1, off sc0 sc1" :: "v"(xp), "v"(cb16) : "memory");
      }
    }
    ++g; gbar(gctr, root, grp, g);

    // ---- P4: gates MFMA (bid<128) ----
    if (bid < 128){
      f32x4 av[2][6];
      f32x4 acc[4] = {{0,0,0,0},{0,0,0,0},{0,0,0,0},{0,0,0,0}};
      {
        const unsigned short* xp0 = xbuf + (size_t)(lane&15)*1536 + wv*192 + (lane>>4)*8;
        #pragma unroll
        for (int ks=0;ks<6;ks++){
          const unsigned short* p = xp0 + ks*32;
          asm volatile("global_load_dwordx4 %0, %1, off sc0 sc1" : "=v"(av[0][ks]) : "v"(p) : "memory");
        }
      }
      #pragma unroll
      for (int mt=0; mt<4; ++mt){
        if (mt<3){
          const unsigned short* xpn = xbuf + (size_t)((mt+1)*16 + (lane&15))*1536 + wv*192 + (lane>>4)*8;
          #pragma unroll
          for (int ks=0;ks<6;ks++){
            const unsigned short* p = xpn + ks*32;
            asm volatile("global_load_dwordx4 %0, %1, off sc0 sc1" : "=v"(av[(mt+1)&1][ks]) : "v"(p) : "memory");
          }
          asm volatile("s_waitcnt vmcnt(6)" ::: "memory");
        } else {
          asm volatile("s_waitcnt vmcnt(0)" ::: "memory");
        }
        __builtin_amdgcn_sched_barrier(0);
        #pragma unroll
        for (int ks=0;ks<6;ks++){
          V16 a; a.f = av[mt&1][ks];
          acc[mt] = __builtin_amdgcn_mfma_f32_16x16x32_bf16(a.s, gw[ks], acc[mt], 0, 0, 0);
        }
      }
      #pragma unroll
      for (int mt=0; mt<4; ++mt)
        *(f32x4*)&redl[wv*1024 + lane*16 + mt*4] = acc[mt];
    }
    __syncthreads();
    if (bid < 128){
      #pragma unroll
      for (int h2=0; h2<2; ++h2){
        const int o = h2*512 + tid;
        const int ob = o>>4, col = o&15;
        const int mt = ob>>4, row = ob&15;
        const int base = (((row>>2)<<4) | col)*16 + mt*4 + (row&3);
        float gsum = 0.f;
        #pragma unroll
        for (int w2=0; w2<8; ++w2) gsum += redl[w2*1024 + base];
        float* gp = gates + ob*2048 + bid*16 + col;
        asm volatile("global_store_dword %0, %1, off sc0 sc1" :: "v"(gp), "v"(gsum) : "memory");
      }
    }
    ++g; gbar(gctr, root, grp, g);

    // ---- P5: cell update + heads (quad==0) ----
    if (isb){
      float g4[4], c0v, c1v;
      {
        const float* gp = gates + b*2048 + tid;
        const float* cp = ctxf + b*1024 + tid;
        asm volatile("global_load_dword %0, %1, off sc0 sc1" : "=v"(g4[0]) : "v"(gp) : "memory");
        asm volatile("global_load_dword %0, %1, off sc0 sc1" : "=v"(g4[1]) : "v"(gp+512) : "memory");
        asm volatile("global_load_dword %0, %1, off sc0 sc1" : "=v"(g4[2]) : "v"(gp+1024) : "memory");
        asm volatile("global_load_dword %0, %1, off sc0 sc1" : "=v"(g4[3]) : "v"(gp+1536) : "memory");
        asm volatile("global_load_dword %0, %1, off sc0 sc1" : "=v"(c0v) : "v"(cp) : "memory");
        asm volatile("global_load_dword %0, %1, off sc0 sc1" : "=v"(c1v) : "v"(cp+512) : "memory");
        asm volatile("s_waitcnt vmcnt(0)" ::: "memory");
        __builtin_amdgcn_sched_barrier(0);
      }
      const float x = trg[b*96 + t]*0.001f;
      const float gi = g4[0] + x*pqi + qqi;
      const float gf = g4[1] + x*pqf + qqf;
      const float gg = g4[2] + x*pqg + qqg;
      const float go = g4[3] + x*pqo + qqo;
      const float cn = fmaf(sigm(gf), cr, sigm(gi)*tanhfast(gg));
      const float hn = sigm(go)*tanhfast(cn);
      cr = cn; hr = hn;
      const unsigned hb16 = (unsigned)bfbits(hn);
      unsigned short* xp = xbuf + b*1536 + 1024 + tid;
      asm volatile("global_store_short %0, %1, off sc0 sc1" :: "v"(xp), "v"(hb16) : "memory");
      float* hp = hcur + b*512 + tid;
      asm volatile("global_store_dword %0, %1, off sc0 sc1" :: "v"(hp), "v"(hn) : "memory");
      redl[512+tid]  = fmaf(hn, vwh, fmaf(c0v, vwc0, c1v*vwc1));
      redl[1024+tid] = fmaf(hn, swh, fmaf(c0v, swc0, c1v*swc1));
      __syncthreads();
      for (int off=256; off>0; off>>=1){
        if (tid<off){ redl[512+tid]+=redl[512+tid+off]; redl[1024+tid]+=redl[1024+tid+off]; }
        __syncthreads();
      }
      if (tid==0){
        out[b*95 + t] = (redl[512] + x*hc[0] + hc[1])*1000.f;
        out[6080 + b*95 + t] = redl[1024] + x*hc[2] + hc[3];
      }
    }
    ++m; mbar(mc, m);
  }
}

// ---------------- launch ----------------
extern "C" void kernel_launch(void* const* d_in, const int* in_sizes, int n_in,
                              void* d_out, int out_size, void* d_ws, size_t ws_size,
                              hipStream_t stream)
{
  (void)in_sizes; (void)n_in; (void)out_size; (void)ws_size;
  const float* src   = (const float*)d_in[0];
  const int*   smask = (const int*)  d_in[1];
  const float* trg   = (const float*)d_in[2];
  const float* epW   = (const float*)d_in[4];
  const float* epb   = (const float*)d_in[5];
  const float* Wihf  = (const float*)d_in[6];
  const float* Whhf  = (const float*)d_in[7];
  const float* bihf  = (const float*)d_in[8];
  const float* bhhf  = (const float*)d_in[9];
  const float* Wihb  = (const float*)d_in[10];
  const float* Whhb  = (const float*)d_in[11];
  const float* bihb  = (const float*)d_in[12];
  const float* bhhb  = (const float*)d_in[13];
  const float* fchW  = (const float*)d_in[14];
  const float* fchB  = (const float*)d_in[15];
  const float* fccW  = (const float*)d_in[16];
  const float* fccB  = (const float*)d_in[17];
  const float* dpW   = (const float*)d_in[18];
  const float* dpb   = (const float*)d_in[19];
  const float* Wenc  = (const float*)d_in[20];
  const float* Wdec  = (const float*)d_in[21];
  const float* attnv = (const float*)d_in[22];
  const float* dWih  = (const float*)d_in[23];
  const float* dWhh  = (const float*)d_in[24];
  const float* dbih  = (const float*)d_in[25];
  const float* dbhh  = (const float*)d_in[26];
  const float* valW  = (const float*)d_in[27];
  const float* valb  = (const float*)d_in[28];
  const float* stopW = (const float*)d_in[29];
  const float* stopb = (const float*)d_in[30];
  float* out = (float*)d_out;

  // ---- bump allocator (round-7 lesson: never hand-compute offsets) ----
  char* ws = (char*)d_ws;
  size_t off = 0;
  auto take = [&](size_t nbytes) -> char* {
    char* p = ws + off;
    off += (nbytes + 255) & ~(size_t)255;
    return p;
  };
  unsigned short* enc   = (unsigned short*)take((size_t)64*512*1024*2);  // 64 MiB
  unsigned short* eh2   = (unsigned short*)take((size_t)64*512*512*2);   // 32 MiB
  unsigned short* encT2 = (unsigned short*)take((size_t)64*1024*512*2);  // 64 MiB
  unsigned short* hbuf  = (unsigned short*)take(2*2*64*512*2);
  unsigned short* Wbf   = (unsigned short*)take((size_t)2*2048*512*2);
  unsigned short* Wcat  = (unsigned short*)take((size_t)2048*1536*2);
  unsigned short* Wdecb = (unsigned short*)take(512*512*2);
  float* WT    = (float*)take((size_t)1024*512*4);
  float* hfin  = (float*)take(2*64*512*4);
  float* cf    = (float*)take(64*512*4);
  float* cb    = (float*)take(64*512*4);
  float* PQ    = (float*)take(6*2048*4);
  float* dech0 = (float*)take(64*512*4);
  float* decc0 = (float*)take(64*512*4);
  float* scorep= (float*)take(256*512*4);
  float* ctxf  = (float*)take(64*1024*4);
  unsigned short* xbuf = (unsigned short*)take(64*1536*2);
  float* gates = (float*)take(64*2048*4);
  float* hcur  = (float*)take(64*512*4);
  float* hc    = (float*)take(128);
  unsigned* cnt  = (unsigned*)take(1024);
  unsigned* gctr = (unsigned*)take(2048);
  unsigned* root = (unsigned*)take(256);
  unsigned* mctr = (unsigned*)take(8192);
  float* PQd = PQ + 8192;
  (void)hipMemsetAsync(cnt, 0, 1024+2048+256+8192, stream);

  precompute<<<2097, 256, 0, stream>>>(Wenc, Wihf, epW, epb, bihf, bhhf, Wihb, bihb, bhhb,
                                       dWih, dpW, dpb, dbih, dbhh, valW, valb, stopW, stopb,
                                       PQ, WT, hc);
  wconv<<<10752, 512, 0, stream>>>(Whhf, Whhb, dWih, dWhh, Wdec, Wbf, Wcat, Wdecb);

  {
    void* args[] = { (void*)&src, (void*)&smask, (void*)&Wbf, (void*)&PQ,
                     (void*)&hbuf, (void*)&hfin, (void*)&cf, (void*)&cb, (void*)&enc, (void*)&cnt };
    (void)hipLaunchCooperativeKernel((void*)enc_mfma, dim3(256), dim3(512), args, 0, stream);
  }

  {
    const float* hfF = hfin;
    const float* hbF = hfin + 32768;
    fc_init<<<256, 256, 0, stream>>>(hfF, hbF, cf, cb, fchW, fchB, fccW, fccB, dech0, decc0);
  }
  eh_gemm<<<4096, 512, 0, stream>>>((const __hip_bfloat16*)enc, WT, eh2);
  enc_tr<<<8192, 256, 0, stream>>>(enc, encT2);

  {
    void* args[] = { (void*)&trg, (void*)&smask, (void*)&attnv,
                     (void*)&eh2, (void*)&encT2, (void*)&Wcat, (void*)&Wdecb,
                     (void*)&PQd, (void*)&hc, (void*)&valW, (void*)&stopW,
                     (void*)&dech0, (void*)&decc0,
                     (void*)&scorep, (void*)&ctxf,
                     (void*)&xbuf, (void*)&gates, (void*)&hcur, (void*)&out,
                     (void*)&gctr, (void*)&root, (void*)&mctr };
    (void)hipLaunchCooperativeKernel((void*)dec_fused, dim3(256), dim3(512), args, 0, stream);
  }
}

// Round 11
// 7061.398 us; speedup vs baseline: 10.6833x; 1.2559x over previous
//
#include <hip/hip_runtime.h>
#include <hip/hip_bf16.h>

#define AGENT __HIP_MEMORY_SCOPE_AGENT

typedef float f32x4 __attribute__((ext_vector_type(4)));
typedef short short8 __attribute__((ext_vector_type(8)));
union V16 { f32x4 f; short8 s; };

// B=64 S=512 T=96 E=256 H=512 ENC_DIM=1024 4H=2048

__device__ __forceinline__ float sigm(float x){ return 1.f/(1.f+__expf(-x)); }
__device__ __forceinline__ float tanhfast(float x){
  float ax = fabsf(x);
  float e = __expf(-2.f*ax);
  float r = (1.f-e)/(1.f+e);
  return copysignf(r, x);
}
__device__ __forceinline__ float dot4(float4 a, float4 b){
  return fmaf(a.x,b.x, fmaf(a.y,b.y, fmaf(a.z,b.z, a.w*b.w)));
}
__device__ __forceinline__ unsigned short bfbits(float x){
  return __bfloat16_as_ushort(__float2bfloat16(x));
}
__device__ __forceinline__ float bfu2f(unsigned short u){
  union{unsigned v; float f;} x; x.v = ((unsigned)u)<<16; return x.f;
}

// ---------------- precompute ----------------
__global__ void __launch_bounds__(256) precompute(
  const float* __restrict__ Wenc,
  const float* __restrict__ Wihf, const float* __restrict__ epW, const float* __restrict__ epb,
  const float* __restrict__ bihf, const float* __restrict__ bhhf,
  const float* __restrict__ Wihb, const float* __restrict__ bihb, const float* __restrict__ bhhb,
  const float* __restrict__ dWih, const float* __restrict__ dpW, const float* __restrict__ dpb,
  const float* __restrict__ dbih, const float* __restrict__ dbhh,
  const float* __restrict__ valW, const float* __restrict__ valb,
  const float* __restrict__ stopW, const float* __restrict__ stopb,
  float* __restrict__ PQ, float* __restrict__ WT, float* __restrict__ hc)
{
  const int idx = blockIdx.x*256 + threadIdx.x;
  if (idx < 524288){
    const int j = idx >> 9, n = idx & 511;
    WT[idx] = Wenc[(size_t)n*1024 + j];
  } else if (idx < 524288 + 6*2048){
    const int q = idx - 524288;
    const int set = q >> 11, j = q & 2047;
    const float* row; const float* vec; float add = 0.f;
    switch(set){
      case 0: row = Wihf + (size_t)j*256; vec = epW; break;
      case 1: row = Wihf + (size_t)j*256; vec = epb; add = bihf[j]+bhhf[j]; break;
      case 2: row = Wihb + (size_t)j*256; vec = epW; break;
      case 3: row = Wihb + (size_t)j*256; vec = epb; add = bihb[j]+bhhb[j]; break;
      case 4: row = dWih + (size_t)j*1280; vec = dpW; break;
      default: row = dWih + (size_t)j*1280; vec = dpb; add = dbih[j]+dbhh[j]; break;
    }
    float a = add;
    for (int e=0;e<256;e++) a = fmaf(row[e], vec[e], a);
    PQ[set*2048 + j] = a;
  } else if (idx < 524288 + 6*2048 + 4){
    const int q = idx - (524288 + 6*2048);
    const float* wrow = (q<2) ? valW : stopW;
    const float* vec  = (q&1) ? dpb : dpW;
    float a = (q&1) ? ((q<2)? valb[0] : stopb[0]) : 0.f;
    for (int e=0;e<256;e++) a = fmaf(wrow[1536+e], vec[e], a);
    hc[q] = a;
  }
}

// ---------------- weight converts ----------------
__global__ void __launch_bounds__(512) wconv(
  const float* __restrict__ Whhf, const float* __restrict__ Whhb,
  const float* __restrict__ dWih, const float* __restrict__ dWhh,
  const float* __restrict__ Wdec, const float* __restrict__ Wenc,
  unsigned short* __restrict__ Wbf, unsigned short* __restrict__ Wcat,
  unsigned short* __restrict__ Wdecb, unsigned short* __restrict__ Wencb)
{
  const int i = blockIdx.x*512 + threadIdx.x;
  if (i < 2097152){
    const float v = (i < 1048576) ? Whhf[i] : Whhb[i-1048576];
    Wbf[i] = bfbits(v);
  } else if (i < 2097152+3145728){
    const int q = i - 2097152;
    const int r = q/1536, k = q - r*1536;
    const float v = (k<1024) ? dWih[(size_t)r*1280 + 256 + k] : dWhh[(size_t)r*512 + (k-1024)];
    Wcat[q] = bfbits(v);
  } else if (i < 2097152+3145728+262144){
    const int q = i - (2097152+3145728);
    Wdecb[q] = bfbits(Wdec[q]);   // row-major [j][u]
  } else if (i < 2097152+3145728+262144+524288){
    const int q = i - (2097152+3145728+262144);
    Wencb[q] = bfbits(Wenc[q]);   // row-major [n][k]
  }
}

// ---------------- encoder (unchanged, proven) ----------------
__global__ void __launch_bounds__(512) enc_mfma(
    const float* __restrict__ src, const int* __restrict__ smask,
    const unsigned short* __restrict__ Wbf,
    const float* __restrict__ PQ,
    unsigned short* __restrict__ hbuf,
    float* __restrict__ hfin,
    float* __restrict__ cf, float* __restrict__ cb,
    __hip_bfloat16* __restrict__ enc,
    unsigned* __restrict__ cnt)
{
  __shared__ float hlds[16*256];
  __shared__ float red[4*64*4];
  __shared__ float gbuf[4*256];
  __shared__ alignas(16) unsigned short hstage[256];
  __shared__ alignas(16) unsigned short estage[256];

  const int tid = threadIdx.x;
  const int bid = blockIdx.x;
  const int dir = bid>>7, bhalf = (bid>>5)&3, us = bid&31;
  const int b0 = bhalf*16;
  unsigned* gcnt = cnt + (dir*4 + bhalf)*32;
  const int wv = tid>>6, lane = tid&63;
  const int nt = wv&3, kh = wv>>2;
  const int rowb = lane&15;

  short8 bfr[8];
  {
    const int g = nt*512 + us*16 + (lane&15);
    const unsigned short* wp = Wbf + ((size_t)dir*2048 + g)*512 + kh*256 + (lane>>4)*8;
    #pragma unroll
    for (int kt=0;kt<8;kt++) bfr[kt] = *(const short8*)(wp + kt*32);
  }

  float p0=0,p1=0,p2=0,p3=0,q0=0,q1=0,q2=0,q3=0;
  float creg = 0.f, hprev = 0.f;
  int bg = 0, ug = 0;
  if (tid < 256){
    bg = b0 + (tid>>4);
    ug = us*16 + (tid&15);
    const float* P = PQ + dir*4096; const float* Q = P + 2048;
    p0=P[ug]; p1=P[ug+512]; p2=P[ug+1024]; p3=P[ug+1536];
    q0=Q[ug]; q1=Q[ug+512]; q2=Q[ug+1024]; q3=Q[ug+1536];
  }

  for (int tt=0; tt<512; ++tt){
    const int t = dir ? (511-tt) : tt;
    if (tt>0){
      if (tid==0){
        while (__hip_atomic_load(gcnt, __ATOMIC_RELAXED, AGENT) < 32u*(unsigned)tt)
          __builtin_amdgcn_s_sleep(1);
      }
      __syncthreads();
      const int par = (tt-1)&1;
      f32x4 tmp0, tmp1;
      {
        const int f0 = tid, f1 = 512 + tid;
        const unsigned short* g0 = hbuf + (((size_t)(dir*2+par)*64 + b0 + (f0>>6))<<9) + (f0&63)*8;
        const unsigned short* g1 = hbuf + (((size_t)(dir*2+par)*64 + b0 + (f1>>6))<<9) + (f1&63)*8;
        asm volatile("global_load_dwordx4 %0, %1, off sc0 sc1" : "=v"(tmp0) : "v"(g0) : "memory");
        asm volatile("global_load_dwordx4 %0, %1, off sc0 sc1" : "=v"(tmp1) : "v"(g1) : "memory");
      }
      asm volatile("s_waitcnt vmcnt(0)" ::: "memory");
      __builtin_amdgcn_sched_barrier(0);
      {
        const int r0 = tid>>6, c0 = tid&63;
        *(f32x4*)&hlds[r0*256 + ((c0 ^ (r0&7))<<2)] = tmp0;
        const int r1 = (512+tid)>>6, c1 = tid&63;
        *(f32x4*)&hlds[r1*256 + ((c1 ^ (r1&7))<<2)] = tmp1;
      }
      __syncthreads();
    }

    f32x4 acc = {0.f,0.f,0.f,0.f};
    if (tt>0){
      #pragma unroll
      for (int kt=0; kt<8; ++kt){
        const int ch = (kh*8 + kt)*4 + (lane>>4);
        V16 a; a.f = *(const f32x4*)&hlds[rowb*256 + ((ch ^ (rowb&7))<<2)];
        acc = __builtin_amdgcn_mfma_f32_16x16x32_bf16(a.s, bfr[kt], acc, 0, 0, 0);
      }
    }
    if (kh==1) *(f32x4*)&red[(nt*64+lane)*4] = acc;
    __syncthreads();
    if (kh==0){
      const f32x4 o = *(const f32x4*)&red[(nt*64+lane)*4];
      #pragma unroll
      for (int i=0;i<4;i++){
        const int r = (lane>>4)*4 + i, c = lane&15;
        gbuf[nt*256 + r*16 + c] = acc[i] + o[i];
      }
    }
    __syncthreads();

    if (tid < 256){
      const float sx = src[bg*512+t]*0.001f;
      const int m = smask[bg*512+t];
      const float gi = gbuf[0*256+tid] + sx*p0 + q0;
      const float gf = gbuf[1*256+tid] + sx*p1 + q1;
      const float gg = gbuf[2*256+tid] + sx*p2 + q2;
      const float go = gbuf[3*256+tid] + sx*p3 + q3;
      const float cn = fmaf(sigm(gf), creg, sigm(gi)*tanhfast(gg));
      const float hn = sigm(go)*tanhfast(cn);
      const float hk = m ? hn : hprev;
      creg = m ? cn : creg;
      hprev = hk;
      hstage[tid] = bfbits(hk);
      estage[tid] = bfbits(m ? hn : 0.f);
    }
    __syncthreads();
    if (tid < 32){
      const int row = tid>>1, hw = tid&1;
      const f32x4 v = *(const f32x4*)(hstage + row*16 + hw*8);
      unsigned short* dst = hbuf + (((size_t)(dir*2+(tt&1))*64 + b0 + row)<<9) + us*16 + hw*8;
      asm volatile("global_store_dwordx4 %0, %1, off sc0 sc1" :: "v"(dst), "v"(v) : "memory");
    } else if (tid < 64){
      const int j = tid-32, row = j>>1, hw = j&1;
      const f32x4 v = *(const f32x4*)(estage + row*16 + hw*8);
      *(f32x4*)((unsigned short*)enc + ((size_t)((b0+row)*512 + t))*1024 + dir*512 + us*16 + hw*8) = v;
    }
    asm volatile("s_waitcnt vmcnt(0)" ::: "memory");
    __syncthreads();
    if (tid==0) __hip_atomic_fetch_add(gcnt, 1u, __ATOMIC_RELAXED, AGENT);
  }

  if (tid < 256){
    hfin[dir*32768 + bg*512 + ug] = hprev;
    (dir ? cb : cf)[bg*512 + ug] = creg;
  }
}

// ---------------- decoder init ----------------
__global__ void __launch_bounds__(256) fc_init(
  const float* __restrict__ hf0, const float* __restrict__ hb0,
  const float* __restrict__ cf, const float* __restrict__ cb,
  const float* __restrict__ fchW, const float* __restrict__ fchB,
  const float* __restrict__ fccW, const float* __restrict__ fccB,
  float* __restrict__ dech, float* __restrict__ decc)
{
  const int which = blockIdx.x >> 7;
  const int wid = blockIdx.x & 127;
  const int b = threadIdx.x >> 2, ul = threadIdx.x & 3;
  const int u = wid*4 + ul;
  const float* s0 = which ? cf : hf0;
  const float* s1 = which ? cb : hb0;
  const float* W = which ? fccW : fchW;
  float acc = (which ? fccB : fchB)[u];
  const float4* x0 = (const float4*)(s0 + b*512);
  const float4* x1 = (const float4*)(s1 + b*512);
  const float4* wr = (const float4*)(W + (size_t)u*1024);
  #pragma unroll 4
  for (int k=0;k<128;k++) acc += dot4(x0[k], wr[k]);
  #pragma unroll 4
  for (int k=0;k<128;k++) acc += dot4(x1[k], wr[128+k]);
  (which ? decc : dech)[b*512+u] = tanhfast(acc);
}

// ---------------- eh2 via MFMA: eh2[b][s][n] = enc[b] @ Wencb^T ----------------
__global__ void __launch_bounds__(256) eh_mfma(
  const unsigned short* __restrict__ enc,    // [64][512][1024]
  const unsigned short* __restrict__ Wencb,  // [512 n][1024 k]
  unsigned short* __restrict__ eh2)          // [64][512][512]
{
  const int b = blockIdx.x>>6, st = (blockIdx.x>>3)&7, nt0 = blockIdx.x&7;
  const int wv = threadIdx.x>>6, lane = threadIdx.x&63;
  const int sA = st*64 + wv*16 + (lane&15);
  const int kb = (lane>>4)*8;
  const unsigned short* ap  = enc + ((size_t)(b*512 + sA))*1024 + kb;
  const unsigned short* bp0 = Wencb + ((size_t)(nt0*64 + (lane&15)))*1024 + kb;
  f32x4 acc[4] = {{0,0,0,0},{0,0,0,0},{0,0,0,0},{0,0,0,0}};
  for (int k0=0; k0<1024; k0+=32){
    V16 a; a.f = *(const f32x4*)(ap + k0);
    #pragma unroll
    for (int nt=0; nt<4; ++nt){
      V16 bb; bb.f = *(const f32x4*)(bp0 + (size_t)nt*16*1024 + k0);
      acc[nt] = __builtin_amdgcn_mfma_f32_16x16x32_bf16(a.s, bb.s, acc[nt], 0, 0, 0);
    }
  }
  const int sO = st*64 + wv*16 + (lane>>4)*4;
  const int col = lane&15;
  #pragma unroll
  for (int nt=0; nt<4; ++nt){
    #pragma unroll
    for (int i=0;i<4;i++){
      eh2[((size_t)(b*512 + sO + i))*512 + nt0*64 + nt*16 + col] = bfbits(acc[nt][i]);
    }
  }
}

// ---------------- encT2[b][j][s]: transpose of enc (s contiguous) ----------------
__global__ void __launch_bounds__(256) enc_tr(
  const unsigned short* __restrict__ enc, unsigned short* __restrict__ encT2)
{
  __shared__ unsigned short tl[64][80];
  const int b = blockIdx.x>>7, st = (blockIdx.x>>4)&7, jt = blockIdx.x&15;
  const int r = threadIdx.x>>2, q = threadIdx.x&3;
  const unsigned short* src = enc + ((size_t)(b*512 + st*64 + r))*1024 + jt*64 + q*16;
  *(short8*)&tl[r][q*16]   = *(const short8*)src;
  *(short8*)&tl[r][q*16+8] = *(const short8*)(src+8);
  __syncthreads();
  unsigned short tmp[16];
  #pragma unroll
  for (int e=0;e<16;e++) tmp[e] = tl[q*16+e][r];
  unsigned short* dst = encT2 + ((size_t)(b*1024 + jt*64 + r))*512 + st*64 + q*16;
  *(short8*)dst     = *(short8*)&tmp[0];
  *(short8*)(dst+8) = *(short8*)&tmp[8];
}

// ---------------- barriers ----------------
template<int NG>
__device__ __forceinline__ void gbar(unsigned* gctr, unsigned* root, int grp, unsigned gen){
  asm volatile("s_waitcnt vmcnt(0)" ::: "memory");
  __syncthreads();
  if (threadIdx.x==0){
    const unsigned old = __hip_atomic_fetch_add(gctr + grp*32, 1u, __ATOMIC_RELAXED, AGENT);
    if (old == gen*16u - 1u)
      __hip_atomic_fetch_add(root, 1u, __ATOMIC_RELAXED, AGENT);
    while (__hip_atomic_load(root, __ATOMIC_RELAXED, AGENT) < gen*(unsigned)NG)
      __builtin_amdgcn_s_sleep(1);
  }
  __syncthreads();
}
template<int NB>
__device__ __forceinline__ void mbar(unsigned* mc, unsigned mgen){
  asm volatile("s_waitcnt vmcnt(0)" ::: "memory");
  __syncthreads();
  if (threadIdx.x==0){
    __hip_atomic_fetch_add(mc, 1u, __ATOMIC_RELAXED, AGENT);
    while (__hip_atomic_load(mc, __ATOMIC_RELAXED, AGENT) < mgen*(unsigned)NB)
      __builtin_amdgcn_s_sleep(1);
  }
  __syncthreads();
}

// ---------------- fused persistent decoder: 256-block quad version (round 9, proven) ----------------
__global__ void __launch_bounds__(512) dec_fused256(
  const float* __restrict__ trg, const int* __restrict__ smask,
  const float* __restrict__ attnv,
  const unsigned short* __restrict__ eh2,
  const unsigned short* __restrict__ encT2,
  const unsigned short* __restrict__ Wcat,
  const unsigned short* __restrict__ Wdecb,
  const float* __restrict__ PQd, const float* __restrict__ hc,
  const float* __restrict__ valW, const float* __restrict__ stopW,
  const float* __restrict__ dech0, const float* __restrict__ decc0,
  float* __restrict__ scorep, float* __restrict__ ctxf,
  unsigned short* __restrict__ xbuf, float* __restrict__ gates,
  float* __restrict__ hcur, float* __restrict__ out,
  unsigned* __restrict__ gctr, unsigned* __restrict__ root, unsigned* __restrict__ mctr)
{
  __shared__ alignas(16) float redl[8192];
  __shared__ float vlds[512];
  __shared__ float hldsa[512];
  __shared__ float adhl[128];
  __shared__ float wlds[512];
  const int tid = threadIdx.x;
  const int bid = blockIdx.x;
  const int b = bid>>2, quad = bid&3;
  const int grp = bid>>4;
  const int lane = tid&63, wv = tid>>6;
  unsigned* mc = mctr + b*32;
  unsigned g = 0, m = 0;

  vlds[tid] = attnv[tid];

  short8 gw[6];
  if (bid < 128){
    const int n = bid*16 + (lane&15);
    const unsigned short* wp = Wcat + (size_t)n*1536 + wv*192 + (lane>>4)*8;
    #pragma unroll
    for (int ks=0;ks<6;ks++) gw[ks] = *(const short8*)(wp + ks*32);
  }

  const bool isb = (quad==0);
  float hr=0.f, cr=0.f;
  float pqi=0,pqf=0,pqg=0,pqo=0, qqi=0,qqf=0,qqg=0,qqo=0;
  float vwh=0,vwc0=0,vwc1=0, swh=0,swc0=0,swc1=0;
  if (isb){
    hr = dech0[b*512+tid]; cr = decc0[b*512+tid];
    pqi = PQd[tid];      pqf = PQd[512+tid];      pqg = PQd[1024+tid];      pqo = PQd[1536+tid];
    qqi = PQd[2048+tid]; qqf = PQd[2048+512+tid]; qqg = PQd[2048+1024+tid]; qqo = PQd[2048+1536+tid];
    vwh = valW[tid]; vwc0 = valW[512+tid]; vwc1 = valW[1024+tid];
    swh = stopW[tid]; swc0 = stopW[512+tid]; swc1 = stopW[1024+tid];
  }

  if (isb){
    const unsigned hb16 = (unsigned)bfbits(hr);
    unsigned short* xp = xbuf + b*1536 + 1024 + tid;
    asm volatile("global_store_short %0, %1, off sc0 sc1" :: "v"(xp), "v"(hb16) : "memory");
    float* hp = hcur + b*512 + tid;
    asm volatile("global_store_dword %0, %1, off sc0 sc1" :: "v"(hp), "v"(hr) : "memory");
  }
  ++m; mbar<4>(mc, m);

  for (int t=0; t<95; ++t){
    {
      float hv; const float* hp = hcur + b*512 + tid;
      asm volatile("global_load_dword %0, %1, off sc0 sc1\ns_waitcnt vmcnt(0)" : "=v"(hv) : "v"(hp) : "memory");
      hldsa[tid] = hv;
      __syncthreads();
      {
        const int jl = tid>>2, uc = tid&3;
        const unsigned short* wp = Wdecb + (size_t)(quad*128 + jl)*512 + uc*128;
        float a = 0.f;
        #pragma unroll
        for (int i=0;i<16;i++){
          const short8 w8 = *(const short8*)(wp + i*8);
          #pragma unroll
          for (int e=0;e<8;e++)
            a = fmaf(hldsa[uc*128 + i*8 + e], bfu2f((unsigned short)w8[e]), a);
        }
        redl[tid] = a;
      }
      __syncthreads();
      if (tid < 128)
        adhl[tid] = redl[tid*4] + redl[tid*4+1] + redl[tid*4+2] + redl[tid*4+3];
      __syncthreads();
      {
        const unsigned short* ep = eh2 + ((size_t)(b*512 + tid))*512 + quad*128;
        float part = 0.f;
        #pragma unroll
        for (int i=0;i<16;i++){
          const short8 e8 = *(const short8*)(ep + i*8);
          #pragma unroll
          for (int e=0;e<8;e++){
            const int n = i*8 + e;
            part = fmaf(vlds[quad*128+n], tanhfast(adhl[n] + bfu2f((unsigned short)e8[e])), part);
          }
        }
        float* sp = scorep + (size_t)bid*512 + tid;
        asm volatile("global_store_dword %0, %1, off sc0 sc1" :: "v"(sp), "v"(part) : "memory");
      }
    }
    ++m; mbar<4>(mc, m);

    {
      float pa, pb, pc, pd;
      const float* pp = scorep + (size_t)(b*4)*512 + tid;
      asm volatile("global_load_dword %0, %1, off sc0 sc1" : "=v"(pa) : "v"(pp) : "memory");
      asm volatile("global_load_dword %0, %1, off sc0 sc1" : "=v"(pb) : "v"(pp+512) : "memory");
      asm volatile("global_load_dword %0, %1, off sc0 sc1" : "=v"(pc) : "v"(pp+1024) : "memory");
      asm volatile("global_load_dword %0, %1, off sc0 sc1" : "=v"(pd) : "v"(pp+1536) : "memory");
      asm volatile("s_waitcnt vmcnt(0)" ::: "memory");
      __builtin_amdgcn_sched_barrier(0);
      float s0 = (pa+pb)+(pc+pd);
      s0 = smask[b*512+tid] ? s0 : -1.0e9f;
      redl[512+tid] = s0;
      __syncthreads();
      for (int off=256; off>0; off>>=1){
        if (tid<off) redl[512+tid] = fmaxf(redl[512+tid], redl[512+tid+off]);
        __syncthreads();
      }
      const float mx = redl[512];
      __syncthreads();
      const float e = __expf(s0 - mx);
      redl[512+tid] = e;
      __syncthreads();
      for (int off=256; off>0; off>>=1){
        if (tid<off) redl[512+tid] += redl[512+tid+off];
        __syncthreads();
      }
      const float Z = redl[512];
      __syncthreads();
      wlds[tid] = e / Z;
      __syncthreads();
      {
        const int jj = tid>>1, sh = tid&1;
        const unsigned short* cp = encT2 + ((size_t)(b*1024 + quad*256 + jj))*512 + sh*256;
        float c = 0.f;
        #pragma unroll
        for (int i=0;i<32;i++){
          const short8 c8 = *(const short8*)(cp + i*8);
          #pragma unroll
          for (int e2=0;e2<8;e2++)
            c = fmaf(wlds[sh*256 + i*8 + e2], bfu2f((unsigned short)c8[e2]), c);
        }
        redl[tid] = c;
      }
      __syncthreads();
      if (tid < 256){
        const float cv = redl[tid*2] + redl[tid*2+1];
        const int j = quad*256 + tid;
        float* cp2 = ctxf + b*1024 + j;
        asm volatile("global_store_dword %0, %1, off sc0 sc1" :: "v"(cp2), "v"(cv) : "memory");
        const unsigned cb16 = (unsigned)bfbits(cv);
        unsigned short* xp = xbuf + b*1536 + j;
        asm volatile("global_store_short %0, %1, off sc0 sc1" :: "v"(xp), "v"(cb16) : "memory");
      }
    }
    ++g; gbar<16>(gctr, root, grp, g);

    if (bid < 128){
      f32x4 av[2][6];
      f32x4 acc[4] = {{0,0,0,0},{0,0,0,0},{0,0,0,0},{0,0,0,0}};
      {
        const unsigned short* xp0 = xbuf + (size_t)(lane&15)*1536 + wv*192 + (lane>>4)*8;
        #pragma unroll
        for (int ks=0;ks<6;ks++){
          const unsigned short* p = xp0 + ks*32;
          asm volatile("global_load_dwordx4 %0, %1, off sc0 sc1" : "=v"(av[0][ks]) : "v"(p) : "memory");
        }
      }
      #pragma unroll
      for (int mt=0; mt<4; ++mt){
        if (mt<3){
          const unsigned short* xpn = xbuf + (size_t)((mt+1)*16 + (lane&15))*1536 + wv*192 + (lane>>4)*8;
          #pragma unroll
          for (int ks=0;ks<6;ks++){
            const unsigned short* p = xpn + ks*32;
            asm volatile("global_load_dwordx4 %0, %1, off sc0 sc1" : "=v"(av[(mt+1)&1][ks]) : "v"(p) : "memory");
          }
          asm volatile("s_waitcnt vmcnt(6)" ::: "memory");
        } else {
          asm volatile("s_waitcnt vmcnt(0)" ::: "memory");
        }
        __builtin_amdgcn_sched_barrier(0);
        #pragma unroll
        for (int ks=0;ks<6;ks++){
          V16 a; a.f = av[mt&1][ks];
          acc[mt] = __builtin_amdgcn_mfma_f32_16x16x32_bf16(a.s, gw[ks], acc[mt], 0, 0, 0);
        }
      }
      #pragma unroll
      for (int mt=0; mt<4; ++mt)
        *(f32x4*)&redl[wv*1024 + lane*16 + mt*4] = acc[mt];
    }
    __syncthreads();
    if (bid < 128){
      #pragma unroll
      for (int h2=0; h2<2; ++h2){
        const int o = h2*512 + tid;
        const int ob = o>>4, col = o&15;
        const int mt = ob>>4, row = ob&15;
        const int base = (((row>>2)<<4) | col)*16 + mt*4 + (row&3);
        float gsum = 0.f;
        #pragma unroll
        for (int w2=0; w2<8; ++w2) gsum += redl[w2*1024 + base];
        float* gp = gates + ob*2048 + bid*16 + col;
        asm volatile("global_store_dword %0, %1, off sc0 sc1" :: "v"(gp), "v"(gsum) : "memory");
      }
    }
    ++g; gbar<16>(gctr, root, grp, g);

    if (isb){
      float g4[4], c0v, c1v;
      {
        const float* gp = gates + b*2048 + tid;
        const float* cp = ctxf + b*1024 + tid;
        asm volatile("global_load_dword %0, %1, off sc0 sc1" : "=v"(g4[0]) : "v"(gp) : "memory");
        asm volatile("global_load_dword %0, %1, off sc0 sc1" : "=v"(g4[1]) : "v"(gp+512) : "memory");
        asm volatile("global_load_dword %0, %1, off sc0 sc1" : "=v"(g4[2]) : "v"(gp+1024) : "memory");
        asm volatile("global_load_dword %0, %1, off sc0 sc1" : "=v"(g4[3]) : "v"(gp+1536) : "memory");
        asm volatile("global_load_dword %0, %1, off sc0 sc1" : "=v"(c0v) : "v"(cp) : "memory");
        asm volatile("global_load_dword %0, %1, off sc0 sc1" : "=v"(c1v) : "v"(cp+512) : "memory");
        asm volatile("s_waitcnt vmcnt(0)" ::: "memory");
        __builtin_amdgcn_sched_barrier(0);
      }
      const float x = trg[b*96 + t]*0.001f;
      const float gi = g4[0] + x*pqi + qqi;
      const float gf = g4[1] + x*pqf + qqf;
      const float gg = g4[2] + x*pqg + qqg;
      const float go = g4[3] + x*pqo + qqo;
      const float cn = fmaf(sigm(gf), cr, sigm(gi)*tanhfast(gg));
      const float hn = sigm(go)*tanhfast(cn);
      cr = cn; hr = hn;
      const unsigned hb16 = (unsigned)bfbits(hn);
      unsigned short* xp = xbuf + b*1536 + 1024 + tid;
      asm volatile("global_store_short %0, %1, off sc0 sc1" :: "v"(xp), "v"(hb16) : "memory");
      float* hp = hcur + b*512 + tid;
      asm volatile("global_store_dword %0, %1, off sc0 sc1" :: "v"(hp), "v"(hn) : "memory");
      redl[512+tid]  = fmaf(hn, vwh, fmaf(c0v, vwc0, c1v*vwc1));
      redl[1024+tid] = fmaf(hn, swh, fmaf(c0v, swc0, c1v*swc1));
      __syncthreads();
      for (int off=256; off>0; off>>=1){
        if (tid<off){ redl[512+tid]+=redl[512+tid+off]; redl[1024+tid]+=redl[1024+tid+off]; }
        __syncthreads();
      }
      if (tid==0){
        out[b*95 + t] = (redl[512] + x*hc[0] + hc[1])*1000.f;
        out[6080 + b*95 + t] = redl[1024] + x*hc[2] + hc[3];
      }
    }
    ++m; mbar<4>(mc, m);
  }
}

// ---------------- fused persistent decoder: 512-block oct version ----------------
__global__ void __launch_bounds__(512, 4) dec_fused512(
  const float* __restrict__ trg, const int* __restrict__ smask,
  const float* __restrict__ attnv,
  const unsigned short* __restrict__ eh2,
  const unsigned short* __restrict__ encT2,
  const unsigned short* __restrict__ Wcat,
  const unsigned short* __restrict__ Wdecb,
  const float* __restrict__ PQd, const float* __restrict__ hc,
  const float* __restrict__ valW, const float* __restrict__ stopW,
  const float* __restrict__ dech0, const float* __restrict__ decc0,
  float* __restrict__ scorep, float* __restrict__ ctxf,
  unsigned short* __restrict__ xbuf, float* __restrict__ gates,
  float* __restrict__ hcur, float* __restrict__ out,
  unsigned* __restrict__ gctr, unsigned* __restrict__ root, unsigned* __restrict__ mctr)
{
  __shared__ alignas(16) float redl[8192];
  __shared__ float vlds[512];
  __shared__ float hldsa[512];
  __shared__ float adhl[64];
  __shared__ float wlds[512];
  const int tid = threadIdx.x;
  const int bid = blockIdx.x;
  const int b = bid>>3, oct = bid&7;
  const int grp = bid>>4;
  const int lane = tid&63, wv = tid>>6;
  unsigned* mc = mctr + b*32;
  unsigned g = 0, m = 0;

  vlds[tid] = attnv[tid];

  short8 gw[6];
  if (bid < 128){
    const int n = bid*16 + (lane&15);
    const unsigned short* wp = Wcat + (size_t)n*1536 + wv*192 + (lane>>4)*8;
    #pragma unroll
    for (int ks=0;ks<6;ks++) gw[ks] = *(const short8*)(wp + ks*32);
  }

  const bool isb = (oct==0);
  float hr=0.f, cr=0.f;
  float pqi=0,pqf=0,pqg=0,pqo=0, qqi=0,qqf=0,qqg=0,qqo=0;
  float vwh=0,vwc0=0,vwc1=0, swh=0,swc0=0,swc1=0;
  if (isb){
    hr = dech0[b*512+tid]; cr = decc0[b*512+tid];
    pqi = PQd[tid];      pqf = PQd[512+tid];      pqg = PQd[1024+tid];      pqo = PQd[1536+tid];
    qqi = PQd[2048+tid]; qqf = PQd[2048+512+tid]; qqg = PQd[2048+1024+tid]; qqo = PQd[2048+1536+tid];
    vwh = valW[tid]; vwc0 = valW[512+tid]; vwc1 = valW[1024+tid];
    swh = stopW[tid]; swc0 = stopW[512+tid]; swc1 = stopW[1024+tid];
  }

  if (isb){
    const unsigned hb16 = (unsigned)bfbits(hr);
    unsigned short* xp = xbuf + b*1536 + 1024 + tid;
    asm volatile("global_store_short %0, %1, off sc0 sc1" :: "v"(xp), "v"(hb16) : "memory");
    float* hp = hcur + b*512 + tid;
    asm volatile("global_store_dword %0, %1, off sc0 sc1" :: "v"(hp), "v"(hr) : "memory");
  }
  ++m; mbar<8>(mc, m);

  for (int t=0; t<95; ++t){
    {
      float hv; const float* hp = hcur + b*512 + tid;
      asm volatile("global_load_dword %0, %1, off sc0 sc1\ns_waitcnt vmcnt(0)" : "=v"(hv) : "v"(hp) : "memory");
      hldsa[tid] = hv;
      __syncthreads();
      {
        const int jl = tid>>3, uc = tid&7;
        const unsigned short* wp = Wdecb + (size_t)(oct*64 + jl)*512 + uc*64;
        float a = 0.f;
        #pragma unroll
        for (int i=0;i<8;i++){
          const short8 w8 = *(const short8*)(wp + i*8);
          #pragma unroll
          for (int e=0;e<8;e++)
            a = fmaf(hldsa[uc*64 + i*8 + e], bfu2f((unsigned short)w8[e]), a);
        }
        redl[tid] = a;
      }
      __syncthreads();
      if (tid < 64){
        float s8 = 0.f;
        #pragma unroll
        for (int i=0;i<8;i++) s8 += redl[tid*8+i];
        adhl[tid] = s8;
      }
      __syncthreads();
      {
        const unsigned short* ep = eh2 + ((size_t)(b*512 + tid))*512 + oct*64;
        float part = 0.f;
        #pragma unroll
        for (int i=0;i<8;i++){
          const short8 e8 = *(const short8*)(ep + i*8);
          #pragma unroll
          for (int e=0;e<8;e++){
            const int n = i*8 + e;
            part = fmaf(vlds[oct*64+n], tanhfast(adhl[n] + bfu2f((unsigned short)e8[e])), part);
          }
        }
        float* sp = scorep + (size_t)bid*512 + tid;
        asm volatile("global_store_dword %0, %1, off sc0 sc1" :: "v"(sp), "v"(part) : "memory");
      }
    }
    ++m; mbar<8>(mc, m);

    {
      float ps[8];
      const float* pp = scorep + (size_t)(b*8)*512 + tid;
      #pragma unroll
      for (int i=0;i<8;i++){
        const float* p = pp + i*512;
        asm volatile("global_load_dword %0, %1, off sc0 sc1" : "=v"(ps[i]) : "v"(p) : "memory");
      }
      asm volatile("s_waitcnt vmcnt(0)" ::: "memory");
      __builtin_amdgcn_sched_barrier(0);
      float s0 = ((ps[0]+ps[1])+(ps[2]+ps[3]))+((ps[4]+ps[5])+(ps[6]+ps[7]));
      s0 = smask[b*512+tid] ? s0 : -1.0e9f;
      redl[512+tid] = s0;
      __syncthreads();
      for (int off=256; off>0; off>>=1){
        if (tid<off) redl[512+tid] = fmaxf(redl[512+tid], redl[512+tid+off]);
        __syncthreads();
      }
      const float mx = redl[512];
      __syncthreads();
      const float e = __expf(s0 - mx);
      redl[512+tid] = e;
      __syncthreads();
      for (int off=256; off>0; off>>=1){
        if (tid<off) redl[512+tid] += redl[512+tid+off];
        __syncthreads();
      }
      const float Z = redl[512];
      __syncthreads();
      wlds[tid] = e / Z;
      __syncthreads();
      {
        const int jj = tid>>2, sh = tid&3;
        const unsigned short* cp = encT2 + ((size_t)(b*1024 + oct*128 + jj))*512 + sh*128;
        float c = 0.f;
        #pragma unroll
        for (int i=0;i<16;i++){
          const short8 c8 = *(const short8*)(cp + i*8);
          #pragma unroll
          for (int e2=0;e2<8;e2++)
            c = fmaf(wlds[sh*128 + i*8 + e2], bfu2f((unsigned short)c8[e2]), c);
        }
        redl[tid] = c;
      }
      __syncthreads();
      if (tid < 128){
        const float cv = redl[tid*4] + redl[tid*4+1] + redl[tid*4+2] + redl[tid*4+3];
        const int j = oct*128 + tid;
        float* cp2 = ctxf + b*1024 + j;
        asm volatile("global_store_dword %0, %1, off sc0 sc1" :: "v"(cp2), "v"(cv) : "memory");
        const unsigned cb16 = (unsigned)bfbits(cv);
        unsigned short* xp = xbuf + b*1536 + j;
        asm volatile("global_store_short %0, %1, off sc0 sc1" :: "v"(xp), "v"(cb16) : "memory");
      }
    }
    ++g; gbar<32>(gctr, root, grp, g);

    if (bid < 128){
      f32x4 av[2][6];
      f32x4 acc[4] = {{0,0,0,0},{0,0,0,0},{0,0,0,0},{0,0,0,0}};
      {
        const unsigned short* xp0 = xbuf + (size_t)(lane&15)*1536 + wv*192 + (lane>>4)*8;
        #pragma unroll
        for (int ks=0;ks<6;ks++){
          const unsigned short* p = xp0 + ks*32;
          asm volatile("global_load_dwordx4 %0, %1, off sc0 sc1" : "=v"(av[0][ks]) : "v"(p) : "memory");
        }
      }
      #pragma unroll
      for (int mt=0; mt<4; ++mt){
        if (mt<3){
          const unsigned short* xpn = xbuf + (size_t)((mt+1)*16 + (lane&15))*1536 + wv*192 + (lane>>4)*8;
          #pragma unroll
          for (int ks=0;ks<6;ks++){
            const unsigned short* p = xpn + ks*32;
            asm volatile("global_load_dwordx4 %0, %1, off sc0 sc1" : "=v"(av[(mt+1)&1][ks]) : "v"(p) : "memory");
          }
          asm volatile("s_waitcnt vmcnt(6)" ::: "memory");
        } else {
          asm volatile("s_waitcnt vmcnt(0)" ::: "memory");
        }
        __builtin_amdgcn_sched_barrier(0);
        #pragma unroll
        for (int ks=0;ks<6;ks++){
          V16 a; a.f = av[mt&1][ks];
          acc[mt] = __builtin_amdgcn_mfma_f32_16x16x32_bf16(a.s, gw[ks], acc[mt], 0, 0, 0);
        }
      }
      #pragma unroll
      for (int mt=0; mt<4; ++mt)
        *(f32x4*)&redl[wv*1024 + lane*16 + mt*4] = acc[mt];
    }
    __syncthreads();
    if (bid < 128){
      #pragma unroll
      for (int h2=0; h2<2; ++h2){
        const int o = h2*512 + tid;
        const int ob = o>>4, col = o&15;
        const int mt = ob>>4, row = ob&15;
        const int base = (((row>>2)<<4) | col)*16 + mt*4 + (row&3);
        float gsum = 0.f;
        #pragma unroll
        for (int w2=0; w2<8; ++w2) gsum += redl[w2*1024 + base];
        float* gp = gates + ob*2048 + bid*16 + col;
        asm volatile("global_store_dword %0, %1, off sc0 sc1" :: "v"(gp), "v"(gsum) : "memory");
      }
    }
    ++g; gbar<32>(gctr, root, grp, g);

    if (isb){
      float g4[4], c0v, c1v;
      {
        const float* gp = gates + b*2048 + tid;
        const float* cp = ctxf + b*1024 + tid;
        asm volatile("global_load_dword %0, %1, off sc0 sc1" : "=v"(g4[0]) : "v"(gp) : "memory");
        asm volatile("global_load_dword %0, %1, off sc0 sc1" : "=v"(g4[1]) : "v"(gp+512) : "memory");
        asm volatile("global_load_dword %0, %1, off sc0 sc1" : "=v"(g4[2]) : "v"(gp+1024) : "memory");
        asm volatile("global_load_dword %0, %1, off sc0 sc1" : "=v"(g4[3]) : "v"(gp+1536) : "memory");
        asm volatile("global_load_dword %0, %1, off sc0 sc1" : "=v"(c0v) : "v"(cp) : "memory");
        asm volatile("global_load_dword %0, %1, off sc0 sc1" : "=v"(c1v) : "v"(cp+512) : "memory");
        asm volatile("s_waitcnt vmcnt(0)" ::: "memory");
        __builtin_amdgcn_sched_barrier(0);
      }
      const float x = trg[b*96 + t]*0.001f;
      const float gi = g4[0] + x*pqi + qqi;
      const float gf = g4[1] + x*pqf + qqf;
      const float gg = g4[2] + x*pqg + qqg;
      const float go = g4[3] + x*pqo + qqo;
      const float cn = fmaf(sigm(gf), cr, sigm(gi)*tanhfast(gg));
      const float hn = sigm(go)*tanhfast(cn);
      cr = cn; hr = hn;
      const unsigned hb16 = (unsigned)bfbits(hn);
      unsigned short* xp = xbuf + b*1536 + 1024 + tid;
      asm volatile("global_store_short %0, %1, off sc0 sc1" :: "v"(xp), "v"(hb16) : "memory");
      float* hp = hcur + b*512 + tid;
      asm volatile("global_store_dword %0, %1, off sc0 sc1" :: "v"(hp), "v"(hn) : "memory");
      redl[512+tid]  = fmaf(hn, vwh, fmaf(c0v, vwc0, c1v*vwc1));
      redl[1024+tid] = fmaf(hn, swh, fmaf(c0v, swc0, c1v*swc1));
      __syncthreads();
      for (int off=256; off>0; off>>=1){
        if (tid<off){ redl[512+tid]+=redl[512+tid+off]; redl[1024+tid]+=redl[1024+tid+off]; }
        __syncthreads();
      }
      if (tid==0){
        out[b*95 + t] = (redl[512] + x*hc[0] + hc[1])*1000.f;
        out[6080 + b*95 + t] = redl[1024] + x*hc[2] + hc[3];
      }
    }
    ++m; mbar<8>(mc, m);
  }
}

// ---------------- launch ----------------
extern "C" void kernel_launch(void* const* d_in, const int* in_sizes, int n_in,
                              void* d_out, int out_size, void* d_ws, size_t ws_size,
                              hipStream_t stream)
{
  (void)in_sizes; (void)n_in; (void)out_size; (void)ws_size;
  const float* src   = (const float*)d_in[0];
  const int*   smask = (const int*)  d_in[1];
  const float* trg   = (const float*)d_in[2];
  const float* epW   = (const float*)d_in[4];
  const float* epb   = (const float*)d_in[5];
  const float* Wihf  = (const float*)d_in[6];
  const float* Whhf  = (const float*)d_in[7];
  const float* bihf  = (const float*)d_in[8];
  const float* bhhf  = (const float*)d_in[9];
  const float* Wihb  = (const float*)d_in[10];
  const float* Whhb  = (const float*)d_in[11];
  const float* bihb  = (const float*)d_in[12];
  const float* bhhb  = (const float*)d_in[13];
  const float* fchW  = (const float*)d_in[14];
  const float* fchB  = (const float*)d_in[15];
  const float* fccW  = (const float*)d_in[16];
  const float* fccB  = (const float*)d_in[17];
  const float* dpW   = (const float*)d_in[18];
  const float* dpb   = (const float*)d_in[19];
  const float* Wenc  = (const float*)d_in[20];
  const float* Wdec  = (const float*)d_in[21];
  const float* attnv = (const float*)d_in[22];
  const float* dWih  = (const float*)d_in[23];
  const float* dWhh  = (const float*)d_in[24];
  const float* dbih  = (const float*)d_in[25];
  const float* dbhh  = (const float*)d_in[26];
  const float* valW  = (const float*)d_in[27];
  const float* valb  = (const float*)d_in[28];
  const float* stopW = (const float*)d_in[29];
  const float* stopb = (const float*)d_in[30];
  float* out = (float*)d_out;

  // ---- bump allocator ----
  char* ws = (char*)d_ws;
  size_t off = 0;
  auto take = [&](size_t nbytes) -> char* {
    char* p = ws + off;
    off += (nbytes + 255) & ~(size_t)255;
    return p;
  };
  unsigned short* enc   = (unsigned short*)take((size_t)64*512*1024*2);
  unsigned short* eh2   = (unsigned short*)take((size_t)64*512*512*2);
  unsigned short* encT2 = (unsigned short*)take((size_t)64*1024*512*2);
  unsigned short* hbuf  = (unsigned short*)take(2*2*64*512*2);
  unsigned short* Wbf   = (unsigned short*)take((size_t)2*2048*512*2);
  unsigned short* Wcat  = (unsigned short*)take((size_t)2048*1536*2);
  unsigned short* Wdecb = (unsigned short*)take(512*512*2);
  unsigned short* Wencb = (unsigned short*)take(512*1024*2);
  float* WT    = (float*)take((size_t)1024*512*4);
  float* hfin  = (float*)take(2*64*512*4);
  float* cf    = (float*)take(64*512*4);
  float* cb    = (float*)take(64*512*4);
  float* PQ    = (float*)take(6*2048*4);
  float* dech0 = (float*)take(64*512*4);
  float* decc0 = (float*)take(64*512*4);
  float* scorep= (float*)take(512*512*4);
  float* ctxf  = (float*)take(64*1024*4);
  unsigned short* xbuf = (unsigned short*)take(64*1536*2);
  float* gates = (float*)take(64*2048*4);
  float* hcur  = (float*)take(64*512*4);
  float* hc    = (float*)take(256);
  unsigned* cnt  = (unsigned*)take(1024);
  unsigned* gctr = (unsigned*)take(4096);
  unsigned* root = (unsigned*)take(256);
  unsigned* mctr = (unsigned*)take(8192);
  float* PQd = PQ + 8192;
  (void)hipMemsetAsync(cnt, 0, 1024+4096+256+8192, stream);

  precompute<<<2097, 256, 0, stream>>>(Wenc, Wihf, epW, epb, bihf, bhhf, Wihb, bihb, bhhb,
                                       dWih, dpW, dpb, dbih, dbhh, valW, valb, stopW, stopb,
                                       PQ, WT, hc);
  wconv<<<11776, 512, 0, stream>>>(Whhf, Whhb, dWih, dWhh, Wdec, Wenc, Wbf, Wcat, Wdecb, Wencb);

  {
    void* args[] = { (void*)&src, (void*)&smask, (void*)&Wbf, (void*)&PQ,
                     (void*)&hbuf, (void*)&hfin, (void*)&cf, (void*)&cb, (void*)&enc, (void*)&cnt };
    (void)hipLaunchCooperativeKernel((void*)enc_mfma, dim3(256), dim3(512), args, 0, stream);
  }

  {
    const float* hfF = hfin;
    const float* hbF = hfin + 32768;
    fc_init<<<256, 256, 0, stream>>>(hfF, hbF, cf, cb, fchW, fchB, fccW, fccB, dech0, decc0);
  }
  eh_mfma<<<4096, 256, 0, stream>>>(enc, Wencb, eh2);
  enc_tr<<<8192, 256, 0, stream>>>(enc, encT2);

  {
    void* args[] = { (void*)&trg, (void*)&smask, (void*)&attnv,
                     (void*)&eh2, (void*)&encT2, (void*)&Wcat, (void*)&Wdecb,
                     (void*)&PQd, (void*)&hc, (void*)&valW, (void*)&stopW,
                     (void*)&dech0, (void*)&decc0,
                     (void*)&scorep, (void*)&ctxf,
                     (void*)&xbuf, (void*)&gates, (void*)&hcur, (void*)&out,
                     (void*)&gctr, (void*)&root, (void*)&mctr };
    // try 2-blocks/CU oct version; fall back to proven 256-block quad version
    int nb2 = 0;
    (void)hipOccupancyMaxActiveBlocksPerMultiprocessor(&nb2, dec_fused512, 512, 0);
    hipError_t e512 = hipErrorUnknown;
    if (nb2 >= 2)
      e512 = hipLaunchCooperativeKernel((void*)dec_fused512, dim3(512), dim3(512), args, 0, stream);
    if (e512 != hipSuccess)
      (void)hipLaunchCooperativeKernel((void*)dec_fused256, dim3(256), dim3(512), args, 0, stream);
  }
}